// Round 5
// baseline (541.754 us; speedup 1.0000x reference)
//
#include <hip/hip_runtime.h>
#include <math.h>

// Problem constants: B=4, L=1024, D_IN=128, D_MODEL=512, N_LAYERS=2,
// N_CLASSES=3, D_INNER=1024, D_STATE=64, D_CONV=2, DT_RANK=32, BL=4096.
//
// Precision plan: all GEMM operands f16 (conversions hoisted upstream).
// Layer-1 residual h f16 scaled by 2^8 (exact). y scaled by 2^14 at the
// scan store. Head works from y16(l1) directly with fp32 weights.
//
// R21: scan v4 — R20 proved (VGPR=32) the compiler re-serializes chunk
// loads no matter what C++-level hints are used; the scan is latency-bound
// (~2000 cy/chunk vs ~150 cy VALU). Now all 10 per-chunk loads are inline-asm
// global_load_* into explicit register buffers (asm-volatile order is
// immutable), gated by counted `s_waitcnt vmcnt(10)` + sched_barrier(0)
// (rule #18). Two buffers, issue(n+1) after compute(n): 1-chunk prefetch
// distance guaranteed, x4 waves TLP.

using half8  = __attribute__((ext_vector_type(8))) _Float16;
using half4v = __attribute__((ext_vector_type(4))) _Float16;
using f32x4  = __attribute__((ext_vector_type(4))) float;

#define Y_SCALE 16384.0f   // 2^14
#define H1_SCALE 256.0f    // 2^8

__device__ __forceinline__ float silu_f(float v) {
  return v / (1.f + __expf(-v));
}

__device__ __forceinline__ float fast_exp2(float x) {
#if __has_builtin(__builtin_amdgcn_exp2f)
  return __builtin_amdgcn_exp2f(x);
#else
  return __expf(x * 0.69314718055994531f);
#endif
}

// ---------------------------------------------------------------------------
// One-shot fp32 -> f16 conversion of all weights + x into the w16 pool.
//   exp_w 0..65536 | in_w ..2162688 | xproj_w ..2490368 | dtproj_w ..2555904
//   | out_w ..3604480 | x ..4128768
// ---------------------------------------------------------------------------
__global__ void wcvt_kernel(const float* __restrict__ exp_w,
                            const float* __restrict__ in_w,
                            const float* __restrict__ xproj_w,
                            const float* __restrict__ dtproj_w,
                            const float* __restrict__ out_w,
                            const float* __restrict__ x,
                            _Float16* __restrict__ w16)
{
  size_t gi = ((size_t)blockIdx.x * 256 + threadIdx.x) * 4;
  const float* src; size_t off;
  if      (gi < 65536)   { src = exp_w;    off = gi; }
  else if (gi < 2162688) { src = in_w;     off = gi - 65536; }
  else if (gi < 2490368) { src = xproj_w;  off = gi - 2162688; }
  else if (gi < 2555904) { src = dtproj_w; off = gi - 2490368; }
  else if (gi < 3604480) { src = out_w;    off = gi - 2555904; }
  else                   { src = x;        off = gi - 3604480; }
  float4 v = *(const float4*)(src + off);
  half4v h;
  h[0] = (_Float16)v.x; h[1] = (_Float16)v.y;
  h[2] = (_Float16)v.z; h[3] = (_Float16)v.w;
  *(half4v*)(w16 + gi) = h;
}

// ---------------------------------------------------------------------------
// f16 MFMA GEMM, 64 x BN tile, BK-chunk K-loop. Block 256 thr = 4 waves;
// wave-tile 32 x (BN/2), MI=2 m-frags. BK in {32,64}.
// Modes: 0 plain / 1 in_proj fused (REQUIRES BK=64, BN=128; Tz aliases Ws) /
// 2 xproj split (dtr16 + Bsc/Csc scan layout) / 3 dtproj transposed-softplus.
// MFMA layouts (m89/m120-verified): A-frag A[m=lane&15][k=q*8+j],
// B-frag B[k=q*8+j][n=lane&15], D: col(n)=lane&15, row(m)=q*4+r.
// ---------------------------------------------------------------------------
template<int BN, int BK, int ACT, int OF16, int MODE>
__global__ __launch_bounds__(256)
void gemm_mfma(const _Float16* __restrict__ A, int lda,
               const _Float16* __restrict__ W,
               const float* __restrict__ bias,
               void* __restrict__ Cv, int ldc,
               int N, int K, float oscale,
               void* __restrict__ Cv2)
{
  static_assert(MODE != 1 || (BK == 64 && BN == 128), "MODE1 needs BK=64/BN=128");
  constexpr int NF  = BN / 32;           // n-frags per wave
  constexpr int LS  = BK + 8;            // LDS row stride in halfs (16B-aligned)
  constexpr int NA  = BK / 32;           // A half8 regs per thread
  constexpr int WTR = 256 / BN;          // threads per W row
  constexpr int WH  = BK / WTR;          // W halfs per thread (R18b fix)
  constexpr int NW  = WH / 8;            // W half8 regs per thread
  static_assert(NA >= 1 && NW >= 1, "staging arithmetic");

  __shared__ _Float16 As[64 * LS];
  __shared__ _Float16 Ws[BN * LS];       // MODE1: reused as Tz in epilogue
  __shared__ float    Td[(MODE == 3) ? 64 * 68 : 2];
  const int tid  = threadIdx.x;
  const int lane = tid & 63;
  const int wid  = tid >> 6;
  const int wm   = wid & 1, wn = wid >> 1;   // wave-tile: 32 m x BN/2 n
  const int m0   = blockIdx.y * 64;
  const int n0   = blockIdx.x * BN;
  const int q    = lane >> 4, l16 = lane & 15;

  // staging coords
  const int ar  = tid >> 2;                  // A: 4 thr/row
  const int akq = (tid & 3) * (BK / 4);
  const int wr  = tid / WTR;
  const int wkq = (tid % WTR) * WH;
  const int wrow = n0 + wr;
  const bool wv  = (wrow < N);

  const _Float16* Wp = W + (size_t)wrow * K;
  const size_t aoff = (size_t)(m0 + ar) * lda + akq;

  half8 zh;
  #pragma unroll
  for (int i = 0; i < 8; ++i) zh[i] = (_Float16)0.f;

  // initial loads (k0 = 0)
  half8 rah[NA], rwh[NW];
  #pragma unroll
  for (int i = 0; i < NA; ++i) rah[i] = *(const half8*)(A + aoff + i * 8);
  #pragma unroll
  for (int j = 0; j < NW; ++j)
    rwh[j] = wv ? *(const half8*)(Wp + wkq + j * 8) : zh;

  f32x4 acc[2][NF];
  #pragma unroll
  for (int mi = 0; mi < 2; ++mi)
    #pragma unroll
    for (int ni = 0; ni < NF; ++ni)
      acc[mi][ni] = (f32x4){0.f, 0.f, 0.f, 0.f};

  for (int k0 = 0; k0 < K; k0 += BK) {
    if (k0) __syncthreads();
    #pragma unroll
    for (int i = 0; i < NA; ++i)
      *(half8*)&As[ar * LS + akq + i * 8] = rah[i];
    #pragma unroll
    for (int j = 0; j < NW; ++j)
      *(half8*)&Ws[wr * LS + wkq + j * 8] = rwh[j];
    __syncthreads();

    if (k0 + BK < K) {            // prefetch next chunk
      const int kn = k0 + BK;
      #pragma unroll
      for (int i = 0; i < NA; ++i)
        rah[i] = *(const half8*)(A + aoff + kn + i * 8);
      if (wv) {
        #pragma unroll
        for (int j = 0; j < NW; ++j)
          rwh[j] = *(const half8*)(Wp + kn + wkq + j * 8);
      }
    }

    #pragma unroll
    for (int kk = 0; kk < BK / 32; ++kk) {
      half8 af[2], wf[NF];
      #pragma unroll
      for (int mi = 0; mi < 2; ++mi)
        af[mi] = *(const half8*)&As[(wm * 32 + mi * 16 + l16) * LS + kk * 32 + q * 8];
      #pragma unroll
      for (int ni = 0; ni < NF; ++ni)
        wf[ni] = *(const half8*)&Ws[(wn * (BN / 2) + ni * 16 + l16) * LS + kk * 32 + q * 8];
      #pragma unroll
      for (int mi = 0; mi < 2; ++mi)
        #pragma unroll
        for (int ni = 0; ni < NF; ++ni)
          acc[mi][ni] = __builtin_amdgcn_mfma_f32_16x16x32_f16(af[mi], wf[ni],
                                                               acc[mi][ni], 0, 0, 0);
    }
  }

  float*    Cf = (float*)Cv;
  _Float16* Ch = (_Float16*)Cv;

  if (MODE == 1) {
    if (n0 < 1024) {
      // xc half: f16 [M][1024]
      #pragma unroll
      for (int ni = 0; ni < NF; ++ni) {
        const int n = n0 + wn * (BN / 2) + ni * 16 + l16;
        #pragma unroll
        for (int mi = 0; mi < 2; ++mi) {
          const int mb = m0 + wm * 32 + mi * 16 + q * 4;
          #pragma unroll
          for (int r = 0; r < 4; ++r)
            Ch[(size_t)(mb + r) * 1024 + n] = (_Float16)(acc[mi][ni][r] * oscale);
        }
      }
    } else {
      // z half: silu -> f16, LDS transpose (Tz aliases Ws; LS==72),
      // coalesced 16B row stores
      _Float16* Tz = Ws;
      _Float16* Ch2 = (_Float16*)Cv2;
      __syncthreads();                  // all MFMA reads of Ws done
      #pragma unroll
      for (int ni = 0; ni < NF; ++ni) {
        const int nnl = wn * (BN / 2) + ni * 16 + l16;   // 0..127 local
        #pragma unroll
        for (int mi = 0; mi < 2; ++mi) {
          const int mbl = wm * 32 + mi * 16 + q * 4;     // 0..63 local
          half4v h4;
          #pragma unroll
          for (int r = 0; r < 4; ++r)
            h4[r] = (_Float16)silu_f(acc[mi][ni][r] * oscale);
          *(half4v*)&Tz[nnl * LS + mbl] = h4;
        }
      }
      __syncthreads();
      const int sr = tid >> 3;          // 0..31
      const int sc = (tid & 7) * 8;     // halfs 0..56
      #pragma unroll
      for (int rd = 0; rd < 4; ++rd) {
        const int row = rd * 32 + sr;
        half8 v = *(const half8*)&Tz[row * LS + sc];
        *(half8*)&Ch2[(size_t)(n0 - 1024 + row) * 4096 + m0 + sc] = v;
      }
    }
    return;
  }

  if (MODE == 2) {
    // xproj split:
    //   n <  32           -> dtr16 f16 [M][32]           (via Cv2)
    //   32 <= n <  96     -> Bsc scan layout             (via Cv)
    //   96 <= n < 160     -> Csc = Bsc + 262144
    // Scan layout: [b*256 + t/4][s 0..63][t&3] fp32. mb%4==0 so the 4 acc
    // components (rows mb..mb+3) form one contiguous float4 at s*4.
    float* Bs = Cf;
    _Float16* dtr = (_Float16*)Cv2;
    #pragma unroll
    for (int ni = 0; ni < NF; ++ni) {
      const int n = n0 + wn * (BN / 2) + ni * 16 + l16;
      #pragma unroll
      for (int mi = 0; mi < 2; ++mi) {
        const int mb = m0 + wm * 32 + mi * 16 + q * 4;
        if (n < 32) {
          #pragma unroll
          for (int r = 0; r < 4; ++r)
            dtr[(size_t)(mb + r) * 32 + n] = (_Float16)acc[mi][ni][r];
        } else if (n < 160) {
          const int s = (n < 96) ? (n - 32) : (n - 96);
          float* dst = Bs + ((n < 96) ? 0 : 262144);
          float4 v = make_float4(acc[mi][ni][0], acc[mi][ni][1],
                                 acc[mi][ni][2], acc[mi][ni][3]);
          *(float4*)&dst[((size_t)(mb >> 2) << 8) + s * 4] = v;
        }
      }
    }
    return;
  }

  if (MODE == 3) {
    // dtproj: softplus(acc*oscale + bias) -> fp32 [N][4096] via LDS transpose
    __syncthreads();
    #pragma unroll
    for (int ni = 0; ni < NF; ++ni) {
      const int nnl = wn * (BN / 2) + ni * 16 + l16;     // 0..63 local
      const float bv = (bias != nullptr) ? bias[n0 + nnl] : 0.f;
      #pragma unroll
      for (int mi = 0; mi < 2; ++mi) {
        const int mbl = wm * 32 + mi * 16 + q * 4;       // 0..63 local
        float o[4];
        #pragma unroll
        for (int r = 0; r < 4; ++r) {
          float v = acc[mi][ni][r] * oscale + bv;
          o[r] = (v > 20.f) ? v : log1pf(__expf(v));     // softplus
        }
        *(float4*)&Td[nnl * 68 + mbl] = make_float4(o[0], o[1], o[2], o[3]);
      }
    }
    __syncthreads();
    const int sr = tid >> 4;            // 0..15
    const int sc = (tid & 15) * 4;      // floats 0..60
    #pragma unroll
    for (int rd = 0; rd < 4; ++rd) {
      const int row = rd * 16 + sr;
      float4 v = *(const float4*)&Td[row * 68 + sc];
      *(float4*)&Cf[(size_t)(n0 + row) * 4096 + m0 + sc] = v;
    }
    return;
  }

  // MODE 0 epilogue
  #pragma unroll
  for (int ni = 0; ni < NF; ++ni) {
    const int n = n0 + wn * (BN / 2) + ni * 16 + l16;
    if (n < N) {
      const float bv = (bias != nullptr) ? bias[n] : 0.f;
      #pragma unroll
      for (int mi = 0; mi < 2; ++mi) {
        const int mb = m0 + wm * 32 + mi * 16 + q * 4;
        #pragma unroll
        for (int r = 0; r < 4; ++r) {
          float v = acc[mi][ni][r] * oscale + bv;
          if (ACT == 1) v = (v > 20.f) ? v : log1pf(__expf(v));
          if (ACT == 2) v = silu_f(v);
          size_t off = (size_t)(mb + r) * ldc + n;
          if (OF16) Ch[off] = (_Float16)v;
          else      Cf[off] = v;
        }
      }
    }
  }
}

// ---------------------------------------------------------------------------
// Depthwise causal conv (D_CONV=2) + silu, 64x64 LDS transpose.
// in : xcp [4096 bl][1024 d] f16
// out: xcT [1024 d][4096 bl] fp32 (scan input)  +  xcf [4096 bl][1024 d] f16
// ---------------------------------------------------------------------------
__global__ void conv_t_kernel(const _Float16* __restrict__ xcp,
                              const float* __restrict__ cw,   // [1024][2]
                              const float* __restrict__ cb,   // [1024]
                              float* __restrict__ xcT,
                              _Float16* __restrict__ xcf)
{
  __shared__ float tile[64][65];
  const int blk = blockIdx.x;            // b*256 + tt*16 + dd
  const int b  = blk >> 8;
  const int tt = (blk >> 4) & 15;
  const int dd = blk & 15;
  const int t0 = tt * 64, d0 = dd * 64;
  const int tid = threadIdx.x;

  #pragma unroll
  for (int i = 0; i < 16; ++i) {
    int idx = i * 256 + tid;
    int t = idx >> 6, d = idx & 63;
    int gt = t0 + t;
    size_t rcur = ((size_t)(b * 1024 + gt) << 10) + d0 + d;
    float cur  = (float)xcp[rcur];
    float prev = (gt > 0) ? (float)xcp[rcur - 1024] : 0.f;
    float v = fmaf(prev, cw[(d0+d)*2], fmaf(cur, cw[(d0+d)*2 + 1], cb[d0+d]));
    float sv = silu_f(v);
    tile[t][d] = sv;
    xcf[rcur] = (_Float16)sv;
  }
  __syncthreads();
  #pragma unroll
  for (int i = 0; i < 16; ++i) {
    int idx = i * 256 + tid;
    int d = idx >> 6, t = idx & 63;
    xcT[((size_t)(d0 + d) << 12) + b * 1024 + t0 + t] = tile[t][d];
  }
}

// ---------------------------------------------------------------------------
// Selective scan v4, time-major. One wave per (b,d), lane = s (D_STATE=64).
// Chunk = 8 timesteps; TWO register buffers filled by inline-asm VMEM
// (volatile => issue order immutable), gated by counted s_waitcnt vmcnt(10)
// + sched_barrier(0). Steady state: [wait(10); SB; compute(buf); issue(buf,
// +16)] per half-iteration -> each chunk's 10 loads fly across one full
// compute phase, x4 waves TLP. B/C from scan-native [b][t/4][s][4] layout.
// ---------------------------------------------------------------------------
struct CBuf {
  f32x4 B0, B1, C0, C1, d0, d1, x0, x1;   // 32 VGPRs
  unsigned zsu;                            // ushort payload
  float xvl;
};

__device__ __forceinline__ void issue_chunk(int t0, CBuf& c,
    const float* Bb, const float* Cbp,
    const float* dtp, const float* xp,
    const _Float16* zsp, int tt_r)
{
  const float* Bp = Bb  + ((size_t)((unsigned)t0 >> 2) << 8);   // t0*64 floats
  const float* Cp = Cbp + ((size_t)((unsigned)t0 >> 2) << 8);
  // 10 VMEM ops, program-ordered (asm volatile). SIInsertWaitcnts does not
  // model these; OUR counted waits below are the only gates.
  asm volatile("global_load_dwordx4 %0, %1, off" : "=v"(c.B0) : "v"(Bp));
  asm volatile("global_load_dwordx4 %0, %1, off" : "=v"(c.B1) : "v"(Bp + 256));
  asm volatile("global_load_dwordx4 %0, %1, off" : "=v"(c.C0) : "v"(Cp));
  asm volatile("global_load_dwordx4 %0, %1, off" : "=v"(c.C1) : "v"(Cp + 256));
  asm volatile("global_load_dwordx4 %0, %1, off" : "=v"(c.d0) : "v"(dtp + t0));
  asm volatile("global_load_dwordx4 %0, %1, off" : "=v"(c.d1) : "v"(dtp + t0 + 4));
  asm volatile("global_load_dwordx4 %0, %1, off" : "=v"(c.x0) : "v"(xp + t0));
  asm volatile("global_load_dwordx4 %0, %1, off" : "=v"(c.x1) : "v"(xp + t0 + 4));
  asm volatile("global_load_ushort %0, %1, off"  : "=v"(c.zsu) : "v"(zsp + t0 + tt_r));
  asm volatile("global_load_dword  %0, %1, off"  : "=v"(c.xvl) : "v"(xp + t0 + tt_r));
}

// wait until at most N of our VMEM ops remain in flight, then fence the
// scheduler so no use of the waited-on registers can hoist above (rule #18).
#define SCAN_WAIT(N) do {                                   \
    asm volatile("s_waitcnt vmcnt(" #N ")" ::: "memory");   \
    __builtin_amdgcn_sched_barrier(0);                      \
  } while (0)

__device__ __forceinline__ void compute_chunk(int t0, const CBuf& c, float& h,
    float al2, float dpv, float (*Pw)[68], int lane, int tt_r, int c0,
    _Float16* __restrict__ yp)
{
  float dvv[8] = {c.d0[0], c.d0[1], c.d0[2], c.d0[3],
                  c.d1[0], c.d1[1], c.d1[2], c.d1[3]};
  float xvv[8] = {c.x0[0], c.x0[1], c.x0[2], c.x0[3],
                  c.x1[0], c.x1[1], c.x1[2], c.x1[3]};
  float Bvv[8] = {c.B0[0], c.B0[1], c.B0[2], c.B0[3],
                  c.B1[0], c.B1[1], c.B1[2], c.B1[3]};
  float Cvv[8] = {c.C0[0], c.C0[1], c.C0[2], c.C0[3],
                  c.C1[0], c.C1[1], c.C1[2], c.C1[3]};
  const float zs = (float)__builtin_bit_cast(_Float16,
                     (unsigned short)(c.zsu & 0xffffu)) * Y_SCALE;
  // parallel phase: everything h-independent
  float dA[8], ub[8];
  #pragma unroll
  for (int tt = 0; tt < 8; ++tt) {
    dA[tt] = fast_exp2(dvv[tt] * al2);
    ub[tt] = dvv[tt] * xvv[tt] * Bvv[tt];
  }
  // serial recurrence: fma -> mul -> ds_write per t
  #pragma unroll
  for (int tt = 0; tt < 8; ++tt) {
    h = fmaf(h, dA[tt], ub[tt]);
    Pw[tt][lane] = h * Cvv[tt];
  }
  // batched reduction: lane L sums 8 states of timestep L>>3
  float4 s0 = *(const float4*)&Pw[tt_r][c0];
  float4 s1 = *(const float4*)&Pw[tt_r][c0 + 4];
  float r = ((s0.x + s0.y) + (s0.z + s0.w)) + ((s1.x + s1.y) + (s1.z + s1.w));
  r += __shfl_xor(r, 1, 64);
  r += __shfl_xor(r, 2, 64);
  r += __shfl_xor(r, 4, 64);
  if ((lane & 7) == 0)
    yp[(size_t)(t0 + tt_r) << 10] = (_Float16)(fmaf(c.xvl, dpv, r) * zs);
}

__global__ __launch_bounds__(256, 3)   // reg budget ~170: headroom, no spills
void scan_kernel(const float* __restrict__ dtT,     // [1024][4096]
                 const float* __restrict__ xcT,     // [1024][4096]
                 const _Float16* __restrict__ zsT,  // [1024][4096], silu(z), f16
                 const float* __restrict__ Bsc,     // [4][256][64][4]; Csc at +262144
                 const float* __restrict__ A_log,   // [1024][64]
                 const float* __restrict__ Dp,      // [1024]
                 _Float16* __restrict__ y16)        // [4096 bl][1024 d], y*2^14
{
  __shared__ float P[4][8][68];        // per-wave reduction tile (wave-private)
  const int tid  = threadIdx.x;
  const int lane = tid & 63;
  const int wrp  = tid >> 6;
  const int rb   = blockIdx.x;
  const int bswz = ((rb & 7) << 7) | (rb >> 3);          // XCD swizzle
  const int wid  = __builtin_amdgcn_readfirstlane(bswz * 4 + wrp);
  const int b = wid >> 10;
  const int d = wid & 1023;
  float (*Pw)[68] = P[wrp];

  const float a   = -__expf(A_log[d * 64 + lane]);
  const float al2 = a * 1.44269504088896f;               // hoisted log2(e)
  const float dpv = Dp[d];
  // pin prologue loads: forces the compiler's auto vmcnt wait for Dp/A_log
  // to land HERE (pre-loop), not inside the loop where it would drain our
  // asm pipeline every iteration.
  asm volatile("" :: "v"(dpv), "v"(al2));
  const size_t row = ((size_t)d << 12) + b * 1024;
  const float*    dtp = dtT + row;
  const float*    xp  = xcT + row;
  const _Float16* zsp = zsT + row;
  _Float16*       yp  = y16 + ((size_t)b << 20) + d;     // + t*1024
  const float*    Bb  = Bsc + ((size_t)b << 16) + lane * 4;
  const float*    Cbp = Bb + 262144;

  const int tt_r = lane >> 3;          // timestep this lane reduces
  const int c0   = (lane & 7) << 3;    // its 8-state column base

  float h = 0.f;
  CBuf ca, cb;
  issue_chunk(0, ca, Bb, Cbp, dtp, xp, zsp, tt_r);   // 10 in flight
  issue_chunk(8, cb, Bb, Cbp, dtp, xp, zsp, tt_r);   // 20 in flight

  // Steady state per half: wait(10) retires the oldest 10 (this buffer's
  // chunk; in-order vmcnt retirement), compute it, re-issue into the freed
  // buffer. The y16 store adds <=1 transient vmcnt entry — wait(10) is
  // conservative-safe (waits at least until this chunk's loads land).
  for (int t0 = 0; t0 < 1024 - 16; t0 += 16) {
    SCAN_WAIT(10);
    compute_chunk(t0, ca, h, al2, dpv, Pw, lane, tt_r, c0, yp);
    issue_chunk(t0 + 16, ca, Bb, Cbp, dtp, xp, zsp, tt_r);
    SCAN_WAIT(10);
    compute_chunk(t0 + 8, cb, h, al2, dpv, Pw, lane, tt_r, c0, yp);
    issue_chunk(t0 + 24, cb, Bb, Cbp, dtp, xp, zsp, tt_r);  // t0+24 <= 1016
  }
  // tail: chunks 1008 (ca) and 1016 (cb) already issued
  SCAN_WAIT(10);
  compute_chunk(1008, ca, h, al2, dpv, Pw, lane, tt_r, c0, yp);
  SCAN_WAIT(0);
  compute_chunk(1016, cb, h, al2, dpv, Pw, lane, tt_r, c0, yp);
}

// ---------------------------------------------------------------------------
// Fused out_proj(l1)+fc head: only h[b, L-1, :] reaches the output.
// out[b,c] = (sum_di y16l1[b*1024+1023][di] * w2[c][di]) * 2^-14 + fc_b[c],
// w2[c][di] = sum_dm fc_w[c][dm] * out_w1[dm][di]   (fp32 weights).
// ---------------------------------------------------------------------------
__global__ void head2_kernel(const _Float16* __restrict__ y16,
                             const float* __restrict__ out_w1,  // [512][1024]
                             const float* __restrict__ fc_w,    // [3][512]
                             const float* __restrict__ fc_b,
                             float* __restrict__ out)
{
  __shared__ float red[4];
  const int bc = blockIdx.x;            // 0..11
  const int b = bc / 3, c = bc % 3;
  const int tid = threadIdx.x;
  const int lane = tid & 63, wv = tid >> 6;

  float4 w2 = make_float4(0.f, 0.f, 0.f, 0.f);
  const float* fcr = fc_w + c * 512;
  const float* owp = out_w1 + tid * 4;
  for (int dm = 0; dm < 512; ++dm) {
    float f = fcr[dm];
    float4 o = *(const float4*)(owp + (size_t)dm * 1024);
    w2.x = fmaf(f, o.x, w2.x); w2.y = fmaf(f, o.y, w2.y);
    w2.z = fmaf(f, o.z, w2.z); w2.w = fmaf(f, o.w, w2.w);
  }
  const _Float16* yr = y16 + ((size_t)(b * 1024 + 1023) << 10) + tid * 4;
  half4v yv = *(const half4v*)yr;
  float s = (float)yv[0] * w2.x + (float)yv[1] * w2.y
          + (float)yv[2] * w2.z + (float)yv[3] * w2.w;
  #pragma unroll
  for (int o = 32; o > 0; o >>= 1) s += __shfl_xor(s, o, 64);
  if (lane == 0) red[wv] = s;
  __syncthreads();
  if (tid == 0)
    out[b * 3 + c] = (red[0] + red[1] + red[2] + red[3]) * (1.f / Y_SCALE)
                     + fc_b[c];
}

extern "C" void kernel_launch(void* const* d_in, const int* in_sizes, int n_in,
                              void* d_out, int out_size, void* d_ws, size_t ws_size,
                              hipStream_t stream)
{
  const float* x        = (const float*)d_in[0];
  const float* exp_w    = (const float*)d_in[1];
  const float* exp_b    = (const float*)d_in[2];
  const float* in_w     = (const float*)d_in[3];
  const float* conv_w   = (const float*)d_in[4];
  const float* conv_b   = (const float*)d_in[5];
  const float* xproj_w  = (const float*)d_in[6];
  const float* dtproj_w = (const float*)d_in[7];
  const float* dtproj_b = (const float*)d_in[8];
  const float* A_log    = (const float*)d_in[9];
  const float* Dp       = (const float*)d_in[10];
  const float* out_w    = (const float*)d_in[11];
  const float* fc_w     = (const float*)d_in[12];
  const float* fc_b     = (const float*)d_in[13];
  float* out = (float*)d_out;

  // Workspace layout (byte offsets), 72 MB total.
  // 4..20 MB region sequentially reused: xcpre16 (8MB) -> dtT (16MB).
  char* ws = (char*)d_ws;
  _Float16* hf16    = (_Float16*)(ws);                        //  4 MB [4096][512] f16
  _Float16* xcpre16 = (_Float16*)(ws + ((size_t)4  << 20));   //  8 MB [4096][1024] f16
  float*    dtT     = (float*)   (ws + ((size_t)4  << 20));   // 16 MB [1024][4096] (reuse)
  float*    xcT     = (float*)   (ws + ((size_t)20 << 20));   // 16 MB [1024][4096]
  _Float16* zsT     = (_Float16*)(ws + ((size_t)36 << 20));   //  8 MB [1024][4096]
  float*    Bsc     = (float*)   (ws + ((size_t)44 << 20));   //  2 MB [4][256][64][4] B then C
  _Float16* dtr16   = (_Float16*)(ws + ((size_t)47 << 20));   //  0.25 MB [4096][32]
  _Float16* xc16    = (_Float16*)(ws + ((size_t)48 << 20));   //  8 MB [4096][1024]
  _Float16* y16     = (_Float16*)(ws + ((size_t)56 << 20));   //  8 MB [4096][1024]
  _Float16* w16     = (_Float16*)(ws + ((size_t)64 << 20));   //  7.9 MB f16 pool

  _Float16* exp16 = w16;                 // [512][128]
  _Float16* in16  = w16 + 65536;         // [2][2048][512]
  _Float16* xp16  = w16 + 2162688;       // [2][160][1024]
  _Float16* dt16  = w16 + 2490368;       // [2][1024][32]
  _Float16* out16 = w16 + 2555904;       // [2][512][1024]
  _Float16* x16   = w16 + 3604480;       // [4096][128]

  dim3 blk(256);

  // one-shot f16 conversion of all weights + x (4128768 elems, 4032 blocks)
  wcvt_kernel<<<4032, blk, 0, stream>>>(exp_w, in_w, xproj_w, dtproj_w, out_w,
                                        x, w16);

  // expand: hf16 = f16(x @ exp_w^T + exp_b)   [4096,512] K=128, BK=32.
  gemm_mfma<64,32,0,1,0><<<dim3(8,64), blk, 0, stream>>>(x16, 128, exp16, exp_b,
                                                         hf16, 512, 512, 128, 1.f,
                                                         nullptr);

  for (int l = 0; l < 2; ++l) {
    const float is = l ? (1.f / H1_SCALE) : 1.f;     // undo h1 scaling (exact)
    // fused in_proj: xcpre16 f16 + zsT f16 (Tz aliases Ws). N=2048 K=512 BK=64.
    gemm_mfma<128,64,0,0,1><<<dim3(16,64), blk, 0, stream>>>(hf16, 512,
                                                             in16 + (size_t)l*1048576,
                                                             nullptr, xcpre16, 1024,
                                                             2048, 512, is, zsT);
    // conv + silu -> xcT (fp32, scan) + xc16 (f16, xproj A)
    conv_t_kernel<<<1024, blk, 0, stream>>>(xcpre16, conv_w + l*2048, conv_b + l*1024,
                                            xcT, xc16);
    // xproj (MODE 2): dtr16 f16 [4096][32] + Bsc/Csc scan layout. K=1024 BK=64.
    gemm_mfma<64,64,0,0,2><<<dim3(3,64), blk, 0, stream>>>(xc16, 1024,
                                                           xp16 + (size_t)l*163840,
                                                           nullptr, Bsc, 160,
                                                           160, 1024, 1.f, dtr16);
    // dtproj (MODE 3): dtT [1024][4096] softplus, LDS-transposed. K=32 BK=32.
    gemm_mfma<64,32,0,0,3><<<dim3(16,64), blk, 0, stream>>>(dtr16, 32,
                                                            dt16 + (size_t)l*32768,
                                                            dtproj_b + l*1024,
                                                            dtT, 4096, 1024, 32, 1.f,
                                                            nullptr);
    // selective scan v4 (asm-VMEM counted-vmcnt pipeline)
    scan_kernel<<<1024, blk, 0, stream>>>(dtT, xcT, zsT, Bsc,
                                          A_log + (size_t)l*65536, Dp + l*1024, y16);
    // out_proj only for layer 0 (layer-1 h only matters at t=L-1 -> head2)
    if (l == 0)
      gemm_mfma<64,64,0,1,0><<<dim3(8,64), blk, 0, stream>>>(y16, 1024,
                                                             out16, nullptr,
                                                             hf16, 512, 512, 1024,
                                                             H1_SCALE / Y_SCALE,
                                                             nullptr);
  }

  // fused out_proj(l1) + fc head from y16(l1) directly (fp32 weights)
  head2_kernel<<<12, blk, 0, stream>>>(y16, out_w + (size_t)512*1024,
                                       fc_w, fc_b, out);
}

// Round 6
// 533.268 us; speedup vs baseline: 1.0159x; 1.0159x over previous
//
#include <hip/hip_runtime.h>
#include <math.h>

// Problem constants: B=4, L=1024, D_IN=128, D_MODEL=512, N_LAYERS=2,
// N_CLASSES=3, D_INNER=1024, D_STATE=64, D_CONV=2, DT_RANK=32, BL=4096.
//
// Precision plan: all GEMM operands f16 (conversions hoisted upstream).
// Layer-1 residual h f16 scaled by 2^8 (exact). y scaled by 2^14 at the
// scan store. Head works from y16(l1) directly with fp32 weights.
//
// R22: scan v5 — R21's regression (108->164us) was the y16 store entering
// the vmcnt stream: wait(10) forced completion of the just-issued scattered
// store every half-chunk. Fix: y buffered in per-wave LDS (lgkmcnt domain),
// flushed once at kernel end -> loop vmcnt stream is PURE LOADS and counted
// waits are exact (wait(9) retires exactly the chunk being computed).
// xvl load dropped (selected from uniform x regs via cndmask tree):
// 9 asm loads/chunk, 33 regs/buffer, ~104 VGPR peak (cap 128, 4 waves/SIMD).

using half8  = __attribute__((ext_vector_type(8))) _Float16;
using half4v = __attribute__((ext_vector_type(4))) _Float16;
using f32x4  = __attribute__((ext_vector_type(4))) float;

#define Y_SCALE 16384.0f   // 2^14
#define H1_SCALE 256.0f    // 2^8

__device__ __forceinline__ float silu_f(float v) {
  return v / (1.f + __expf(-v));
}

__device__ __forceinline__ float fast_exp2(float x) {
#if __has_builtin(__builtin_amdgcn_exp2f)
  return __builtin_amdgcn_exp2f(x);
#else
  return __expf(x * 0.69314718055994531f);
#endif
}

// ---------------------------------------------------------------------------
// One-shot fp32 -> f16 conversion of all weights + x into the w16 pool.
//   exp_w 0..65536 | in_w ..2162688 | xproj_w ..2490368 | dtproj_w ..2555904
//   | out_w ..3604480 | x ..4128768
// ---------------------------------------------------------------------------
__global__ void wcvt_kernel(const float* __restrict__ exp_w,
                            const float* __restrict__ in_w,
                            const float* __restrict__ xproj_w,
                            const float* __restrict__ dtproj_w,
                            const float* __restrict__ out_w,
                            const float* __restrict__ x,
                            _Float16* __restrict__ w16)
{
  size_t gi = ((size_t)blockIdx.x * 256 + threadIdx.x) * 4;
  const float* src; size_t off;
  if      (gi < 65536)   { src = exp_w;    off = gi; }
  else if (gi < 2162688) { src = in_w;     off = gi - 65536; }
  else if (gi < 2490368) { src = xproj_w;  off = gi - 2162688; }
  else if (gi < 2555904) { src = dtproj_w; off = gi - 2490368; }
  else if (gi < 3604480) { src = out_w;    off = gi - 2555904; }
  else                   { src = x;        off = gi - 3604480; }
  float4 v = *(const float4*)(src + off);
  half4v h;
  h[0] = (_Float16)v.x; h[1] = (_Float16)v.y;
  h[2] = (_Float16)v.z; h[3] = (_Float16)v.w;
  *(half4v*)(w16 + gi) = h;
}

// ---------------------------------------------------------------------------
// f16 MFMA GEMM, 64 x BN tile, BK-chunk K-loop. Block 256 thr = 4 waves;
// wave-tile 32 x (BN/2), MI=2 m-frags. BK in {32,64}.
// Modes: 0 plain / 1 in_proj fused (REQUIRES BK=64, BN=128; Tz aliases Ws) /
// 2 xproj split (dtr16 + Bsc/Csc scan layout) / 3 dtproj transposed-softplus.
// MFMA layouts (m89/m120-verified): A-frag A[m=lane&15][k=q*8+j],
// B-frag B[k=q*8+j][n=lane&15], D: col(n)=lane&15, row(m)=q*4+r.
// ---------------------------------------------------------------------------
template<int BN, int BK, int ACT, int OF16, int MODE>
__global__ __launch_bounds__(256)
void gemm_mfma(const _Float16* __restrict__ A, int lda,
               const _Float16* __restrict__ W,
               const float* __restrict__ bias,
               void* __restrict__ Cv, int ldc,
               int N, int K, float oscale,
               void* __restrict__ Cv2)
{
  static_assert(MODE != 1 || (BK == 64 && BN == 128), "MODE1 needs BK=64/BN=128");
  constexpr int NF  = BN / 32;           // n-frags per wave
  constexpr int LS  = BK + 8;            // LDS row stride in halfs (16B-aligned)
  constexpr int NA  = BK / 32;           // A half8 regs per thread
  constexpr int WTR = 256 / BN;          // threads per W row
  constexpr int WH  = BK / WTR;          // W halfs per thread (R18b fix)
  constexpr int NW  = WH / 8;            // W half8 regs per thread
  static_assert(NA >= 1 && NW >= 1, "staging arithmetic");

  __shared__ _Float16 As[64 * LS];
  __shared__ _Float16 Ws[BN * LS];       // MODE1: reused as Tz in epilogue
  __shared__ float    Td[(MODE == 3) ? 64 * 68 : 2];
  const int tid  = threadIdx.x;
  const int lane = tid & 63;
  const int wid  = tid >> 6;
  const int wm   = wid & 1, wn = wid >> 1;   // wave-tile: 32 m x BN/2 n
  const int m0   = blockIdx.y * 64;
  const int n0   = blockIdx.x * BN;
  const int q    = lane >> 4, l16 = lane & 15;

  // staging coords
  const int ar  = tid >> 2;                  // A: 4 thr/row
  const int akq = (tid & 3) * (BK / 4);
  const int wr  = tid / WTR;
  const int wkq = (tid % WTR) * WH;
  const int wrow = n0 + wr;
  const bool wv  = (wrow < N);

  const _Float16* Wp = W + (size_t)wrow * K;
  const size_t aoff = (size_t)(m0 + ar) * lda + akq;

  half8 zh;
  #pragma unroll
  for (int i = 0; i < 8; ++i) zh[i] = (_Float16)0.f;

  // initial loads (k0 = 0)
  half8 rah[NA], rwh[NW];
  #pragma unroll
  for (int i = 0; i < NA; ++i) rah[i] = *(const half8*)(A + aoff + i * 8);
  #pragma unroll
  for (int j = 0; j < NW; ++j)
    rwh[j] = wv ? *(const half8*)(Wp + wkq + j * 8) : zh;

  f32x4 acc[2][NF];
  #pragma unroll
  for (int mi = 0; mi < 2; ++mi)
    #pragma unroll
    for (int ni = 0; ni < NF; ++ni)
      acc[mi][ni] = (f32x4){0.f, 0.f, 0.f, 0.f};

  for (int k0 = 0; k0 < K; k0 += BK) {
    if (k0) __syncthreads();
    #pragma unroll
    for (int i = 0; i < NA; ++i)
      *(half8*)&As[ar * LS + akq + i * 8] = rah[i];
    #pragma unroll
    for (int j = 0; j < NW; ++j)
      *(half8*)&Ws[wr * LS + wkq + j * 8] = rwh[j];
    __syncthreads();

    if (k0 + BK < K) {            // prefetch next chunk
      const int kn = k0 + BK;
      #pragma unroll
      for (int i = 0; i < NA; ++i)
        rah[i] = *(const half8*)(A + aoff + kn + i * 8);
      if (wv) {
        #pragma unroll
        for (int j = 0; j < NW; ++j)
          rwh[j] = *(const half8*)(Wp + kn + wkq + j * 8);
      }
    }

    #pragma unroll
    for (int kk = 0; kk < BK / 32; ++kk) {
      half8 af[2], wf[NF];
      #pragma unroll
      for (int mi = 0; mi < 2; ++mi)
        af[mi] = *(const half8*)&As[(wm * 32 + mi * 16 + l16) * LS + kk * 32 + q * 8];
      #pragma unroll
      for (int ni = 0; ni < NF; ++ni)
        wf[ni] = *(const half8*)&Ws[(wn * (BN / 2) + ni * 16 + l16) * LS + kk * 32 + q * 8];
      #pragma unroll
      for (int mi = 0; mi < 2; ++mi)
        #pragma unroll
        for (int ni = 0; ni < NF; ++ni)
          acc[mi][ni] = __builtin_amdgcn_mfma_f32_16x16x32_f16(af[mi], wf[ni],
                                                               acc[mi][ni], 0, 0, 0);
    }
  }

  float*    Cf = (float*)Cv;
  _Float16* Ch = (_Float16*)Cv;

  if (MODE == 1) {
    if (n0 < 1024) {
      // xc half: f16 [M][1024]
      #pragma unroll
      for (int ni = 0; ni < NF; ++ni) {
        const int n = n0 + wn * (BN / 2) + ni * 16 + l16;
        #pragma unroll
        for (int mi = 0; mi < 2; ++mi) {
          const int mb = m0 + wm * 32 + mi * 16 + q * 4;
          #pragma unroll
          for (int r = 0; r < 4; ++r)
            Ch[(size_t)(mb + r) * 1024 + n] = (_Float16)(acc[mi][ni][r] * oscale);
        }
      }
    } else {
      // z half: silu -> f16, LDS transpose (Tz aliases Ws; LS==72),
      // coalesced 16B row stores
      _Float16* Tz = Ws;
      _Float16* Ch2 = (_Float16*)Cv2;
      __syncthreads();                  // all MFMA reads of Ws done
      #pragma unroll
      for (int ni = 0; ni < NF; ++ni) {
        const int nnl = wn * (BN / 2) + ni * 16 + l16;   // 0..127 local
        #pragma unroll
        for (int mi = 0; mi < 2; ++mi) {
          const int mbl = wm * 32 + mi * 16 + q * 4;     // 0..63 local
          half4v h4;
          #pragma unroll
          for (int r = 0; r < 4; ++r)
            h4[r] = (_Float16)silu_f(acc[mi][ni][r] * oscale);
          *(half4v*)&Tz[nnl * LS + mbl] = h4;
        }
      }
      __syncthreads();
      const int sr = tid >> 3;          // 0..31
      const int sc = (tid & 7) * 8;     // halfs 0..56
      #pragma unroll
      for (int rd = 0; rd < 4; ++rd) {
        const int row = rd * 32 + sr;
        half8 v = *(const half8*)&Tz[row * LS + sc];
        *(half8*)&Ch2[(size_t)(n0 - 1024 + row) * 4096 + m0 + sc] = v;
      }
    }
    return;
  }

  if (MODE == 2) {
    // xproj split:
    //   n <  32           -> dtr16 f16 [M][32]           (via Cv2)
    //   32 <= n <  96     -> Bsc scan layout             (via Cv)
    //   96 <= n < 160     -> Csc = Bsc + 262144
    // Scan layout: [b*256 + t/4][s 0..63][t&3] fp32. mb%4==0 so the 4 acc
    // components (rows mb..mb+3) form one contiguous float4 at s*4.
    float* Bs = Cf;
    _Float16* dtr = (_Float16*)Cv2;
    #pragma unroll
    for (int ni = 0; ni < NF; ++ni) {
      const int n = n0 + wn * (BN / 2) + ni * 16 + l16;
      #pragma unroll
      for (int mi = 0; mi < 2; ++mi) {
        const int mb = m0 + wm * 32 + mi * 16 + q * 4;
        if (n < 32) {
          #pragma unroll
          for (int r = 0; r < 4; ++r)
            dtr[(size_t)(mb + r) * 32 + n] = (_Float16)acc[mi][ni][r];
        } else if (n < 160) {
          const int s = (n < 96) ? (n - 32) : (n - 96);
          float* dst = Bs + ((n < 96) ? 0 : 262144);
          float4 v = make_float4(acc[mi][ni][0], acc[mi][ni][1],
                                 acc[mi][ni][2], acc[mi][ni][3]);
          *(float4*)&dst[((size_t)(mb >> 2) << 8) + s * 4] = v;
        }
      }
    }
    return;
  }

  if (MODE == 3) {
    // dtproj: softplus(acc*oscale + bias) -> fp32 [N][4096] via LDS transpose
    __syncthreads();
    #pragma unroll
    for (int ni = 0; ni < NF; ++ni) {
      const int nnl = wn * (BN / 2) + ni * 16 + l16;     // 0..63 local
      const float bv = (bias != nullptr) ? bias[n0 + nnl] : 0.f;
      #pragma unroll
      for (int mi = 0; mi < 2; ++mi) {
        const int mbl = wm * 32 + mi * 16 + q * 4;       // 0..63 local
        float o[4];
        #pragma unroll
        for (int r = 0; r < 4; ++r) {
          float v = acc[mi][ni][r] * oscale + bv;
          o[r] = (v > 20.f) ? v : log1pf(__expf(v));     // softplus
        }
        *(float4*)&Td[nnl * 68 + mbl] = make_float4(o[0], o[1], o[2], o[3]);
      }
    }
    __syncthreads();
    const int sr = tid >> 4;            // 0..15
    const int sc = (tid & 15) * 4;      // floats 0..60
    #pragma unroll
    for (int rd = 0; rd < 4; ++rd) {
      const int row = rd * 16 + sr;
      float4 v = *(const float4*)&Td[row * 68 + sc];
      *(float4*)&Cf[(size_t)(n0 + row) * 4096 + m0 + sc] = v;
    }
    return;
  }

  // MODE 0 epilogue
  #pragma unroll
  for (int ni = 0; ni < NF; ++ni) {
    const int n = n0 + wn * (BN / 2) + ni * 16 + l16;
    if (n < N) {
      const float bv = (bias != nullptr) ? bias[n] : 0.f;
      #pragma unroll
      for (int mi = 0; mi < 2; ++mi) {
        const int mb = m0 + wm * 32 + mi * 16 + q * 4;
        #pragma unroll
        for (int r = 0; r < 4; ++r) {
          float v = acc[mi][ni][r] * oscale + bv;
          if (ACT == 1) v = (v > 20.f) ? v : log1pf(__expf(v));
          if (ACT == 2) v = silu_f(v);
          size_t off = (size_t)(mb + r) * ldc + n;
          if (OF16) Ch[off] = (_Float16)v;
          else      Cf[off] = v;
        }
      }
    }
  }
}

// ---------------------------------------------------------------------------
// Depthwise causal conv (D_CONV=2) + silu, 64x64 LDS transpose.
// in : xcp [4096 bl][1024 d] f16
// out: xcT [1024 d][4096 bl] fp32 (scan input)  +  xcf [4096 bl][1024 d] f16
// ---------------------------------------------------------------------------
__global__ void conv_t_kernel(const _Float16* __restrict__ xcp,
                              const float* __restrict__ cw,   // [1024][2]
                              const float* __restrict__ cb,   // [1024]
                              float* __restrict__ xcT,
                              _Float16* __restrict__ xcf)
{
  __shared__ float tile[64][65];
  const int blk = blockIdx.x;            // b*256 + tt*16 + dd
  const int b  = blk >> 8;
  const int tt = (blk >> 4) & 15;
  const int dd = blk & 15;
  const int t0 = tt * 64, d0 = dd * 64;
  const int tid = threadIdx.x;

  #pragma unroll
  for (int i = 0; i < 16; ++i) {
    int idx = i * 256 + tid;
    int t = idx >> 6, d = idx & 63;
    int gt = t0 + t;
    size_t rcur = ((size_t)(b * 1024 + gt) << 10) + d0 + d;
    float cur  = (float)xcp[rcur];
    float prev = (gt > 0) ? (float)xcp[rcur - 1024] : 0.f;
    float v = fmaf(prev, cw[(d0+d)*2], fmaf(cur, cw[(d0+d)*2 + 1], cb[d0+d]));
    float sv = silu_f(v);
    tile[t][d] = sv;
    xcf[rcur] = (_Float16)sv;
  }
  __syncthreads();
  #pragma unroll
  for (int i = 0; i < 16; ++i) {
    int idx = i * 256 + tid;
    int d = idx >> 6, t = idx & 63;
    xcT[((size_t)(d0 + d) << 12) + b * 1024 + t0 + t] = tile[t][d];
  }
}

// ---------------------------------------------------------------------------
// Selective scan v5, time-major. One wave per (b,d), lane = s (D_STATE=64).
// Chunk = 8 timesteps; two register buffers filled by inline-asm VMEM
// (volatile => issue order immutable). Loop vmcnt stream = PURE LOADS
// (y buffered in per-wave LDS, flushed at end) so counted waits are exact:
// 18 loads in flight, wait(9) retires exactly the chunk being computed.
// xvl selected from uniform x regs (cndmask tree) instead of a 10th load.
// ---------------------------------------------------------------------------
struct CBuf {
  f32x4 B0, B1, C0, C1, d0, d1, x0, x1;   // 32 VGPRs
  unsigned zsu;                            // f16 payload of silu(z)[t0+tt_r]
};

__device__ __forceinline__ void issue_chunk(int t0, CBuf& c,
    const float* Bb, const float* Cbp,
    const float* dtp, const float* xp,
    const _Float16* zsp, int tt_r)
{
  const float* Bp = Bb  + ((size_t)((unsigned)t0 >> 2) << 8);   // t0*64 floats
  const float* Cp = Cbp + ((size_t)((unsigned)t0 >> 2) << 8);
  // 9 VMEM loads, program-ordered (asm volatile). SIInsertWaitcnts does not
  // model these; OUR counted waits are the only gates. offset: immediates
  // reuse one address pair per stream.
  asm volatile("global_load_dwordx4 %0, %1, off"             : "=v"(c.B0) : "v"(Bp));
  asm volatile("global_load_dwordx4 %0, %1, off offset:1024" : "=v"(c.B1) : "v"(Bp));
  asm volatile("global_load_dwordx4 %0, %1, off"             : "=v"(c.C0) : "v"(Cp));
  asm volatile("global_load_dwordx4 %0, %1, off offset:1024" : "=v"(c.C1) : "v"(Cp));
  asm volatile("global_load_dwordx4 %0, %1, off"             : "=v"(c.d0) : "v"(dtp + t0));
  asm volatile("global_load_dwordx4 %0, %1, off offset:16"   : "=v"(c.d1) : "v"(dtp + t0));
  asm volatile("global_load_dwordx4 %0, %1, off"             : "=v"(c.x0) : "v"(xp + t0));
  asm volatile("global_load_dwordx4 %0, %1, off offset:16"   : "=v"(c.x1) : "v"(xp + t0));
  asm volatile("global_load_ushort %0, %1, off"              : "=v"(c.zsu) : "v"(zsp + t0 + tt_r));
}

// wait until at most N of our VMEM loads remain in flight, then fence the
// scheduler so no use of the waited-on registers can hoist above (rule #18).
#define SCAN_WAIT(N) do {                                   \
    asm volatile("s_waitcnt vmcnt(" #N ")" ::: "memory");   \
    __builtin_amdgcn_sched_barrier(0);                      \
  } while (0)

__device__ __forceinline__ void compute_chunk(int t0, const CBuf& c, float& h,
    float al2, float dpv, float (*Pw)[68], _Float16* ybw,
    int lane, int tt_r, int c0)
{
  float dvv[8] = {c.d0[0], c.d0[1], c.d0[2], c.d0[3],
                  c.d1[0], c.d1[1], c.d1[2], c.d1[3]};
  float xvv[8] = {c.x0[0], c.x0[1], c.x0[2], c.x0[3],
                  c.x1[0], c.x1[1], c.x1[2], c.x1[3]};
  float Bvv[8] = {c.B0[0], c.B0[1], c.B0[2], c.B0[3],
                  c.B1[0], c.B1[1], c.B1[2], c.B1[3]};
  float Cvv[8] = {c.C0[0], c.C0[1], c.C0[2], c.C0[3],
                  c.C1[0], c.C1[1], c.C1[2], c.C1[3]};
  // xvl = x[t0 + tt_r]: dt/x loads are wave-uniform, so every lane holds all
  // 8 x values -> 7-cndmask selection tree instead of a dedicated load.
  const float xvl = (tt_r & 4)
      ? ((tt_r & 2) ? ((tt_r & 1) ? xvv[7] : xvv[6])
                    : ((tt_r & 1) ? xvv[5] : xvv[4]))
      : ((tt_r & 2) ? ((tt_r & 1) ? xvv[3] : xvv[2])
                    : ((tt_r & 1) ? xvv[1] : xvv[0]));
  const float zs = (float)__builtin_bit_cast(_Float16,
                     (unsigned short)(c.zsu & 0xffffu)) * Y_SCALE;
  // parallel phase: everything h-independent
  float dA[8], ub[8];
  #pragma unroll
  for (int tt = 0; tt < 8; ++tt) {
    dA[tt] = fast_exp2(dvv[tt] * al2);
    ub[tt] = dvv[tt] * xvv[tt] * Bvv[tt];
  }
  // serial recurrence: fma -> mul -> ds_write per t
  #pragma unroll
  for (int tt = 0; tt < 8; ++tt) {
    h = fmaf(h, dA[tt], ub[tt]);
    Pw[tt][lane] = h * Cvv[tt];
  }
  // batched reduction: lane L sums 8 states of timestep L>>3
  float4 s0 = *(const float4*)&Pw[tt_r][c0];
  float4 s1 = *(const float4*)&Pw[tt_r][c0 + 4];
  float r = ((s0.x + s0.y) + (s0.z + s0.w)) + ((s1.x + s1.y) + (s1.z + s1.w));
  r += __shfl_xor(r, 1, 64);
  r += __shfl_xor(r, 2, 64);
  r += __shfl_xor(r, 4, 64);
  // y -> per-wave LDS (lgkmcnt domain; keeps the vmcnt stream load-only)
  if ((lane & 7) == 0)
    ybw[t0 + tt_r] = (_Float16)(fmaf(xvl, dpv, r) * zs);
}

__global__ __launch_bounds__(256, 4)   // VGPR cap 128: keep 4 waves/SIMD
void scan_kernel(const float* __restrict__ dtT,     // [1024][4096]
                 const float* __restrict__ xcT,     // [1024][4096]
                 const _Float16* __restrict__ zsT,  // [1024][4096], silu(z), f16
                 const float* __restrict__ Bsc,     // [4][256][64][4]; Csc at +262144
                 const float* __restrict__ A_log,   // [1024][64]
                 const float* __restrict__ Dp,      // [1024]
                 _Float16* __restrict__ y16)        // [4096 bl][1024 d], y*2^14
{
  __shared__ float    P[4][8][68];     // per-wave reduction tile (wave-private)
  __shared__ _Float16 yb[4][1024];     // per-wave y buffer (flushed at end)
  const int tid  = threadIdx.x;
  const int lane = tid & 63;
  const int wrp  = tid >> 6;
  const int rb   = blockIdx.x;
  const int bswz = ((rb & 7) << 7) | (rb >> 3);          // XCD swizzle
  const int wid  = __builtin_amdgcn_readfirstlane(bswz * 4 + wrp);
  const int b = wid >> 10;
  const int d = wid & 1023;
  float (*Pw)[68] = P[wrp];
  _Float16* ybw   = yb[wrp];

  const float a   = -__expf(A_log[d * 64 + lane]);
  const float al2 = a * 1.44269504088896f;               // hoisted log2(e)
  const float dpv = Dp[d];
  // pin prologue loads: forces the compiler's auto vmcnt wait for Dp/A_log
  // to land HERE (pre-loop), not inside the loop where it would drain our
  // asm pipeline every iteration.
  asm volatile("" :: "v"(dpv), "v"(al2));
  const size_t row = ((size_t)d << 12) + b * 1024;
  const float*    dtp = dtT + row;
  const float*    xp  = xcT + row;
  const _Float16* zsp = zsT + row;
  _Float16*       yp  = y16 + ((size_t)b << 20) + d;     // + t*1024
  const float*    Bb  = Bsc + ((size_t)b << 16) + lane * 4;
  const float*    Cbp = Bb + 262144;

  const int tt_r = lane >> 3;          // timestep this lane reduces
  const int c0   = (lane & 7) << 3;    // its 8-state column base

  float h = 0.f;
  CBuf ca, cb;
  issue_chunk(0, ca, Bb, Cbp, dtp, xp, zsp, tt_r);   //  9 in flight
  issue_chunk(8, cb, Bb, Cbp, dtp, xp, zsp, tt_r);   // 18 in flight

  // Steady state per half: wait(9) retires the oldest 9 (this buffer's
  // chunk; in-order vmcnt retirement; no stores in the stream), compute it
  // (LDS/VALU only), re-issue into the freed buffer.
  for (int t0 = 0; t0 < 1024 - 16; t0 += 16) {
    SCAN_WAIT(9);
    compute_chunk(t0, ca, h, al2, dpv, Pw, ybw, lane, tt_r, c0);
    issue_chunk(t0 + 16, ca, Bb, Cbp, dtp, xp, zsp, tt_r);
    SCAN_WAIT(9);
    compute_chunk(t0 + 8, cb, h, al2, dpv, Pw, ybw, lane, tt_r, c0);
    issue_chunk(t0 + 24, cb, Bb, Cbp, dtp, xp, zsp, tt_r);  // t0+24 <= 1016
  }
  // tail: chunks 1008 (ca) and 1016 (cb) already issued
  SCAN_WAIT(9);
  compute_chunk(1008, ca, h, al2, dpv, Pw, ybw, lane, tt_r, c0);
  SCAN_WAIT(0);
  compute_chunk(1016, cb, h, al2, dpv, Pw, ybw, lane, tt_r, c0);

  // flush y row (wave-private LDS, DS ops wave-ordered -> no barrier)
  #pragma unroll
  for (int i = 0; i < 16; ++i) {
    const int t = i * 64 + lane;
    yp[(size_t)t << 10] = ybw[t];
  }
}

// ---------------------------------------------------------------------------
// Fused out_proj(l1)+fc head: only h[b, L-1, :] reaches the output.
// out[b,c] = (sum_di y16l1[b*1024+1023][di] * w2[c][di]) * 2^-14 + fc_b[c],
// w2[c][di] = sum_dm fc_w[c][dm] * out_w1[dm][di]   (fp32 weights).
// ---------------------------------------------------------------------------
__global__ void head2_kernel(const _Float16* __restrict__ y16,
                             const float* __restrict__ out_w1,  // [512][1024]
                             const float* __restrict__ fc_w,    // [3][512]
                             const float* __restrict__ fc_b,
                             float* __restrict__ out)
{
  __shared__ float red[4];
  const int bc = blockIdx.x;            // 0..11
  const int b = bc / 3, c = bc % 3;
  const int tid = threadIdx.x;
  const int lane = tid & 63, wv = tid >> 6;

  float4 w2 = make_float4(0.f, 0.f, 0.f, 0.f);
  const float* fcr = fc_w + c * 512;
  const float* owp = out_w1 + tid * 4;
  for (int dm = 0; dm < 512; ++dm) {
    float f = fcr[dm];
    float4 o = *(const float4*)(owp + (size_t)dm * 1024);
    w2.x = fmaf(f, o.x, w2.x); w2.y = fmaf(f, o.y, w2.y);
    w2.z = fmaf(f, o.z, w2.z); w2.w = fmaf(f, o.w, w2.w);
  }
  const _Float16* yr = y16 + ((size_t)(b * 1024 + 1023) << 10) + tid * 4;
  half4v yv = *(const half4v*)yr;
  float s = (float)yv[0] * w2.x + (float)yv[1] * w2.y
          + (float)yv[2] * w2.z + (float)yv[3] * w2.w;
  #pragma unroll
  for (int o = 32; o > 0; o >>= 1) s += __shfl_xor(s, o, 64);
  if (lane == 0) red[wv] = s;
  __syncthreads();
  if (tid == 0)
    out[b * 3 + c] = (red[0] + red[1] + red[2] + red[3]) * (1.f / Y_SCALE)
                     + fc_b[c];
}

extern "C" void kernel_launch(void* const* d_in, const int* in_sizes, int n_in,
                              void* d_out, int out_size, void* d_ws, size_t ws_size,
                              hipStream_t stream)
{
  const float* x        = (const float*)d_in[0];
  const float* exp_w    = (const float*)d_in[1];
  const float* exp_b    = (const float*)d_in[2];
  const float* in_w     = (const float*)d_in[3];
  const float* conv_w   = (const float*)d_in[4];
  const float* conv_b   = (const float*)d_in[5];
  const float* xproj_w  = (const float*)d_in[6];
  const float* dtproj_w = (const float*)d_in[7];
  const float* dtproj_b = (const float*)d_in[8];
  const float* A_log    = (const float*)d_in[9];
  const float* Dp       = (const float*)d_in[10];
  const float* out_w    = (const float*)d_in[11];
  const float* fc_w     = (const float*)d_in[12];
  const float* fc_b     = (const float*)d_in[13];
  float* out = (float*)d_out;

  // Workspace layout (byte offsets), 72 MB total.
  // 4..20 MB region sequentially reused: xcpre16 (8MB) -> dtT (16MB).
  char* ws = (char*)d_ws;
  _Float16* hf16    = (_Float16*)(ws);                        //  4 MB [4096][512] f16
  _Float16* xcpre16 = (_Float16*)(ws + ((size_t)4  << 20));   //  8 MB [4096][1024] f16
  float*    dtT     = (float*)   (ws + ((size_t)4  << 20));   // 16 MB [1024][4096] (reuse)
  float*    xcT     = (float*)   (ws + ((size_t)20 << 20));   // 16 MB [1024][4096]
  _Float16* zsT     = (_Float16*)(ws + ((size_t)36 << 20));   //  8 MB [1024][4096]
  float*    Bsc     = (float*)   (ws + ((size_t)44 << 20));   //  2 MB [4][256][64][4] B then C
  _Float16* dtr16   = (_Float16*)(ws + ((size_t)47 << 20));   //  0.25 MB [4096][32]
  _Float16* xc16    = (_Float16*)(ws + ((size_t)48 << 20));   //  8 MB [4096][1024]
  _Float16* y16     = (_Float16*)(ws + ((size_t)56 << 20));   //  8 MB [4096][1024]
  _Float16* w16     = (_Float16*)(ws + ((size_t)64 << 20));   //  7.9 MB f16 pool

  _Float16* exp16 = w16;                 // [512][128]
  _Float16* in16  = w16 + 65536;         // [2][2048][512]
  _Float16* xp16  = w16 + 2162688;       // [2][160][1024]
  _Float16* dt16  = w16 + 2490368;       // [2][1024][32]
  _Float16* out16 = w16 + 2555904;       // [2][512][1024]
  _Float16* x16   = w16 + 3604480;       // [4096][128]

  dim3 blk(256);

  // one-shot f16 conversion of all weights + x (4128768 elems, 4032 blocks)
  wcvt_kernel<<<4032, blk, 0, stream>>>(exp_w, in_w, xproj_w, dtproj_w, out_w,
                                        x, w16);

  // expand: hf16 = f16(x @ exp_w^T + exp_b)   [4096,512] K=128, BK=32.
  gemm_mfma<64,32,0,1,0><<<dim3(8,64), blk, 0, stream>>>(x16, 128, exp16, exp_b,
                                                         hf16, 512, 512, 128, 1.f,
                                                         nullptr);

  for (int l = 0; l < 2; ++l) {
    const float is = l ? (1.f / H1_SCALE) : 1.f;     // undo h1 scaling (exact)
    // fused in_proj: xcpre16 f16 + zsT f16 (Tz aliases Ws). N=2048 K=512 BK=64.
    gemm_mfma<128,64,0,0,1><<<dim3(16,64), blk, 0, stream>>>(hf16, 512,
                                                             in16 + (size_t)l*1048576,
                                                             nullptr, xcpre16, 1024,
                                                             2048, 512, is, zsT);
    // conv + silu -> xcT (fp32, scan) + xc16 (f16, xproj A)
    conv_t_kernel<<<1024, blk, 0, stream>>>(xcpre16, conv_w + l*2048, conv_b + l*1024,
                                            xcT, xc16);
    // xproj (MODE 2): dtr16 f16 [4096][32] + Bsc/Csc scan layout. K=1024 BK=64.
    gemm_mfma<64,64,0,0,2><<<dim3(3,64), blk, 0, stream>>>(xc16, 1024,
                                                           xp16 + (size_t)l*163840,
                                                           nullptr, Bsc, 160,
                                                           160, 1024, 1.f, dtr16);
    // dtproj (MODE 3): dtT [1024][4096] softplus, LDS-transposed. K=32 BK=32.
    gemm_mfma<64,32,0,0,3><<<dim3(16,64), blk, 0, stream>>>(dtr16, 32,
                                                            dt16 + (size_t)l*32768,
                                                            dtproj_b + l*1024,
                                                            dtT, 4096, 1024, 32, 1.f,
                                                            nullptr);
    // selective scan v5 (pure-load vmcnt pipeline, LDS y-flush)
    scan_kernel<<<1024, blk, 0, stream>>>(dtT, xcT, zsT, Bsc,
                                          A_log + (size_t)l*65536, Dp + l*1024, y16);
    // out_proj only for layer 0 (layer-1 h only matters at t=L-1 -> head2)
    if (l == 0)
      gemm_mfma<64,64,0,1,0><<<dim3(8,64), blk, 0, stream>>>(y16, 1024,
                                                             out16, nullptr,
                                                             hf16, 512, 512, 1024,
                                                             H1_SCALE / Y_SCALE,
                                                             nullptr);
  }

  // fused out_proj(l1) + fc head from y16(l1) directly (fp32 weights)
  head2_kernel<<<12, blk, 0, stream>>>(y16, out_w + (size_t)512*1024,
                                       fc_w, fc_b, out);
}

// Round 7
// 531.385 us; speedup vs baseline: 1.0195x; 1.0035x over previous
//
#include <hip/hip_runtime.h>
#include <math.h>

// Problem constants: B=4, L=1024, D_IN=128, D_MODEL=512, N_LAYERS=2,
// N_CLASSES=3, D_INNER=1024, D_STATE=64, D_CONV=2, DT_RANK=32, BL=4096.
//
// Precision plan: all GEMM operands f16 (conversions hoisted upstream).
// Layer-1 residual h f16 scaled by 2^8 (exact). y scaled by 2^14 at the
// scan store. Head works from y16(l1) directly with fp32 weights.
//
// R23: scan v6 — R21/R22 identical timing proved the per-wave asm-VMEM
// pipeline is the wrong structure; the real cost is 4x-redundant B/C L2
// traffic (2 GB/dispatch: every d-wave re-reads the full (b,t,s) stream)
// plus convoy waits. New structure (m201-verified pattern): block = (b,
// 4 d's); B/C chunk staged ONCE per block into double-buffered LDS via
// global_load_lds; dt/x/zs staged async into a per-wave LDS slot. Loop has
// ZERO compiler VMEM: 2 async ops/chunk/wave, counted s_waitcnt vmcnt(2),
// raw s_barrier x2 per chunk. Compute reads LDS via normal loads.

using half8  = __attribute__((ext_vector_type(8))) _Float16;
using half4v = __attribute__((ext_vector_type(4))) _Float16;
using f32x4  = __attribute__((ext_vector_type(4))) float;

#define Y_SCALE 16384.0f   // 2^14
#define H1_SCALE 256.0f    // 2^8

__device__ __forceinline__ float silu_f(float v) {
  return v / (1.f + __expf(-v));
}

__device__ __forceinline__ float fast_exp2(float x) {
#if __has_builtin(__builtin_amdgcn_exp2f)
  return __builtin_amdgcn_exp2f(x);
#else
  return __expf(x * 0.69314718055994531f);
#endif
}

// ---------------------------------------------------------------------------
// One-shot fp32 -> f16 conversion of all weights + x into the w16 pool.
//   exp_w 0..65536 | in_w ..2162688 | xproj_w ..2490368 | dtproj_w ..2555904
//   | out_w ..3604480 | x ..4128768
// ---------------------------------------------------------------------------
__global__ void wcvt_kernel(const float* __restrict__ exp_w,
                            const float* __restrict__ in_w,
                            const float* __restrict__ xproj_w,
                            const float* __restrict__ dtproj_w,
                            const float* __restrict__ out_w,
                            const float* __restrict__ x,
                            _Float16* __restrict__ w16)
{
  size_t gi = ((size_t)blockIdx.x * 256 + threadIdx.x) * 4;
  const float* src; size_t off;
  if      (gi < 65536)   { src = exp_w;    off = gi; }
  else if (gi < 2162688) { src = in_w;     off = gi - 65536; }
  else if (gi < 2490368) { src = xproj_w;  off = gi - 2162688; }
  else if (gi < 2555904) { src = dtproj_w; off = gi - 2490368; }
  else if (gi < 3604480) { src = out_w;    off = gi - 2555904; }
  else                   { src = x;        off = gi - 3604480; }
  float4 v = *(const float4*)(src + off);
  half4v h;
  h[0] = (_Float16)v.x; h[1] = (_Float16)v.y;
  h[2] = (_Float16)v.z; h[3] = (_Float16)v.w;
  *(half4v*)(w16 + gi) = h;
}

// ---------------------------------------------------------------------------
// f16 MFMA GEMM, 64 x BN tile, BK-chunk K-loop. Block 256 thr = 4 waves;
// wave-tile 32 x (BN/2), MI=2 m-frags. BK in {32,64}.
// Modes: 0 plain / 1 in_proj fused (REQUIRES BK=64, BN=128; Tz aliases Ws) /
// 2 xproj split (dtr16 + Bsc/Csc scan layout) / 3 dtproj transposed-softplus.
// MFMA layouts (m89/m120-verified): A-frag A[m=lane&15][k=q*8+j],
// B-frag B[k=q*8+j][n=lane&15], D: col(n)=lane&15, row(m)=q*4+r.
// ---------------------------------------------------------------------------
template<int BN, int BK, int ACT, int OF16, int MODE>
__global__ __launch_bounds__(256)
void gemm_mfma(const _Float16* __restrict__ A, int lda,
               const _Float16* __restrict__ W,
               const float* __restrict__ bias,
               void* __restrict__ Cv, int ldc,
               int N, int K, float oscale,
               void* __restrict__ Cv2)
{
  static_assert(MODE != 1 || (BK == 64 && BN == 128), "MODE1 needs BK=64/BN=128");
  constexpr int NF  = BN / 32;           // n-frags per wave
  constexpr int LS  = BK + 8;            // LDS row stride in halfs (16B-aligned)
  constexpr int NA  = BK / 32;           // A half8 regs per thread
  constexpr int WTR = 256 / BN;          // threads per W row
  constexpr int WH  = BK / WTR;          // W halfs per thread (R18b fix)
  constexpr int NW  = WH / 8;            // W half8 regs per thread
  static_assert(NA >= 1 && NW >= 1, "staging arithmetic");

  __shared__ _Float16 As[64 * LS];
  __shared__ _Float16 Ws[BN * LS];       // MODE1: reused as Tz in epilogue
  __shared__ float    Td[(MODE == 3) ? 64 * 68 : 2];
  const int tid  = threadIdx.x;
  const int lane = tid & 63;
  const int wid  = tid >> 6;
  const int wm   = wid & 1, wn = wid >> 1;   // wave-tile: 32 m x BN/2 n
  const int m0   = blockIdx.y * 64;
  const int n0   = blockIdx.x * BN;
  const int q    = lane >> 4, l16 = lane & 15;

  // staging coords
  const int ar  = tid >> 2;                  // A: 4 thr/row
  const int akq = (tid & 3) * (BK / 4);
  const int wr  = tid / WTR;
  const int wkq = (tid % WTR) * WH;
  const int wrow = n0 + wr;
  const bool wv  = (wrow < N);

  const _Float16* Wp = W + (size_t)wrow * K;
  const size_t aoff = (size_t)(m0 + ar) * lda + akq;

  half8 zh;
  #pragma unroll
  for (int i = 0; i < 8; ++i) zh[i] = (_Float16)0.f;

  // initial loads (k0 = 0)
  half8 rah[NA], rwh[NW];
  #pragma unroll
  for (int i = 0; i < NA; ++i) rah[i] = *(const half8*)(A + aoff + i * 8);
  #pragma unroll
  for (int j = 0; j < NW; ++j)
    rwh[j] = wv ? *(const half8*)(Wp + wkq + j * 8) : zh;

  f32x4 acc[2][NF];
  #pragma unroll
  for (int mi = 0; mi < 2; ++mi)
    #pragma unroll
    for (int ni = 0; ni < NF; ++ni)
      acc[mi][ni] = (f32x4){0.f, 0.f, 0.f, 0.f};

  for (int k0 = 0; k0 < K; k0 += BK) {
    if (k0) __syncthreads();
    #pragma unroll
    for (int i = 0; i < NA; ++i)
      *(half8*)&As[ar * LS + akq + i * 8] = rah[i];
    #pragma unroll
    for (int j = 0; j < NW; ++j)
      *(half8*)&Ws[wr * LS + wkq + j * 8] = rwh[j];
    __syncthreads();

    if (k0 + BK < K) {            // prefetch next chunk
      const int kn = k0 + BK;
      #pragma unroll
      for (int i = 0; i < NA; ++i)
        rah[i] = *(const half8*)(A + aoff + kn + i * 8);
      if (wv) {
        #pragma unroll
        for (int j = 0; j < NW; ++j)
          rwh[j] = *(const half8*)(Wp + kn + wkq + j * 8);
      }
    }

    #pragma unroll
    for (int kk = 0; kk < BK / 32; ++kk) {
      half8 af[2], wf[NF];
      #pragma unroll
      for (int mi = 0; mi < 2; ++mi)
        af[mi] = *(const half8*)&As[(wm * 32 + mi * 16 + l16) * LS + kk * 32 + q * 8];
      #pragma unroll
      for (int ni = 0; ni < NF; ++ni)
        wf[ni] = *(const half8*)&Ws[(wn * (BN / 2) + ni * 16 + l16) * LS + kk * 32 + q * 8];
      #pragma unroll
      for (int mi = 0; mi < 2; ++mi)
        #pragma unroll
        for (int ni = 0; ni < NF; ++ni)
          acc[mi][ni] = __builtin_amdgcn_mfma_f32_16x16x32_f16(af[mi], wf[ni],
                                                               acc[mi][ni], 0, 0, 0);
    }
  }

  float*    Cf = (float*)Cv;
  _Float16* Ch = (_Float16*)Cv;

  if (MODE == 1) {
    if (n0 < 1024) {
      // xc half: f16 [M][1024]
      #pragma unroll
      for (int ni = 0; ni < NF; ++ni) {
        const int n = n0 + wn * (BN / 2) + ni * 16 + l16;
        #pragma unroll
        for (int mi = 0; mi < 2; ++mi) {
          const int mb = m0 + wm * 32 + mi * 16 + q * 4;
          #pragma unroll
          for (int r = 0; r < 4; ++r)
            Ch[(size_t)(mb + r) * 1024 + n] = (_Float16)(acc[mi][ni][r] * oscale);
        }
      }
    } else {
      // z half: silu -> f16, LDS transpose (Tz aliases Ws; LS==72),
      // coalesced 16B row stores
      _Float16* Tz = Ws;
      _Float16* Ch2 = (_Float16*)Cv2;
      __syncthreads();                  // all MFMA reads of Ws done
      #pragma unroll
      for (int ni = 0; ni < NF; ++ni) {
        const int nnl = wn * (BN / 2) + ni * 16 + l16;   // 0..127 local
        #pragma unroll
        for (int mi = 0; mi < 2; ++mi) {
          const int mbl = wm * 32 + mi * 16 + q * 4;     // 0..63 local
          half4v h4;
          #pragma unroll
          for (int r = 0; r < 4; ++r)
            h4[r] = (_Float16)silu_f(acc[mi][ni][r] * oscale);
          *(half4v*)&Tz[nnl * LS + mbl] = h4;
        }
      }
      __syncthreads();
      const int sr = tid >> 3;          // 0..31
      const int sc = (tid & 7) * 8;     // halfs 0..56
      #pragma unroll
      for (int rd = 0; rd < 4; ++rd) {
        const int row = rd * 32 + sr;
        half8 v = *(const half8*)&Tz[row * LS + sc];
        *(half8*)&Ch2[(size_t)(n0 - 1024 + row) * 4096 + m0 + sc] = v;
      }
    }
    return;
  }

  if (MODE == 2) {
    // xproj split:
    //   n <  32           -> dtr16 f16 [M][32]           (via Cv2)
    //   32 <= n <  96     -> Bsc scan layout             (via Cv)
    //   96 <= n < 160     -> Csc = Bsc + 262144
    // Scan layout: [b*256 + t/4][s 0..63][t&3] fp32. mb%4==0 so the 4 acc
    // components (rows mb..mb+3) form one contiguous float4 at s*4.
    float* Bs = Cf;
    _Float16* dtr = (_Float16*)Cv2;
    #pragma unroll
    for (int ni = 0; ni < NF; ++ni) {
      const int n = n0 + wn * (BN / 2) + ni * 16 + l16;
      #pragma unroll
      for (int mi = 0; mi < 2; ++mi) {
        const int mb = m0 + wm * 32 + mi * 16 + q * 4;
        if (n < 32) {
          #pragma unroll
          for (int r = 0; r < 4; ++r)
            dtr[(size_t)(mb + r) * 32 + n] = (_Float16)acc[mi][ni][r];
        } else if (n < 160) {
          const int s = (n < 96) ? (n - 32) : (n - 96);
          float* dst = Bs + ((n < 96) ? 0 : 262144);
          float4 v = make_float4(acc[mi][ni][0], acc[mi][ni][1],
                                 acc[mi][ni][2], acc[mi][ni][3]);
          *(float4*)&dst[((size_t)(mb >> 2) << 8) + s * 4] = v;
        }
      }
    }
    return;
  }

  if (MODE == 3) {
    // dtproj: softplus(acc*oscale + bias) -> fp32 [N][4096] via LDS transpose
    __syncthreads();
    #pragma unroll
    for (int ni = 0; ni < NF; ++ni) {
      const int nnl = wn * (BN / 2) + ni * 16 + l16;     // 0..63 local
      const float bv = (bias != nullptr) ? bias[n0 + nnl] : 0.f;
      #pragma unroll
      for (int mi = 0; mi < 2; ++mi) {
        const int mbl = wm * 32 + mi * 16 + q * 4;       // 0..63 local
        float o[4];
        #pragma unroll
        for (int r = 0; r < 4; ++r) {
          float v = acc[mi][ni][r] * oscale + bv;
          o[r] = (v > 20.f) ? v : log1pf(__expf(v));     // softplus
        }
        *(float4*)&Td[nnl * 68 + mbl] = make_float4(o[0], o[1], o[2], o[3]);
      }
    }
    __syncthreads();
    const int sr = tid >> 4;            // 0..15
    const int sc = (tid & 15) * 4;      // floats 0..60
    #pragma unroll
    for (int rd = 0; rd < 4; ++rd) {
      const int row = rd * 16 + sr;
      float4 v = *(const float4*)&Td[row * 68 + sc];
      *(float4*)&Cf[(size_t)(n0 + row) * 4096 + m0 + sc] = v;
    }
    return;
  }

  // MODE 0 epilogue
  #pragma unroll
  for (int ni = 0; ni < NF; ++ni) {
    const int n = n0 + wn * (BN / 2) + ni * 16 + l16;
    if (n < N) {
      const float bv = (bias != nullptr) ? bias[n] : 0.f;
      #pragma unroll
      for (int mi = 0; mi < 2; ++mi) {
        const int mb = m0 + wm * 32 + mi * 16 + q * 4;
        #pragma unroll
        for (int r = 0; r < 4; ++r) {
          float v = acc[mi][ni][r] * oscale + bv;
          if (ACT == 1) v = (v > 20.f) ? v : log1pf(__expf(v));
          if (ACT == 2) v = silu_f(v);
          size_t off = (size_t)(mb + r) * ldc + n;
          if (OF16) Ch[off] = (_Float16)v;
          else      Cf[off] = v;
        }
      }
    }
  }
}

// ---------------------------------------------------------------------------
// Depthwise causal conv (D_CONV=2) + silu, 64x64 LDS transpose.
// in : xcp [4096 bl][1024 d] f16
// out: xcT [1024 d][4096 bl] fp32 (scan input)  +  xcf [4096 bl][1024 d] f16
// ---------------------------------------------------------------------------
__global__ void conv_t_kernel(const _Float16* __restrict__ xcp,
                              const float* __restrict__ cw,   // [1024][2]
                              const float* __restrict__ cb,   // [1024]
                              float* __restrict__ xcT,
                              _Float16* __restrict__ xcf)
{
  __shared__ float tile[64][65];
  const int blk = blockIdx.x;            // b*256 + tt*16 + dd
  const int b  = blk >> 8;
  const int tt = (blk >> 4) & 15;
  const int dd = blk & 15;
  const int t0 = tt * 64, d0 = dd * 64;
  const int tid = threadIdx.x;

  #pragma unroll
  for (int i = 0; i < 16; ++i) {
    int idx = i * 256 + tid;
    int t = idx >> 6, d = idx & 63;
    int gt = t0 + t;
    size_t rcur = ((size_t)(b * 1024 + gt) << 10) + d0 + d;
    float cur  = (float)xcp[rcur];
    float prev = (gt > 0) ? (float)xcp[rcur - 1024] : 0.f;
    float v = fmaf(prev, cw[(d0+d)*2], fmaf(cur, cw[(d0+d)*2 + 1], cb[d0+d]));
    float sv = silu_f(v);
    tile[t][d] = sv;
    xcf[rcur] = (_Float16)sv;
  }
  __syncthreads();
  #pragma unroll
  for (int i = 0; i < 16; ++i) {
    int idx = i * 256 + tid;
    int d = idx >> 6, t = idx & 63;
    xcT[((size_t)(d0 + d) << 12) + b * 1024 + t0 + t] = tile[t][d];
  }
}

// ---------------------------------------------------------------------------
// Selective scan v6. Block = (b, dgroup): 4 waves share batch b, wave wrp
// handles d = dg*4 + wrp; lane = s. Per chunk-8:
//   stage (async, global_load_lds): B/C chunk 4KB (each wave 1KB quarter)
//     + per-wave 256B slot {dt[8] | x[8] | zs[8] f16} (one dword gload).
//   wait vmcnt(2) -> s_barrier -> compute from LDS -> s_barrier -> re-stage.
// B/C loaded ONCE per block (was once per wave): 4x less L2 traffic.
// Loop has zero compiler VMEM; y buffered per-wave in LDS, flushed at end.
// ---------------------------------------------------------------------------
#define GLDS16(src, dst)                                                    \
  __builtin_amdgcn_global_load_lds(                                         \
      (const __attribute__((address_space(1))) void*)(src),                 \
      (__attribute__((address_space(3))) void*)(dst), 16, 0, 0)
#define GLDS4(src, dst)                                                     \
  __builtin_amdgcn_global_load_lds(                                         \
      (const __attribute__((address_space(1))) void*)(src),                 \
      (__attribute__((address_space(3))) void*)(dst), 4, 0, 0)

#define WAITVM(N) do {                                      \
    asm volatile("s_waitcnt vmcnt(" #N ")" ::: "memory");   \
    __builtin_amdgcn_sched_barrier(0);                      \
  } while (0)

__device__ __forceinline__ void scan_compute(int t0, const float* bb,
    const float* sl, float& h, float al2, float dpv, float (*Pw)[68],
    _Float16* ybw, int lane, int tt_r, int c0)
{
  // B/C: lane s reads its 4 t-values per quad (contiguous 16B, conflict-free)
  float4 Bq0 = *(const float4*)(bb + lane * 4);
  float4 Bq1 = *(const float4*)(bb + 256 + lane * 4);
  float4 Cq0 = *(const float4*)(bb + 512 + lane * 4);
  float4 Cq1 = *(const float4*)(bb + 768 + lane * 4);
  // slot: dwords 0-7 dt, 8-15 x, 16-19 zs (f16 x8). Uniform reads broadcast.
  float4 dq0 = *(const float4*)(sl + 0);
  float4 dq1 = *(const float4*)(sl + 4);
  float4 xq0 = *(const float4*)(sl + 8);
  float4 xq1 = *(const float4*)(sl + 12);
  float  xvl = sl[8 + tt_r];
  float  zs  = (float)((const _Float16*)(sl + 16))[tt_r] * Y_SCALE;

  float dvv[8] = {dq0.x, dq0.y, dq0.z, dq0.w, dq1.x, dq1.y, dq1.z, dq1.w};
  float xvv[8] = {xq0.x, xq0.y, xq0.z, xq0.w, xq1.x, xq1.y, xq1.z, xq1.w};
  float Bvv[8] = {Bq0.x, Bq0.y, Bq0.z, Bq0.w, Bq1.x, Bq1.y, Bq1.z, Bq1.w};
  float Cvv[8] = {Cq0.x, Cq0.y, Cq0.z, Cq0.w, Cq1.x, Cq1.y, Cq1.z, Cq1.w};

  float dA[8], ub[8];
  #pragma unroll
  for (int tt = 0; tt < 8; ++tt) {
    dA[tt] = fast_exp2(dvv[tt] * al2);
    ub[tt] = dvv[tt] * xvv[tt] * Bvv[tt];
  }
  #pragma unroll
  for (int tt = 0; tt < 8; ++tt) {
    h = fmaf(h, dA[tt], ub[tt]);
    Pw[tt][lane] = h * Cvv[tt];
  }
  float4 s0 = *(const float4*)&Pw[tt_r][c0];
  float4 s1 = *(const float4*)&Pw[tt_r][c0 + 4];
  float r = ((s0.x + s0.y) + (s0.z + s0.w)) + ((s1.x + s1.y) + (s1.z + s1.w));
  r += __shfl_xor(r, 1, 64);
  r += __shfl_xor(r, 2, 64);
  r += __shfl_xor(r, 4, 64);
  if ((lane & 7) == 0)
    ybw[t0 + tt_r] = (_Float16)(fmaf(xvl, dpv, r) * zs);
}

__global__ __launch_bounds__(256, 4)
void scan_kernel(const float* __restrict__ dtT,     // [1024][4096]
                 const float* __restrict__ xcT,     // [1024][4096]
                 const _Float16* __restrict__ zsT,  // [1024][4096], silu(z), f16
                 const float* __restrict__ Bsc,     // [4][256][64][4]; Csc at +262144 fl
                 const float* __restrict__ A_log,   // [1024][64]
                 const float* __restrict__ Dp,      // [1024]
                 _Float16* __restrict__ y16)        // [4096 bl][1024 d], y*2^14
{
  __shared__ float    bufBC[2][1024];  // [buf][B 2KB | C 2KB] per chunk
  __shared__ float    slotD[2][4][64]; // [buf][wave][dt8|x8|zs(4dw)|pad]
  __shared__ float    P[4][8][68];     // per-wave reduction tile
  __shared__ _Float16 yb[4][1024];     // per-wave y buffer (flushed at end)

  const int tid  = threadIdx.x;
  const int lane = tid & 63;
  const int wrp  = tid >> 6;
  const int rb   = blockIdx.x;
  const int bswz = ((rb & 7) << 7) | (rb >> 3);          // XCD swizzle
  const int bsu  = __builtin_amdgcn_readfirstlane(bswz);
  const int b  = bsu >> 8;                               // batch
  const int dg = bsu & 255;                              // d-group
  const int d  = dg * 4 + wrp;                           // this wave's channel
  float (*Pw)[68] = P[wrp];
  _Float16* ybw   = yb[wrp];

  const float a   = -__expf(A_log[d * 64 + lane]);
  const float al2 = a * 1.44269504088896f;               // hoisted log2(e)
  const float dpv = Dp[d];
  // force prologue loads (A_log/Dp) to complete before the async pipeline
  asm volatile("" :: "v"(dpv), "v"(al2));

  const size_t row = ((size_t)d << 12) + b * 1024;
  const float*    dtp = dtT + row;
  const float*    xp  = xcT + row;
  const _Float16* zsp = zsT + row;
  _Float16*       yp  = y16 + ((size_t)b << 20) + d;     // + t*1024

  const int tt_r = lane >> 3;          // timestep this lane reduces
  const int c0   = (lane & 7) << 3;    // its 8-state column base

  // per-lane stage sources.
  // B/C: wave quarter w: w<2 -> B half w, w>=2 -> C half (w-2). +2048B/chunk.
  const char* srcBC = (const char*)Bsc + (size_t)b * 262144
      + ((wrp < 2) ? wrp * 1024 : 1048576 + (wrp - 2) * 1024) + lane * 16;
  // slot: lanes 0-7 dt, 8-15 x, 16-19 zs (as dwords), 20-63 harmless dup.
  const char* srcS; int strS;
  if      (lane < 8)  { srcS = (const char*)(dtp + lane);       strS = 32; }
  else if (lane < 16) { srcS = (const char*)(xp + (lane & 7));  strS = 32; }
  else if (lane < 20) { srcS = (const char*)zsp + (lane - 16) * 4; strS = 16; }
  else                { srcS = (const char*)(dtp + (lane & 7)); strS = 32; }

  char* dBC0 = (char*)&bufBC[0][0] + wrp * 1024;
  char* dBC1 = (char*)&bufBC[1][0] + wrp * 1024;
  float* dS0 = &slotD[0][wrp][0];
  float* dS1 = &slotD[1][wrp][0];

  // prologue: stage chunks 0 and 1 (2 vmcnt ops per chunk per wave)
  GLDS16(srcBC, dBC0); GLDS4(srcS, dS0); srcBC += 2048; srcS += strS;
  GLDS16(srcBC, dBC1); GLDS4(srcS, dS1); srcBC += 2048; srcS += strS;

  float h = 0.f;
  // 128 chunks; unroll x2 for static buffer indices. n = 0..124 step 2
  // covers chunks 0..125 with re-stage of n+2 (max 127).
  for (int n = 0; n < 126; n += 2) {
    WAITVM(2);                             // chunk n landed (this wave's ops)
    __builtin_amdgcn_s_barrier();          // all waves' quarters landed
    scan_compute(n * 8, &bufBC[0][0], dS0, h, al2, dpv, Pw, ybw, lane, tt_r, c0);
    __builtin_amdgcn_s_barrier();          // all waves done reading buf0
    GLDS16(srcBC, dBC0); GLDS4(srcS, dS0); srcBC += 2048; srcS += strS;  // n+2

    WAITVM(2);                             // chunk n+1 landed
    __builtin_amdgcn_s_barrier();
    scan_compute(n * 8 + 8, &bufBC[1][0], dS1, h, al2, dpv, Pw, ybw, lane, tt_r, c0);
    __builtin_amdgcn_s_barrier();
    GLDS16(srcBC, dBC1); GLDS4(srcS, dS1); srcBC += 2048; srcS += strS;  // n+3
  }
  // tail: chunks 126 (buf0) and 127 (buf1), already staged
  WAITVM(2);
  __builtin_amdgcn_s_barrier();
  scan_compute(1008, &bufBC[0][0], dS0, h, al2, dpv, Pw, ybw, lane, tt_r, c0);
  WAITVM(0);
  __builtin_amdgcn_s_barrier();
  scan_compute(1016, &bufBC[1][0], dS1, h, al2, dpv, Pw, ybw, lane, tt_r, c0);

  // flush y row (wave-private LDS, DS ops wave-ordered -> no barrier)
  #pragma unroll
  for (int i = 0; i < 16; ++i) {
    const int t = i * 64 + lane;
    yp[(size_t)t << 10] = ybw[t];
  }
}

// ---------------------------------------------------------------------------
// Fused out_proj(l1)+fc head: only h[b, L-1, :] reaches the output.
// out[b,c] = (sum_di y16l1[b*1024+1023][di] * w2[c][di]) * 2^-14 + fc_b[c],
// w2[c][di] = sum_dm fc_w[c][dm] * out_w1[dm][di]   (fp32 weights).
// ---------------------------------------------------------------------------
__global__ void head2_kernel(const _Float16* __restrict__ y16,
                             const float* __restrict__ out_w1,  // [512][1024]
                             const float* __restrict__ fc_w,    // [3][512]
                             const float* __restrict__ fc_b,
                             float* __restrict__ out)
{
  __shared__ float red[4];
  const int bc = blockIdx.x;            // 0..11
  const int b = bc / 3, c = bc % 3;
  const int tid = threadIdx.x;
  const int lane = tid & 63, wv = tid >> 6;

  float4 w2 = make_float4(0.f, 0.f, 0.f, 0.f);
  const float* fcr = fc_w + c * 512;
  const float* owp = out_w1 + tid * 4;
  for (int dm = 0; dm < 512; ++dm) {
    float f = fcr[dm];
    float4 o = *(const float4*)(owp + (size_t)dm * 1024);
    w2.x = fmaf(f, o.x, w2.x); w2.y = fmaf(f, o.y, w2.y);
    w2.z = fmaf(f, o.z, w2.z); w2.w = fmaf(f, o.w, w2.w);
  }
  const _Float16* yr = y16 + ((size_t)(b * 1024 + 1023) << 10) + tid * 4;
  half4v yv = *(const half4v*)yr;
  float s = (float)yv[0] * w2.x + (float)yv[1] * w2.y
          + (float)yv[2] * w2.z + (float)yv[3] * w2.w;
  #pragma unroll
  for (int o = 32; o > 0; o >>= 1) s += __shfl_xor(s, o, 64);
  if (lane == 0) red[wv] = s;
  __syncthreads();
  if (tid == 0)
    out[b * 3 + c] = (red[0] + red[1] + red[2] + red[3]) * (1.f / Y_SCALE)
                     + fc_b[c];
}

extern "C" void kernel_launch(void* const* d_in, const int* in_sizes, int n_in,
                              void* d_out, int out_size, void* d_ws, size_t ws_size,
                              hipStream_t stream)
{
  const float* x        = (const float*)d_in[0];
  const float* exp_w    = (const float*)d_in[1];
  const float* exp_b    = (const float*)d_in[2];
  const float* in_w     = (const float*)d_in[3];
  const float* conv_w   = (const float*)d_in[4];
  const float* conv_b   = (const float*)d_in[5];
  const float* xproj_w  = (const float*)d_in[6];
  const float* dtproj_w = (const float*)d_in[7];
  const float* dtproj_b = (const float*)d_in[8];
  const float* A_log    = (const float*)d_in[9];
  const float* Dp       = (const float*)d_in[10];
  const float* out_w    = (const float*)d_in[11];
  const float* fc_w     = (const float*)d_in[12];
  const float* fc_b     = (const float*)d_in[13];
  float* out = (float*)d_out;

  // Workspace layout (byte offsets), 72 MB total.
  // 4..20 MB region sequentially reused: xcpre16 (8MB) -> dtT (16MB).
  char* ws = (char*)d_ws;
  _Float16* hf16    = (_Float16*)(ws);                        //  4 MB [4096][512] f16
  _Float16* xcpre16 = (_Float16*)(ws + ((size_t)4  << 20));   //  8 MB [4096][1024] f16
  float*    dtT     = (float*)   (ws + ((size_t)4  << 20));   // 16 MB [1024][4096] (reuse)
  float*    xcT     = (float*)   (ws + ((size_t)20 << 20));   // 16 MB [1024][4096]
  _Float16* zsT     = (_Float16*)(ws + ((size_t)36 << 20));   //  8 MB [1024][4096]
  float*    Bsc     = (float*)   (ws + ((size_t)44 << 20));   //  2 MB [4][256][64][4] B then C
  _Float16* dtr16   = (_Float16*)(ws + ((size_t)47 << 20));   //  0.25 MB [4096][32]
  _Float16* xc16    = (_Float16*)(ws + ((size_t)48 << 20));   //  8 MB [4096][1024]
  _Float16* y16     = (_Float16*)(ws + ((size_t)56 << 20));   //  8 MB [4096][1024]
  _Float16* w16     = (_Float16*)(ws + ((size_t)64 << 20));   //  7.9 MB f16 pool

  _Float16* exp16 = w16;                 // [512][128]
  _Float16* in16  = w16 + 65536;         // [2][2048][512]
  _Float16* xp16  = w16 + 2162688;       // [2][160][1024]
  _Float16* dt16  = w16 + 2490368;       // [2][1024][32]
  _Float16* out16 = w16 + 2555904;       // [2][512][1024]
  _Float16* x16   = w16 + 3604480;       // [4096][128]

  dim3 blk(256);

  // one-shot f16 conversion of all weights + x (4128768 elems, 4032 blocks)
  wcvt_kernel<<<4032, blk, 0, stream>>>(exp_w, in_w, xproj_w, dtproj_w, out_w,
                                        x, w16);

  // expand: hf16 = f16(x @ exp_w^T + exp_b)   [4096,512] K=128, BK=32.
  gemm_mfma<64,32,0,1,0><<<dim3(8,64), blk, 0, stream>>>(x16, 128, exp16, exp_b,
                                                         hf16, 512, 512, 128, 1.f,
                                                         nullptr);

  for (int l = 0; l < 2; ++l) {
    const float is = l ? (1.f / H1_SCALE) : 1.f;     // undo h1 scaling (exact)
    // fused in_proj: xcpre16 f16 + zsT f16 (Tz aliases Ws). N=2048 K=512 BK=64.
    gemm_mfma<128,64,0,0,1><<<dim3(16,64), blk, 0, stream>>>(hf16, 512,
                                                             in16 + (size_t)l*1048576,
                                                             nullptr, xcpre16, 1024,
                                                             2048, 512, is, zsT);
    // conv + silu -> xcT (fp32, scan) + xc16 (f16, xproj A)
    conv_t_kernel<<<1024, blk, 0, stream>>>(xcpre16, conv_w + l*2048, conv_b + l*1024,
                                            xcT, xc16);
    // xproj (MODE 2): dtr16 f16 [4096][32] + Bsc/Csc scan layout. K=1024 BK=64.
    gemm_mfma<64,64,0,0,2><<<dim3(3,64), blk, 0, stream>>>(xc16, 1024,
                                                           xp16 + (size_t)l*163840,
                                                           nullptr, Bsc, 160,
                                                           160, 1024, 1.f, dtr16);
    // dtproj (MODE 3): dtT [1024][4096] softplus, LDS-transposed. K=32 BK=32.
    gemm_mfma<64,32,0,0,3><<<dim3(16,64), blk, 0, stream>>>(dtr16, 32,
                                                            dt16 + (size_t)l*32768,
                                                            dtproj_b + l*1024,
                                                            dtT, 4096, 1024, 32, 1.f,
                                                            nullptr);
    // selective scan v6 (LDS-shared B/C staging, async gload_lds pipeline)
    scan_kernel<<<1024, blk, 0, stream>>>(dtT, xcT, zsT, Bsc,
                                          A_log + (size_t)l*65536, Dp + l*1024, y16);
    // out_proj only for layer 0 (layer-1 h only matters at t=L-1 -> head2)
    if (l == 0)
      gemm_mfma<64,64,0,1,0><<<dim3(8,64), blk, 0, stream>>>(y16, 1024,
                                                             out16, nullptr,
                                                             hf16, 512, 512, 1024,
                                                             H1_SCALE / Y_SCALE,
                                                             nullptr);
  }

  // fused out_proj(l1) + fc head from y16(l1) directly (fp32 weights)
  head2_kernel<<<12, blk, 0, stream>>>(y16, out_w + (size_t)512*1024,
                                       fc_w, fc_b, out);
}

// Round 8
// 526.194 us; speedup vs baseline: 1.0296x; 1.0099x over previous
//
#include <hip/hip_runtime.h>
#include <math.h>

// Problem constants: B=4, L=1024, D_IN=128, D_MODEL=512, N_LAYERS=2,
// N_CLASSES=3, D_INNER=1024, D_STATE=64, D_CONV=2, DT_RANK=32, BL=4096.
//
// Precision plan: all GEMM operands f16 (conversions hoisted upstream).
// Layer-1 residual h f16 scaled by 2^8 (exact). y scaled by 2^14 at the
// scan store. Head works from y16(l1) directly with fp32 weights.
//
// R24: scan v7 — R23 (2-deep LDS staging) still stalled ~54%: 1-chunk
// prefetch distance (~370 cyc) < L3 latency (~500-900 cyc), and the
// 2-barrier lockstep convoys all 4 waves on the slowest load. VALU-busy
// time is ~72us across ALL variants => the rest is coverable stall.
// Single change vs R23: pipeline depth 2 -> 4 (prefetch distance 3
// chunk-computes ~1100 cyc > L3 latency; steady wait vmcnt(6) retires
// already-landed loads). LDS 37KB/block x4 blocks/CU = 148KB <= 160.

using half8  = __attribute__((ext_vector_type(8))) _Float16;
using half4v = __attribute__((ext_vector_type(4))) _Float16;
using f32x4  = __attribute__((ext_vector_type(4))) float;

#define Y_SCALE 16384.0f   // 2^14
#define H1_SCALE 256.0f    // 2^8

__device__ __forceinline__ float silu_f(float v) {
  return v / (1.f + __expf(-v));
}

__device__ __forceinline__ float fast_exp2(float x) {
#if __has_builtin(__builtin_amdgcn_exp2f)
  return __builtin_amdgcn_exp2f(x);
#else
  return __expf(x * 0.69314718055994531f);
#endif
}

// ---------------------------------------------------------------------------
// One-shot fp32 -> f16 conversion of all weights + x into the w16 pool.
//   exp_w 0..65536 | in_w ..2162688 | xproj_w ..2490368 | dtproj_w ..2555904
//   | out_w ..3604480 | x ..4128768
// ---------------------------------------------------------------------------
__global__ void wcvt_kernel(const float* __restrict__ exp_w,
                            const float* __restrict__ in_w,
                            const float* __restrict__ xproj_w,
                            const float* __restrict__ dtproj_w,
                            const float* __restrict__ out_w,
                            const float* __restrict__ x,
                            _Float16* __restrict__ w16)
{
  size_t gi = ((size_t)blockIdx.x * 256 + threadIdx.x) * 4;
  const float* src; size_t off;
  if      (gi < 65536)   { src = exp_w;    off = gi; }
  else if (gi < 2162688) { src = in_w;     off = gi - 65536; }
  else if (gi < 2490368) { src = xproj_w;  off = gi - 2162688; }
  else if (gi < 2555904) { src = dtproj_w; off = gi - 2490368; }
  else if (gi < 3604480) { src = out_w;    off = gi - 2555904; }
  else                   { src = x;        off = gi - 3604480; }
  float4 v = *(const float4*)(src + off);
  half4v h;
  h[0] = (_Float16)v.x; h[1] = (_Float16)v.y;
  h[2] = (_Float16)v.z; h[3] = (_Float16)v.w;
  *(half4v*)(w16 + gi) = h;
}

// ---------------------------------------------------------------------------
// f16 MFMA GEMM, 64 x BN tile, BK-chunk K-loop. Block 256 thr = 4 waves;
// wave-tile 32 x (BN/2), MI=2 m-frags. BK in {32,64}.
// Modes: 0 plain / 1 in_proj fused (REQUIRES BK=64, BN=128; Tz aliases Ws) /
// 2 xproj split (dtr16 + Bsc/Csc scan layout) / 3 dtproj transposed-softplus.
// MFMA layouts (m89/m120-verified): A-frag A[m=lane&15][k=q*8+j],
// B-frag B[k=q*8+j][n=lane&15], D: col(n)=lane&15, row(m)=q*4+r.
// ---------------------------------------------------------------------------
template<int BN, int BK, int ACT, int OF16, int MODE>
__global__ __launch_bounds__(256)
void gemm_mfma(const _Float16* __restrict__ A, int lda,
               const _Float16* __restrict__ W,
               const float* __restrict__ bias,
               void* __restrict__ Cv, int ldc,
               int N, int K, float oscale,
               void* __restrict__ Cv2)
{
  static_assert(MODE != 1 || (BK == 64 && BN == 128), "MODE1 needs BK=64/BN=128");
  constexpr int NF  = BN / 32;           // n-frags per wave
  constexpr int LS  = BK + 8;            // LDS row stride in halfs (16B-aligned)
  constexpr int NA  = BK / 32;           // A half8 regs per thread
  constexpr int WTR = 256 / BN;          // threads per W row
  constexpr int WH  = BK / WTR;          // W halfs per thread (R18b fix)
  constexpr int NW  = WH / 8;            // W half8 regs per thread
  static_assert(NA >= 1 && NW >= 1, "staging arithmetic");

  __shared__ _Float16 As[64 * LS];
  __shared__ _Float16 Ws[BN * LS];       // MODE1: reused as Tz in epilogue
  __shared__ float    Td[(MODE == 3) ? 64 * 68 : 2];
  const int tid  = threadIdx.x;
  const int lane = tid & 63;
  const int wid  = tid >> 6;
  const int wm   = wid & 1, wn = wid >> 1;   // wave-tile: 32 m x BN/2 n
  const int m0   = blockIdx.y * 64;
  const int n0   = blockIdx.x * BN;
  const int q    = lane >> 4, l16 = lane & 15;

  // staging coords
  const int ar  = tid >> 2;                  // A: 4 thr/row
  const int akq = (tid & 3) * (BK / 4);
  const int wr  = tid / WTR;
  const int wkq = (tid % WTR) * WH;
  const int wrow = n0 + wr;
  const bool wv  = (wrow < N);

  const _Float16* Wp = W + (size_t)wrow * K;
  const size_t aoff = (size_t)(m0 + ar) * lda + akq;

  half8 zh;
  #pragma unroll
  for (int i = 0; i < 8; ++i) zh[i] = (_Float16)0.f;

  // initial loads (k0 = 0)
  half8 rah[NA], rwh[NW];
  #pragma unroll
  for (int i = 0; i < NA; ++i) rah[i] = *(const half8*)(A + aoff + i * 8);
  #pragma unroll
  for (int j = 0; j < NW; ++j)
    rwh[j] = wv ? *(const half8*)(Wp + wkq + j * 8) : zh;

  f32x4 acc[2][NF];
  #pragma unroll
  for (int mi = 0; mi < 2; ++mi)
    #pragma unroll
    for (int ni = 0; ni < NF; ++ni)
      acc[mi][ni] = (f32x4){0.f, 0.f, 0.f, 0.f};

  for (int k0 = 0; k0 < K; k0 += BK) {
    if (k0) __syncthreads();
    #pragma unroll
    for (int i = 0; i < NA; ++i)
      *(half8*)&As[ar * LS + akq + i * 8] = rah[i];
    #pragma unroll
    for (int j = 0; j < NW; ++j)
      *(half8*)&Ws[wr * LS + wkq + j * 8] = rwh[j];
    __syncthreads();

    if (k0 + BK < K) {            // prefetch next chunk
      const int kn = k0 + BK;
      #pragma unroll
      for (int i = 0; i < NA; ++i)
        rah[i] = *(const half8*)(A + aoff + kn + i * 8);
      if (wv) {
        #pragma unroll
        for (int j = 0; j < NW; ++j)
          rwh[j] = *(const half8*)(Wp + kn + wkq + j * 8);
      }
    }

    #pragma unroll
    for (int kk = 0; kk < BK / 32; ++kk) {
      half8 af[2], wf[NF];
      #pragma unroll
      for (int mi = 0; mi < 2; ++mi)
        af[mi] = *(const half8*)&As[(wm * 32 + mi * 16 + l16) * LS + kk * 32 + q * 8];
      #pragma unroll
      for (int ni = 0; ni < NF; ++ni)
        wf[ni] = *(const half8*)&Ws[(wn * (BN / 2) + ni * 16 + l16) * LS + kk * 32 + q * 8];
      #pragma unroll
      for (int mi = 0; mi < 2; ++mi)
        #pragma unroll
        for (int ni = 0; ni < NF; ++ni)
          acc[mi][ni] = __builtin_amdgcn_mfma_f32_16x16x32_f16(af[mi], wf[ni],
                                                               acc[mi][ni], 0, 0, 0);
    }
  }

  float*    Cf = (float*)Cv;
  _Float16* Ch = (_Float16*)Cv;

  if (MODE == 1) {
    if (n0 < 1024) {
      // xc half: f16 [M][1024]
      #pragma unroll
      for (int ni = 0; ni < NF; ++ni) {
        const int n = n0 + wn * (BN / 2) + ni * 16 + l16;
        #pragma unroll
        for (int mi = 0; mi < 2; ++mi) {
          const int mb = m0 + wm * 32 + mi * 16 + q * 4;
          #pragma unroll
          for (int r = 0; r < 4; ++r)
            Ch[(size_t)(mb + r) * 1024 + n] = (_Float16)(acc[mi][ni][r] * oscale);
        }
      }
    } else {
      // z half: silu -> f16, LDS transpose (Tz aliases Ws; LS==72),
      // coalesced 16B row stores
      _Float16* Tz = Ws;
      _Float16* Ch2 = (_Float16*)Cv2;
      __syncthreads();                  // all MFMA reads of Ws done
      #pragma unroll
      for (int ni = 0; ni < NF; ++ni) {
        const int nnl = wn * (BN / 2) + ni * 16 + l16;   // 0..127 local
        #pragma unroll
        for (int mi = 0; mi < 2; ++mi) {
          const int mbl = wm * 32 + mi * 16 + q * 4;     // 0..63 local
          half4v h4;
          #pragma unroll
          for (int r = 0; r < 4; ++r)
            h4[r] = (_Float16)silu_f(acc[mi][ni][r] * oscale);
          *(half4v*)&Tz[nnl * LS + mbl] = h4;
        }
      }
      __syncthreads();
      const int sr = tid >> 3;          // 0..31
      const int sc = (tid & 7) * 8;     // halfs 0..56
      #pragma unroll
      for (int rd = 0; rd < 4; ++rd) {
        const int row = rd * 32 + sr;
        half8 v = *(const half8*)&Tz[row * LS + sc];
        *(half8*)&Ch2[(size_t)(n0 - 1024 + row) * 4096 + m0 + sc] = v;
      }
    }
    return;
  }

  if (MODE == 2) {
    // xproj split:
    //   n <  32           -> dtr16 f16 [M][32]           (via Cv2)
    //   32 <= n <  96     -> Bsc scan layout             (via Cv)
    //   96 <= n < 160     -> Csc = Bsc + 262144
    // Scan layout: [b*256 + t/4][s 0..63][t&3] fp32. mb%4==0 so the 4 acc
    // components (rows mb..mb+3) form one contiguous float4 at s*4.
    float* Bs = Cf;
    _Float16* dtr = (_Float16*)Cv2;
    #pragma unroll
    for (int ni = 0; ni < NF; ++ni) {
      const int n = n0 + wn * (BN / 2) + ni * 16 + l16;
      #pragma unroll
      for (int mi = 0; mi < 2; ++mi) {
        const int mb = m0 + wm * 32 + mi * 16 + q * 4;
        if (n < 32) {
          #pragma unroll
          for (int r = 0; r < 4; ++r)
            dtr[(size_t)(mb + r) * 32 + n] = (_Float16)acc[mi][ni][r];
        } else if (n < 160) {
          const int s = (n < 96) ? (n - 32) : (n - 96);
          float* dst = Bs + ((n < 96) ? 0 : 262144);
          float4 v = make_float4(acc[mi][ni][0], acc[mi][ni][1],
                                 acc[mi][ni][2], acc[mi][ni][3]);
          *(float4*)&dst[((size_t)(mb >> 2) << 8) + s * 4] = v;
        }
      }
    }
    return;
  }

  if (MODE == 3) {
    // dtproj: softplus(acc*oscale + bias) -> fp32 [N][4096] via LDS transpose
    __syncthreads();
    #pragma unroll
    for (int ni = 0; ni < NF; ++ni) {
      const int nnl = wn * (BN / 2) + ni * 16 + l16;     // 0..63 local
      const float bv = (bias != nullptr) ? bias[n0 + nnl] : 0.f;
      #pragma unroll
      for (int mi = 0; mi < 2; ++mi) {
        const int mbl = wm * 32 + mi * 16 + q * 4;       // 0..63 local
        float o[4];
        #pragma unroll
        for (int r = 0; r < 4; ++r) {
          float v = acc[mi][ni][r] * oscale + bv;
          o[r] = (v > 20.f) ? v : log1pf(__expf(v));     // softplus
        }
        *(float4*)&Td[nnl * 68 + mbl] = make_float4(o[0], o[1], o[2], o[3]);
      }
    }
    __syncthreads();
    const int sr = tid >> 4;            // 0..15
    const int sc = (tid & 15) * 4;      // floats 0..60
    #pragma unroll
    for (int rd = 0; rd < 4; ++rd) {
      const int row = rd * 16 + sr;
      float4 v = *(const float4*)&Td[row * 68 + sc];
      *(float4*)&Cf[(size_t)(n0 + row) * 4096 + m0 + sc] = v;
    }
    return;
  }

  // MODE 0 epilogue
  #pragma unroll
  for (int ni = 0; ni < NF; ++ni) {
    const int n = n0 + wn * (BN / 2) + ni * 16 + l16;
    if (n < N) {
      const float bv = (bias != nullptr) ? bias[n] : 0.f;
      #pragma unroll
      for (int mi = 0; mi < 2; ++mi) {
        const int mb = m0 + wm * 32 + mi * 16 + q * 4;
        #pragma unroll
        for (int r = 0; r < 4; ++r) {
          float v = acc[mi][ni][r] * oscale + bv;
          if (ACT == 1) v = (v > 20.f) ? v : log1pf(__expf(v));
          if (ACT == 2) v = silu_f(v);
          size_t off = (size_t)(mb + r) * ldc + n;
          if (OF16) Ch[off] = (_Float16)v;
          else      Cf[off] = v;
        }
      }
    }
  }
}

// ---------------------------------------------------------------------------
// Depthwise causal conv (D_CONV=2) + silu, 64x64 LDS transpose.
// in : xcp [4096 bl][1024 d] f16
// out: xcT [1024 d][4096 bl] fp32 (scan input)  +  xcf [4096 bl][1024 d] f16
// ---------------------------------------------------------------------------
__global__ void conv_t_kernel(const _Float16* __restrict__ xcp,
                              const float* __restrict__ cw,   // [1024][2]
                              const float* __restrict__ cb,   // [1024]
                              float* __restrict__ xcT,
                              _Float16* __restrict__ xcf)
{
  __shared__ float tile[64][65];
  const int blk = blockIdx.x;            // b*256 + tt*16 + dd
  const int b  = blk >> 8;
  const int tt = (blk >> 4) & 15;
  const int dd = blk & 15;
  const int t0 = tt * 64, d0 = dd * 64;
  const int tid = threadIdx.x;

  #pragma unroll
  for (int i = 0; i < 16; ++i) {
    int idx = i * 256 + tid;
    int t = idx >> 6, d = idx & 63;
    int gt = t0 + t;
    size_t rcur = ((size_t)(b * 1024 + gt) << 10) + d0 + d;
    float cur  = (float)xcp[rcur];
    float prev = (gt > 0) ? (float)xcp[rcur - 1024] : 0.f;
    float v = fmaf(prev, cw[(d0+d)*2], fmaf(cur, cw[(d0+d)*2 + 1], cb[d0+d]));
    float sv = silu_f(v);
    tile[t][d] = sv;
    xcf[rcur] = (_Float16)sv;
  }
  __syncthreads();
  #pragma unroll
  for (int i = 0; i < 16; ++i) {
    int idx = i * 256 + tid;
    int d = idx >> 6, t = idx & 63;
    xcT[((size_t)(d0 + d) << 12) + b * 1024 + t0 + t] = tile[t][d];
  }
}

// ---------------------------------------------------------------------------
// Selective scan v7. Block = (b, dgroup): 4 waves share batch b, wave wrp
// handles d = dg*4 + wrp; lane = s. 4-deep LDS chunk pipeline:
//   stage (async, global_load_lds): B/C chunk 4KB (each wave 1KB quarter)
//     + per-wave 256B slot {dt[8] | x[8] | zs[8] f16} (one dword gload).
//   per chunk: wait vmcnt(6) (own oldest pair landed) -> s_barrier (all
//   quarters present) -> compute from LDS -> s_barrier -> re-stage chunk+4.
// Prefetch distance = 3 chunk-computes (~1100 cyc) > L3 latency.
// ---------------------------------------------------------------------------
#define GLDS16(src, dst)                                                    \
  __builtin_amdgcn_global_load_lds(                                         \
      (const __attribute__((address_space(1))) void*)(src),                 \
      (__attribute__((address_space(3))) void*)(dst), 16, 0, 0)
#define GLDS4(src, dst)                                                     \
  __builtin_amdgcn_global_load_lds(                                         \
      (const __attribute__((address_space(1))) void*)(src),                 \
      (__attribute__((address_space(3))) void*)(dst), 4, 0, 0)

#define WAITVM(N) do {                                      \
    asm volatile("s_waitcnt vmcnt(" #N ")" ::: "memory");   \
    __builtin_amdgcn_sched_barrier(0);                      \
  } while (0)

__device__ __forceinline__ void scan_compute(int t0, const float* bb,
    const float* sl, float& h, float al2, float dpv, float (*Pw)[68],
    _Float16* ybw, int lane, int tt_r, int c0)
{
  // B/C: lane s reads its 4 t-values per quad (contiguous 16B)
  float4 Bq0 = *(const float4*)(bb + lane * 4);
  float4 Bq1 = *(const float4*)(bb + 256 + lane * 4);
  float4 Cq0 = *(const float4*)(bb + 512 + lane * 4);
  float4 Cq1 = *(const float4*)(bb + 768 + lane * 4);
  // slot: dwords 0-7 dt, 8-15 x, 16-19 zs (f16 x8). Uniform reads broadcast.
  float4 dq0 = *(const float4*)(sl + 0);
  float4 dq1 = *(const float4*)(sl + 4);
  float4 xq0 = *(const float4*)(sl + 8);
  float4 xq1 = *(const float4*)(sl + 12);
  float  xvl = sl[8 + tt_r];
  float  zs  = (float)((const _Float16*)(sl + 16))[tt_r] * Y_SCALE;

  float dvv[8] = {dq0.x, dq0.y, dq0.z, dq0.w, dq1.x, dq1.y, dq1.z, dq1.w};
  float xvv[8] = {xq0.x, xq0.y, xq0.z, xq0.w, xq1.x, xq1.y, xq1.z, xq1.w};
  float Bvv[8] = {Bq0.x, Bq0.y, Bq0.z, Bq0.w, Bq1.x, Bq1.y, Bq1.z, Bq1.w};
  float Cvv[8] = {Cq0.x, Cq0.y, Cq0.z, Cq0.w, Cq1.x, Cq1.y, Cq1.z, Cq1.w};

  float dA[8], ub[8];
  #pragma unroll
  for (int tt = 0; tt < 8; ++tt) {
    dA[tt] = fast_exp2(dvv[tt] * al2);
    ub[tt] = dvv[tt] * xvv[tt] * Bvv[tt];
  }
  #pragma unroll
  for (int tt = 0; tt < 8; ++tt) {
    h = fmaf(h, dA[tt], ub[tt]);
    Pw[tt][lane] = h * Cvv[tt];
  }
  float4 s0 = *(const float4*)&Pw[tt_r][c0];
  float4 s1 = *(const float4*)&Pw[tt_r][c0 + 4];
  float r = ((s0.x + s0.y) + (s0.z + s0.w)) + ((s1.x + s1.y) + (s1.z + s1.w));
  r += __shfl_xor(r, 1, 64);
  r += __shfl_xor(r, 2, 64);
  r += __shfl_xor(r, 4, 64);
  if ((lane & 7) == 0)
    ybw[t0 + tt_r] = (_Float16)(fmaf(xvl, dpv, r) * zs);
}

__global__ __launch_bounds__(256, 4)
void scan_kernel(const float* __restrict__ dtT,     // [1024][4096]
                 const float* __restrict__ xcT,     // [1024][4096]
                 const _Float16* __restrict__ zsT,  // [1024][4096], silu(z), f16
                 const float* __restrict__ Bsc,     // [4][256][64][4]; Csc at +262144 fl
                 const float* __restrict__ A_log,   // [1024][64]
                 const float* __restrict__ Dp,      // [1024]
                 _Float16* __restrict__ y16)        // [4096 bl][1024 d], y*2^14
{
  __shared__ float    bufBC[4][1024];  // [buf][B 2KB | C 2KB] per chunk
  __shared__ float    slotD[4][4][64]; // [buf][wave][dt8|x8|zs(4dw)|pad]
  __shared__ float    P[4][8][68];     // per-wave reduction tile
  __shared__ _Float16 yb[4][1024];     // per-wave y buffer (flushed at end)

  const int tid  = threadIdx.x;
  const int lane = tid & 63;
  const int wrp  = tid >> 6;
  const int rb   = blockIdx.x;
  const int bswz = ((rb & 7) << 7) | (rb >> 3);          // XCD swizzle
  const int bsu  = __builtin_amdgcn_readfirstlane(bswz);
  const int b  = bsu >> 8;                               // batch
  const int dg = bsu & 255;                              // d-group
  const int d  = dg * 4 + wrp;                           // this wave's channel
  float (*Pw)[68] = P[wrp];
  _Float16* ybw   = yb[wrp];

  const float a   = -__expf(A_log[d * 64 + lane]);
  const float al2 = a * 1.44269504088896f;               // hoisted log2(e)
  const float dpv = Dp[d];
  // force prologue loads (A_log/Dp) to complete before the async pipeline
  asm volatile("" :: "v"(dpv), "v"(al2));

  const size_t row = ((size_t)d << 12) + b * 1024;
  const float*    dtp = dtT + row;
  const float*    xp  = xcT + row;
  const _Float16* zsp = zsT + row;
  _Float16*       yp  = y16 + ((size_t)b << 20) + d;     // + t*1024

  const int tt_r = lane >> 3;          // timestep this lane reduces
  const int c0   = (lane & 7) << 3;    // its 8-state column base

  // per-lane stage sources.
  // B/C: wave quarter w: w<2 -> B half w, w>=2 -> C half (w-2). +2048B/chunk.
  const char* srcBC = (const char*)Bsc + (size_t)b * 262144
      + ((wrp < 2) ? wrp * 1024 : 1048576 + (wrp - 2) * 1024) + lane * 16;
  // slot: lanes 0-7 dt, 8-15 x, 16-19 zs (as dwords), 20-63 harmless dup.
  const char* srcS; int strS;
  if      (lane < 8)  { srcS = (const char*)(dtp + lane);       strS = 32; }
  else if (lane < 16) { srcS = (const char*)(xp + (lane & 7));  strS = 32; }
  else if (lane < 20) { srcS = (const char*)zsp + (lane - 16) * 4; strS = 16; }
  else                { srcS = (const char*)(dtp + (lane & 7)); strS = 32; }

  char*  dBC[4]; float* dS[4];
  #pragma unroll
  for (int i = 0; i < 4; ++i) {
    dBC[i] = (char*)&bufBC[i][0] + wrp * 1024;
    dS[i]  = &slotD[i][wrp][0];
  }

  // prologue: stage chunks 0..3 (2 vmcnt ops per chunk per wave -> 8 in flight)
  GLDS16(srcBC, dBC[0]); GLDS4(srcS, dS[0]); srcBC += 2048; srcS += strS;
  GLDS16(srcBC, dBC[1]); GLDS4(srcS, dS[1]); srcBC += 2048; srcS += strS;
  GLDS16(srcBC, dBC[2]); GLDS4(srcS, dS[2]); srcBC += 2048; srcS += strS;
  GLDS16(srcBC, dBC[3]); GLDS4(srcS, dS[3]); srcBC += 2048; srcS += strS;

  float h = 0.f;
  // 128 chunks; unroll x4 for static buffer indices. Loop computes chunks
  // 0..123 and re-stages 4..127; tail drains 124..127.
  for (int n = 0; n < 124; n += 4) {
    #pragma unroll
    for (int j = 0; j < 4; ++j) {
      WAITVM(6);                           // own pair for chunk n+j landed
      __builtin_amdgcn_s_barrier();        // all waves' quarters landed
      scan_compute((n + j) * 8, &bufBC[j][0], dS[j], h, al2, dpv, Pw, ybw,
                   lane, tt_r, c0);
      __builtin_amdgcn_s_barrier();        // all waves done reading buf j
      GLDS16(srcBC, dBC[j]); GLDS4(srcS, dS[j]);   // stage chunk n+j+4
      srcBC += 2048; srcS += strS;
    }
  }
  // tail: chunks 124..127 in bufs 0..3, already staged; drain counts 6/4/2/0
  WAITVM(6);
  __builtin_amdgcn_s_barrier();
  scan_compute(992,  &bufBC[0][0], dS[0], h, al2, dpv, Pw, ybw, lane, tt_r, c0);
  WAITVM(4);
  __builtin_amdgcn_s_barrier();
  scan_compute(1000, &bufBC[1][0], dS[1], h, al2, dpv, Pw, ybw, lane, tt_r, c0);
  WAITVM(2);
  __builtin_amdgcn_s_barrier();
  scan_compute(1008, &bufBC[2][0], dS[2], h, al2, dpv, Pw, ybw, lane, tt_r, c0);
  WAITVM(0);
  __builtin_amdgcn_s_barrier();
  scan_compute(1016, &bufBC[3][0], dS[3], h, al2, dpv, Pw, ybw, lane, tt_r, c0);

  // flush y row (wave-private LDS, DS ops wave-ordered -> no barrier)
  #pragma unroll
  for (int i = 0; i < 16; ++i) {
    const int t = i * 64 + lane;
    yp[(size_t)t << 10] = ybw[t];
  }
}

// ---------------------------------------------------------------------------
// Fused out_proj(l1)+fc head: only h[b, L-1, :] reaches the output.
// out[b,c] = (sum_di y16l1[b*1024+1023][di] * w2[c][di]) * 2^-14 + fc_b[c],
// w2[c][di] = sum_dm fc_w[c][dm] * out_w1[dm][di]   (fp32 weights).
// ---------------------------------------------------------------------------
__global__ void head2_kernel(const _Float16* __restrict__ y16,
                             const float* __restrict__ out_w1,  // [512][1024]
                             const float* __restrict__ fc_w,    // [3][512]
                             const float* __restrict__ fc_b,
                             float* __restrict__ out)
{
  __shared__ float red[4];
  const int bc = blockIdx.x;            // 0..11
  const int b = bc / 3, c = bc % 3;
  const int tid = threadIdx.x;
  const int lane = tid & 63, wv = tid >> 6;

  float4 w2 = make_float4(0.f, 0.f, 0.f, 0.f);
  const float* fcr = fc_w + c * 512;
  const float* owp = out_w1 + tid * 4;
  for (int dm = 0; dm < 512; ++dm) {
    float f = fcr[dm];
    float4 o = *(const float4*)(owp + (size_t)dm * 1024);
    w2.x = fmaf(f, o.x, w2.x); w2.y = fmaf(f, o.y, w2.y);
    w2.z = fmaf(f, o.z, w2.z); w2.w = fmaf(f, o.w, w2.w);
  }
  const _Float16* yr = y16 + ((size_t)(b * 1024 + 1023) << 10) + tid * 4;
  half4v yv = *(const half4v*)yr;
  float s = (float)yv[0] * w2.x + (float)yv[1] * w2.y
          + (float)yv[2] * w2.z + (float)yv[3] * w2.w;
  #pragma unroll
  for (int o = 32; o > 0; o >>= 1) s += __shfl_xor(s, o, 64);
  if (lane == 0) red[wv] = s;
  __syncthreads();
  if (tid == 0)
    out[b * 3 + c] = (red[0] + red[1] + red[2] + red[3]) * (1.f / Y_SCALE)
                     + fc_b[c];
}

extern "C" void kernel_launch(void* const* d_in, const int* in_sizes, int n_in,
                              void* d_out, int out_size, void* d_ws, size_t ws_size,
                              hipStream_t stream)
{
  const float* x        = (const float*)d_in[0];
  const float* exp_w    = (const float*)d_in[1];
  const float* exp_b    = (const float*)d_in[2];
  const float* in_w     = (const float*)d_in[3];
  const float* conv_w   = (const float*)d_in[4];
  const float* conv_b   = (const float*)d_in[5];
  const float* xproj_w  = (const float*)d_in[6];
  const float* dtproj_w = (const float*)d_in[7];
  const float* dtproj_b = (const float*)d_in[8];
  const float* A_log    = (const float*)d_in[9];
  const float* Dp       = (const float*)d_in[10];
  const float* out_w    = (const float*)d_in[11];
  const float* fc_w     = (const float*)d_in[12];
  const float* fc_b     = (const float*)d_in[13];
  float* out = (float*)d_out;

  // Workspace layout (byte offsets), 72 MB total.
  // 4..20 MB region sequentially reused: xcpre16 (8MB) -> dtT (16MB).
  char* ws = (char*)d_ws;
  _Float16* hf16    = (_Float16*)(ws);                        //  4 MB [4096][512] f16
  _Float16* xcpre16 = (_Float16*)(ws + ((size_t)4  << 20));   //  8 MB [4096][1024] f16
  float*    dtT     = (float*)   (ws + ((size_t)4  << 20));   // 16 MB [1024][4096] (reuse)
  float*    xcT     = (float*)   (ws + ((size_t)20 << 20));   // 16 MB [1024][4096]
  _Float16* zsT     = (_Float16*)(ws + ((size_t)36 << 20));   //  8 MB [1024][4096]
  float*    Bsc     = (float*)   (ws + ((size_t)44 << 20));   //  2 MB [4][256][64][4] B then C
  _Float16* dtr16   = (_Float16*)(ws + ((size_t)47 << 20));   //  0.25 MB [4096][32]
  _Float16* xc16    = (_Float16*)(ws + ((size_t)48 << 20));   //  8 MB [4096][1024]
  _Float16* y16     = (_Float16*)(ws + ((size_t)56 << 20));   //  8 MB [4096][1024]
  _Float16* w16     = (_Float16*)(ws + ((size_t)64 << 20));   //  7.9 MB f16 pool

  _Float16* exp16 = w16;                 // [512][128]
  _Float16* in16  = w16 + 65536;         // [2][2048][512]
  _Float16* xp16  = w16 + 2162688;       // [2][160][1024]
  _Float16* dt16  = w16 + 2490368;       // [2][1024][32]
  _Float16* out16 = w16 + 2555904;       // [2][512][1024]
  _Float16* x16   = w16 + 3604480;       // [4096][128]

  dim3 blk(256);

  // one-shot f16 conversion of all weights + x (4128768 elems, 4032 blocks)
  wcvt_kernel<<<4032, blk, 0, stream>>>(exp_w, in_w, xproj_w, dtproj_w, out_w,
                                        x, w16);

  // expand: hf16 = f16(x @ exp_w^T + exp_b)   [4096,512] K=128, BK=32.
  gemm_mfma<64,32,0,1,0><<<dim3(8,64), blk, 0, stream>>>(x16, 128, exp16, exp_b,
                                                         hf16, 512, 512, 128, 1.f,
                                                         nullptr);

  for (int l = 0; l < 2; ++l) {
    const float is = l ? (1.f / H1_SCALE) : 1.f;     // undo h1 scaling (exact)
    // fused in_proj: xcpre16 f16 + zsT f16 (Tz aliases Ws). N=2048 K=512 BK=64.
    gemm_mfma<128,64,0,0,1><<<dim3(16,64), blk, 0, stream>>>(hf16, 512,
                                                             in16 + (size_t)l*1048576,
                                                             nullptr, xcpre16, 1024,
                                                             2048, 512, is, zsT);
    // conv + silu -> xcT (fp32, scan) + xc16 (f16, xproj A)
    conv_t_kernel<<<1024, blk, 0, stream>>>(xcpre16, conv_w + l*2048, conv_b + l*1024,
                                            xcT, xc16);
    // xproj (MODE 2): dtr16 f16 [4096][32] + Bsc/Csc scan layout. K=1024 BK=64.
    gemm_mfma<64,64,0,0,2><<<dim3(3,64), blk, 0, stream>>>(xc16, 1024,
                                                           xp16 + (size_t)l*163840,
                                                           nullptr, Bsc, 160,
                                                           160, 1024, 1.f, dtr16);
    // dtproj (MODE 3): dtT [1024][4096] softplus, LDS-transposed. K=32 BK=32.
    gemm_mfma<64,32,0,0,3><<<dim3(16,64), blk, 0, stream>>>(dtr16, 32,
                                                            dt16 + (size_t)l*32768,
                                                            dtproj_b + l*1024,
                                                            dtT, 4096, 1024, 32, 1.f,
                                                            nullptr);
    // selective scan v7 (4-deep LDS staging pipeline)
    scan_kernel<<<1024, blk, 0, stream>>>(dtT, xcT, zsT, Bsc,
                                          A_log + (size_t)l*65536, Dp + l*1024, y16);
    // out_proj only for layer 0 (layer-1 h only matters at t=L-1 -> head2)
    if (l == 0)
      gemm_mfma<64,64,0,1,0><<<dim3(8,64), blk, 0, stream>>>(y16, 1024,
                                                             out16, nullptr,
                                                             hf16, 512, 512, 1024,
                                                             H1_SCALE / Y_SCALE,
                                                             nullptr);
  }

  // fused out_proj(l1) + fc head from y16(l1) directly (fp32 weights)
  head2_kernel<<<12, blk, 0, stream>>>(y16, out_w + (size_t)512*1024,
                                       fc_w, fc_b, out);
}

// Round 10
// 437.415 us; speedup vs baseline: 1.2385x; 1.2030x over previous
//
#include <hip/hip_runtime.h>
#include <math.h>

// Problem constants: B=4, L=1024, D_IN=128, D_MODEL=512, N_LAYERS=2,
// N_CLASSES=3, D_INNER=1024, D_STATE=64, D_CONV=2, DT_RANK=32, BL=4096.
//
// Precision plan: all GEMM operands f16 (conversions hoisted upstream).
// Layer-1 residual h f16 scaled by 2^8 (exact). y scaled by 2^14 at the
// scan store. Head works from y16(l1) directly with fp32 weights.
//
// R25 (resubmit after broker timeout): scan v8 — evidence recap: R20
// (compiler-scheduled loads + sched barriers) = 108us is the best of 6
// structures; asm-VMEM (164) and LDS staging x2/x4 (155/154,
// depth-invariant) all lose to their own overhead. R20's secret:
// wave-uniform dt/x float4s become SMEM s_loads (separate lgkm queue).
// Remaining R20 stall = per-chunk serial tail (h-chain -> ds_writes ->
// lgkm -> P-read -> 3 dependent shfl -> y). v8 = R20 base + chain/reduce
// split with double P-buffers: reduce(k) is deferred one chunk and
// co-scheduled with chain(k+1) (VALU hides LDS/shfl latency and vice
// versa). Same instruction count as R20.

using half8  = __attribute__((ext_vector_type(8))) _Float16;
using half4v = __attribute__((ext_vector_type(4))) _Float16;
using f32x4  = __attribute__((ext_vector_type(4))) float;

#define Y_SCALE 16384.0f   // 2^14
#define H1_SCALE 256.0f    // 2^8

__device__ __forceinline__ float silu_f(float v) {
  return v / (1.f + __expf(-v));
}

__device__ __forceinline__ float fast_exp2(float x) {
#if __has_builtin(__builtin_amdgcn_exp2f)
  return __builtin_amdgcn_exp2f(x);
#else
  return __expf(x * 0.69314718055994531f);
#endif
}

// ---------------------------------------------------------------------------
// One-shot fp32 -> f16 conversion of all weights + x into the w16 pool.
//   exp_w 0..65536 | in_w ..2162688 | xproj_w ..2490368 | dtproj_w ..2555904
//   | out_w ..3604480 | x ..4128768
// ---------------------------------------------------------------------------
__global__ void wcvt_kernel(const float* __restrict__ exp_w,
                            const float* __restrict__ in_w,
                            const float* __restrict__ xproj_w,
                            const float* __restrict__ dtproj_w,
                            const float* __restrict__ out_w,
                            const float* __restrict__ x,
                            _Float16* __restrict__ w16)
{
  size_t gi = ((size_t)blockIdx.x * 256 + threadIdx.x) * 4;
  const float* src; size_t off;
  if      (gi < 65536)   { src = exp_w;    off = gi; }
  else if (gi < 2162688) { src = in_w;     off = gi - 65536; }
  else if (gi < 2490368) { src = xproj_w;  off = gi - 2162688; }
  else if (gi < 2555904) { src = dtproj_w; off = gi - 2490368; }
  else if (gi < 3604480) { src = out_w;    off = gi - 2555904; }
  else                   { src = x;        off = gi - 3604480; }
  float4 v = *(const float4*)(src + off);
  half4v h;
  h[0] = (_Float16)v.x; h[1] = (_Float16)v.y;
  h[2] = (_Float16)v.z; h[3] = (_Float16)v.w;
  *(half4v*)(w16 + gi) = h;
}

// ---------------------------------------------------------------------------
// f16 MFMA GEMM, 64 x BN tile, BK-chunk K-loop. Block 256 thr = 4 waves;
// wave-tile 32 x (BN/2), MI=2 m-frags. BK in {32,64}.
// Modes: 0 plain / 1 in_proj fused (REQUIRES BK=64, BN=128; Tz aliases Ws) /
// 2 xproj split (dtr16 + Bsc/Csc scan layout) / 3 dtproj transposed-softplus.
// MFMA layouts (m89/m120-verified): A-frag A[m=lane&15][k=q*8+j],
// B-frag B[k=q*8+j][n=lane&15], D: col(n)=lane&15, row(m)=q*4+r.
// ---------------------------------------------------------------------------
template<int BN, int BK, int ACT, int OF16, int MODE>
__global__ __launch_bounds__(256)
void gemm_mfma(const _Float16* __restrict__ A, int lda,
               const _Float16* __restrict__ W,
               const float* __restrict__ bias,
               void* __restrict__ Cv, int ldc,
               int N, int K, float oscale,
               void* __restrict__ Cv2)
{
  static_assert(MODE != 1 || (BK == 64 && BN == 128), "MODE1 needs BK=64/BN=128");
  constexpr int NF  = BN / 32;           // n-frags per wave
  constexpr int LS  = BK + 8;            // LDS row stride in halfs (16B-aligned)
  constexpr int NA  = BK / 32;           // A half8 regs per thread
  constexpr int WTR = 256 / BN;          // threads per W row
  constexpr int WH  = BK / WTR;          // W halfs per thread (R18b fix)
  constexpr int NW  = WH / 8;            // W half8 regs per thread
  static_assert(NA >= 1 && NW >= 1, "staging arithmetic");

  __shared__ _Float16 As[64 * LS];
  __shared__ _Float16 Ws[BN * LS];       // MODE1: reused as Tz in epilogue
  __shared__ float    Td[(MODE == 3) ? 64 * 68 : 2];
  const int tid  = threadIdx.x;
  const int lane = tid & 63;
  const int wid  = tid >> 6;
  const int wm   = wid & 1, wn = wid >> 1;   // wave-tile: 32 m x BN/2 n
  const int m0   = blockIdx.y * 64;
  const int n0   = blockIdx.x * BN;
  const int q    = lane >> 4, l16 = lane & 15;

  // staging coords
  const int ar  = tid >> 2;                  // A: 4 thr/row
  const int akq = (tid & 3) * (BK / 4);
  const int wr  = tid / WTR;
  const int wkq = (tid % WTR) * WH;
  const int wrow = n0 + wr;
  const bool wv  = (wrow < N);

  const _Float16* Wp = W + (size_t)wrow * K;
  const size_t aoff = (size_t)(m0 + ar) * lda + akq;

  half8 zh;
  #pragma unroll
  for (int i = 0; i < 8; ++i) zh[i] = (_Float16)0.f;

  // initial loads (k0 = 0)
  half8 rah[NA], rwh[NW];
  #pragma unroll
  for (int i = 0; i < NA; ++i) rah[i] = *(const half8*)(A + aoff + i * 8);
  #pragma unroll
  for (int j = 0; j < NW; ++j)
    rwh[j] = wv ? *(const half8*)(Wp + wkq + j * 8) : zh;

  f32x4 acc[2][NF];
  #pragma unroll
  for (int mi = 0; mi < 2; ++mi)
    #pragma unroll
    for (int ni = 0; ni < NF; ++ni)
      acc[mi][ni] = (f32x4){0.f, 0.f, 0.f, 0.f};

  for (int k0 = 0; k0 < K; k0 += BK) {
    if (k0) __syncthreads();
    #pragma unroll
    for (int i = 0; i < NA; ++i)
      *(half8*)&As[ar * LS + akq + i * 8] = rah[i];
    #pragma unroll
    for (int j = 0; j < NW; ++j)
      *(half8*)&Ws[wr * LS + wkq + j * 8] = rwh[j];
    __syncthreads();

    if (k0 + BK < K) {            // prefetch next chunk
      const int kn = k0 + BK;
      #pragma unroll
      for (int i = 0; i < NA; ++i)
        rah[i] = *(const half8*)(A + aoff + kn + i * 8);
      if (wv) {
        #pragma unroll
        for (int j = 0; j < NW; ++j)
          rwh[j] = *(const half8*)(Wp + kn + wkq + j * 8);
      }
    }

    #pragma unroll
    for (int kk = 0; kk < BK / 32; ++kk) {
      half8 af[2], wf[NF];
      #pragma unroll
      for (int mi = 0; mi < 2; ++mi)
        af[mi] = *(const half8*)&As[(wm * 32 + mi * 16 + l16) * LS + kk * 32 + q * 8];
      #pragma unroll
      for (int ni = 0; ni < NF; ++ni)
        wf[ni] = *(const half8*)&Ws[(wn * (BN / 2) + ni * 16 + l16) * LS + kk * 32 + q * 8];
      #pragma unroll
      for (int mi = 0; mi < 2; ++mi)
        #pragma unroll
        for (int ni = 0; ni < NF; ++ni)
          acc[mi][ni] = __builtin_amdgcn_mfma_f32_16x16x32_f16(af[mi], wf[ni],
                                                               acc[mi][ni], 0, 0, 0);
    }
  }

  float*    Cf = (float*)Cv;
  _Float16* Ch = (_Float16*)Cv;

  if (MODE == 1) {
    if (n0 < 1024) {
      // xc half: f16 [M][1024]
      #pragma unroll
      for (int ni = 0; ni < NF; ++ni) {
        const int n = n0 + wn * (BN / 2) + ni * 16 + l16;
        #pragma unroll
        for (int mi = 0; mi < 2; ++mi) {
          const int mb = m0 + wm * 32 + mi * 16 + q * 4;
          #pragma unroll
          for (int r = 0; r < 4; ++r)
            Ch[(size_t)(mb + r) * 1024 + n] = (_Float16)(acc[mi][ni][r] * oscale);
        }
      }
    } else {
      // z half: silu -> f16, LDS transpose (Tz aliases Ws; LS==72),
      // coalesced 16B row stores
      _Float16* Tz = Ws;
      _Float16* Ch2 = (_Float16*)Cv2;
      __syncthreads();                  // all MFMA reads of Ws done
      #pragma unroll
      for (int ni = 0; ni < NF; ++ni) {
        const int nnl = wn * (BN / 2) + ni * 16 + l16;   // 0..127 local
        #pragma unroll
        for (int mi = 0; mi < 2; ++mi) {
          const int mbl = wm * 32 + mi * 16 + q * 4;     // 0..63 local
          half4v h4;
          #pragma unroll
          for (int r = 0; r < 4; ++r)
            h4[r] = (_Float16)silu_f(acc[mi][ni][r] * oscale);
          *(half4v*)&Tz[nnl * LS + mbl] = h4;
        }
      }
      __syncthreads();
      const int sr = tid >> 3;          // 0..31
      const int sc = (tid & 7) * 8;     // halfs 0..56
      #pragma unroll
      for (int rd = 0; rd < 4; ++rd) {
        const int row = rd * 32 + sr;
        half8 v = *(const half8*)&Tz[row * LS + sc];
        *(half8*)&Ch2[(size_t)(n0 - 1024 + row) * 4096 + m0 + sc] = v;
      }
    }
    return;
  }

  if (MODE == 2) {
    // xproj split:
    //   n <  32           -> dtr16 f16 [M][32]           (via Cv2)
    //   32 <= n <  96     -> Bsc scan layout             (via Cv)
    //   96 <= n < 160     -> Csc = Bsc + 262144
    // Scan layout: [b*256 + t/4][s 0..63][t&3] fp32. mb%4==0 so the 4 acc
    // components (rows mb..mb+3) form one contiguous float4 at s*4.
    float* Bs = Cf;
    _Float16* dtr = (_Float16*)Cv2;
    #pragma unroll
    for (int ni = 0; ni < NF; ++ni) {
      const int n = n0 + wn * (BN / 2) + ni * 16 + l16;
      #pragma unroll
      for (int mi = 0; mi < 2; ++mi) {
        const int mb = m0 + wm * 32 + mi * 16 + q * 4;
        if (n < 32) {
          #pragma unroll
          for (int r = 0; r < 4; ++r)
            dtr[(size_t)(mb + r) * 32 + n] = (_Float16)acc[mi][ni][r];
        } else if (n < 160) {
          const int s = (n < 96) ? (n - 32) : (n - 96);
          float* dst = Bs + ((n < 96) ? 0 : 262144);
          float4 v = make_float4(acc[mi][ni][0], acc[mi][ni][1],
                                 acc[mi][ni][2], acc[mi][ni][3]);
          *(float4*)&dst[((size_t)(mb >> 2) << 8) + s * 4] = v;
        }
      }
    }
    return;
  }

  if (MODE == 3) {
    // dtproj: softplus(acc*oscale + bias) -> fp32 [N][4096] via LDS transpose
    __syncthreads();
    #pragma unroll
    for (int ni = 0; ni < NF; ++ni) {
      const int nnl = wn * (BN / 2) + ni * 16 + l16;     // 0..63 local
      const float bv = (bias != nullptr) ? bias[n0 + nnl] : 0.f;
      #pragma unroll
      for (int mi = 0; mi < 2; ++mi) {
        const int mbl = wm * 32 + mi * 16 + q * 4;       // 0..63 local
        float o[4];
        #pragma unroll
        for (int r = 0; r < 4; ++r) {
          float v = acc[mi][ni][r] * oscale + bv;
          o[r] = (v > 20.f) ? v : log1pf(__expf(v));     // softplus
        }
        *(float4*)&Td[nnl * 68 + mbl] = make_float4(o[0], o[1], o[2], o[3]);
      }
    }
    __syncthreads();
    const int sr = tid >> 4;            // 0..15
    const int sc = (tid & 15) * 4;      // floats 0..60
    #pragma unroll
    for (int rd = 0; rd < 4; ++rd) {
      const int row = rd * 16 + sr;
      float4 v = *(const float4*)&Td[row * 68 + sc];
      *(float4*)&Cf[(size_t)(n0 + row) * 4096 + m0 + sc] = v;
    }
    return;
  }

  // MODE 0 epilogue
  #pragma unroll
  for (int ni = 0; ni < NF; ++ni) {
    const int n = n0 + wn * (BN / 2) + ni * 16 + l16;
    if (n < N) {
      const float bv = (bias != nullptr) ? bias[n] : 0.f;
      #pragma unroll
      for (int mi = 0; mi < 2; ++mi) {
        const int mb = m0 + wm * 32 + mi * 16 + q * 4;
        #pragma unroll
        for (int r = 0; r < 4; ++r) {
          float v = acc[mi][ni][r] * oscale + bv;
          if (ACT == 1) v = (v > 20.f) ? v : log1pf(__expf(v));
          if (ACT == 2) v = silu_f(v);
          size_t off = (size_t)(mb + r) * ldc + n;
          if (OF16) Ch[off] = (_Float16)v;
          else      Cf[off] = v;
        }
      }
    }
  }
}

// ---------------------------------------------------------------------------
// Depthwise causal conv (D_CONV=2) + silu, 64x64 LDS transpose.
// in : xcp [4096 bl][1024 d] f16
// out: xcT [1024 d][4096 bl] fp32 (scan input)  +  xcf [4096 bl][1024 d] f16
// ---------------------------------------------------------------------------
__global__ void conv_t_kernel(const _Float16* __restrict__ xcp,
                              const float* __restrict__ cw,   // [1024][2]
                              const float* __restrict__ cb,   // [1024]
                              float* __restrict__ xcT,
                              _Float16* __restrict__ xcf)
{
  __shared__ float tile[64][65];
  const int blk = blockIdx.x;            // b*256 + tt*16 + dd
  const int b  = blk >> 8;
  const int tt = (blk >> 4) & 15;
  const int dd = blk & 15;
  const int t0 = tt * 64, d0 = dd * 64;
  const int tid = threadIdx.x;

  #pragma unroll
  for (int i = 0; i < 16; ++i) {
    int idx = i * 256 + tid;
    int t = idx >> 6, d = idx & 63;
    int gt = t0 + t;
    size_t rcur = ((size_t)(b * 1024 + gt) << 10) + d0 + d;
    float cur  = (float)xcp[rcur];
    float prev = (gt > 0) ? (float)xcp[rcur - 1024] : 0.f;
    float v = fmaf(prev, cw[(d0+d)*2], fmaf(cur, cw[(d0+d)*2 + 1], cb[d0+d]));
    float sv = silu_f(v);
    tile[t][d] = sv;
    xcf[rcur] = (_Float16)sv;
  }
  __syncthreads();
  #pragma unroll
  for (int i = 0; i < 16; ++i) {
    int idx = i * 256 + tid;
    int d = idx >> 6, t = idx & 63;
    xcT[((size_t)(d0 + d) << 12) + b * 1024 + t0 + t] = tile[t][d];
  }
}

// ---------------------------------------------------------------------------
// Selective scan v8, time-major. One wave per (b,d), lane = s (D_STATE=64).
// R20 base (C++ float4 loads -> compiler emits SMEM s_loads for the
// wave-uniform dt/x streams; sched_barrier region pinning), plus a
// chain/reduce software pipeline: chunk k's reduce (P-read + 3 shfl + y
// store, ~400 serial cycles of LDS latency) is deferred one chunk and
// co-scheduled with chunk k+1's chain (pure VALU). Double P buffers;
// zs/xvl carried in registers across the deferral. Barrier-free (P is
// wave-private, DS ops wave-ordered).
// ---------------------------------------------------------------------------
struct Chunk {
  float4 Bq0, Bq1, Cq0, Cq1, dq0, dq1, xq0, xq1;
  float zs, xvl;
};

__device__ __forceinline__ void load_chunk(int t0, Chunk& c,
    const float* __restrict__ Bb, const float* __restrict__ Cbp,
    const float* __restrict__ dtp, const float* __restrict__ xp,
    const _Float16* __restrict__ zsp, int tt_r)
{
  const float* Bp = Bb  + (((size_t)t0 >> 2) << 8);   // t0*64 floats
  const float* Cp = Cbp + (((size_t)t0 >> 2) << 8);
  c.Bq0 = *(const float4*)(Bp);        c.Bq1 = *(const float4*)(Bp + 256);
  c.Cq0 = *(const float4*)(Cp);        c.Cq1 = *(const float4*)(Cp + 256);
  c.dq0 = *(const float4*)(dtp + t0);  c.dq1 = *(const float4*)(dtp + t0 + 4);
  c.xq0 = *(const float4*)(xp + t0);   c.xq1 = *(const float4*)(xp + t0 + 4);
  c.zs  = (float)zsp[t0 + tt_r] * Y_SCALE;   // exact 2^14 fold
  c.xvl = xp[t0 + tt_r];
}

// chain phase: dA/ub prep + serial h-recurrence + P writes. No reduction.
__device__ __forceinline__ void chain_chunk(const Chunk& c, float& h,
    float al2, float (*Pw)[68], int lane)
{
  float dvv[8] = {c.dq0.x, c.dq0.y, c.dq0.z, c.dq0.w,
                  c.dq1.x, c.dq1.y, c.dq1.z, c.dq1.w};
  float xvv[8] = {c.xq0.x, c.xq0.y, c.xq0.z, c.xq0.w,
                  c.xq1.x, c.xq1.y, c.xq1.z, c.xq1.w};
  float Bvv[8] = {c.Bq0.x, c.Bq0.y, c.Bq0.z, c.Bq0.w,
                  c.Bq1.x, c.Bq1.y, c.Bq1.z, c.Bq1.w};
  float Cvv[8] = {c.Cq0.x, c.Cq0.y, c.Cq0.z, c.Cq0.w,
                  c.Cq1.x, c.Cq1.y, c.Cq1.z, c.Cq1.w};
  float dA[8], ub[8];
  #pragma unroll
  for (int tt = 0; tt < 8; ++tt) {
    dA[tt] = fast_exp2(dvv[tt] * al2);
    ub[tt] = dvv[tt] * xvv[tt] * Bvv[tt];
  }
  #pragma unroll
  for (int tt = 0; tt < 8; ++tt) {
    h = fmaf(h, dA[tt], ub[tt]);
    Pw[tt][lane] = h * Cvv[tt];
  }
}

// reduce phase (deferred one chunk): P-read, lane-tree + 3 shfl, y store.
__device__ __forceinline__ void reduce_chunk(int t0, float (*Pw)[68],
    float zs, float xvl, float dpv, _Float16* __restrict__ yp,
    int lane, int tt_r, int c0)
{
  float4 s0 = *(const float4*)&Pw[tt_r][c0];
  float4 s1 = *(const float4*)&Pw[tt_r][c0 + 4];
  float r = ((s0.x + s0.y) + (s0.z + s0.w)) + ((s1.x + s1.y) + (s1.z + s1.w));
  r += __shfl_xor(r, 1, 64);
  r += __shfl_xor(r, 2, 64);
  r += __shfl_xor(r, 4, 64);
  if ((lane & 7) == 0)
    yp[(size_t)(t0 + tt_r) << 10] = (_Float16)(fmaf(xvl, dpv, r) * zs);
}

__global__ __launch_bounds__(256, 4)
void scan_kernel(const float* __restrict__ dtT,     // [1024][4096]
                 const float* __restrict__ xcT,     // [1024][4096]
                 const _Float16* __restrict__ zsT,  // [1024][4096], silu(z), f16
                 const float* __restrict__ Bsc,     // [4][256][64][4]; Csc at +262144
                 const float* __restrict__ A_log,   // [1024][64]
                 const float* __restrict__ Dp,      // [1024]
                 _Float16* __restrict__ y16)        // [4096 bl][1024 d], y*2^14
{
  __shared__ float P[4][2][8][68];     // per-wave double reduction tiles
  const int tid  = threadIdx.x;
  const int lane = tid & 63;
  const int wrp  = tid >> 6;
  const int rb   = blockIdx.x;
  const int bswz = ((rb & 7) << 7) | (rb >> 3);          // XCD swizzle
  const int wid  = __builtin_amdgcn_readfirstlane(bswz * 4 + wrp);
  const int b = wid >> 10;
  const int d = wid & 1023;
  float (*P0)[68] = P[wrp][0];
  float (*P1)[68] = P[wrp][1];

  const float a   = -__expf(A_log[d * 64 + lane]);
  const float al2 = a * 1.44269504088896f;               // hoisted log2(e)
  const float dpv = Dp[d];
  const size_t row = ((size_t)d << 12) + b * 1024;
  const float*    dtp = dtT + row;
  const float*    xp  = xcT + row;
  const _Float16* zsp = zsT + row;
  _Float16*       yp  = y16 + ((size_t)b << 20) + d;     // + t*1024
  const float*    Bb  = Bsc + ((size_t)b << 16) + lane * 4;
  const float*    Cbp = Bb + 262144;

  const int tt_r = lane >> 3;          // timestep this lane reduces
  const int c0   = (lane & 7) << 3;    // its 8-state column base

  float h = 0.f;
  Chunk ca, cb;
  float zs0, xv0, zs1, xv1;

  // prologue: chunks 0 (ca) and 1 (cb); chain chunk 0 into P0.
  load_chunk(0, ca, Bb, Cbp, dtp, xp, zsp, tt_r);
  load_chunk(8, cb, Bb, Cbp, dtp, xp, zsp, tt_r);
  chain_chunk(ca, h, al2, P0, lane);
  zs0 = ca.zs; xv0 = ca.xvl;
  __builtin_amdgcn_sched_barrier(0);

  // steady state, 2 chunks per iteration (static P-buffer indices):
  //   stage A: load(k+2 -> ca) | chain(k+1 = cb -> P1) | reduce(k via P0)
  //   stage B: load(k+3 -> cb) | chain(k+2 = ca -> P0) | reduce(k+1 via P1)
  // The reduce's LDS/shfl latency hides under the chain's VALU and the
  // load issue; the only cross-chunk serial path is the h-chain.
  for (int t0 = 0; t0 < 1008; t0 += 16) {
    load_chunk(t0 + 16, ca, Bb, Cbp, dtp, xp, zsp, tt_r);
    chain_chunk(cb, h, al2, P1, lane);
    zs1 = cb.zs; xv1 = cb.xvl;
    reduce_chunk(t0, P0, zs0, xv0, dpv, yp, lane, tt_r, c0);
    __builtin_amdgcn_sched_barrier(0);

    load_chunk(t0 + 24, cb, Bb, Cbp, dtp, xp, zsp, tt_r);  // t0+24 <= 1016
    chain_chunk(ca, h, al2, P0, lane);
    zs0 = ca.zs; xv0 = ca.xvl;
    reduce_chunk(t0 + 8, P1, zs1, xv1, dpv, yp, lane, tt_r, c0);
    __builtin_amdgcn_sched_barrier(0);
  }
  // epilogue: chunk 127 (cb) chain, then the two pending reduces.
  chain_chunk(cb, h, al2, P1, lane);
  zs1 = cb.zs; xv1 = cb.xvl;
  reduce_chunk(1008, P0, zs0, xv0, dpv, yp, lane, tt_r, c0);
  reduce_chunk(1016, P1, zs1, xv1, dpv, yp, lane, tt_r, c0);
}

// ---------------------------------------------------------------------------
// Fused out_proj(l1)+fc head: only h[b, L-1, :] reaches the output.
// out[b,c] = (sum_di y16l1[b*1024+1023][di] * w2[c][di]) * 2^-14 + fc_b[c],
// w2[c][di] = sum_dm fc_w[c][dm] * out_w1[dm][di]   (fp32 weights).
// ---------------------------------------------------------------------------
__global__ void head2_kernel(const _Float16* __restrict__ y16,
                             const float* __restrict__ out_w1,  // [512][1024]
                             const float* __restrict__ fc_w,    // [3][512]
                             const float* __restrict__ fc_b,
                             float* __restrict__ out)
{
  __shared__ float red[4];
  const int bc = blockIdx.x;            // 0..11
  const int b = bc / 3, c = bc % 3;
  const int tid = threadIdx.x;
  const int lane = tid & 63, wv = tid >> 6;

  float4 w2 = make_float4(0.f, 0.f, 0.f, 0.f);
  const float* fcr = fc_w + c * 512;
  const float* owp = out_w1 + tid * 4;
  for (int dm = 0; dm < 512; ++dm) {
    float f = fcr[dm];
    float4 o = *(const float4*)(owp + (size_t)dm * 1024);
    w2.x = fmaf(f, o.x, w2.x); w2.y = fmaf(f, o.y, w2.y);
    w2.z = fmaf(f, o.z, w2.z); w2.w = fmaf(f, o.w, w2.w);
  }
  const _Float16* yr = y16 + ((size_t)(b * 1024 + 1023) << 10) + tid * 4;
  half4v yv = *(const half4v*)yr;
  float s = (float)yv[0] * w2.x + (float)yv[1] * w2.y
          + (float)yv[2] * w2.z + (float)yv[3] * w2.w;
  #pragma unroll
  for (int o = 32; o > 0; o >>= 1) s += __shfl_xor(s, o, 64);
  if (lane == 0) red[wv] = s;
  __syncthreads();
  if (tid == 0)
    out[b * 3 + c] = (red[0] + red[1] + red[2] + red[3]) * (1.f / Y_SCALE)
                     + fc_b[c];
}

extern "C" void kernel_launch(void* const* d_in, const int* in_sizes, int n_in,
                              void* d_out, int out_size, void* d_ws, size_t ws_size,
                              hipStream_t stream)
{
  const float* x        = (const float*)d_in[0];
  const float* exp_w    = (const float*)d_in[1];
  const float* exp_b    = (const float*)d_in[2];
  const float* in_w     = (const float*)d_in[3];
  const float* conv_w   = (const float*)d_in[4];
  const float* conv_b   = (const float*)d_in[5];
  const float* xproj_w  = (const float*)d_in[6];
  const float* dtproj_w = (const float*)d_in[7];
  const float* dtproj_b = (const float*)d_in[8];
  const float* A_log    = (const float*)d_in[9];
  const float* Dp       = (const float*)d_in[10];
  const float* out_w    = (const float*)d_in[11];
  const float* fc_w     = (const float*)d_in[12];
  const float* fc_b     = (const float*)d_in[13];
  float* out = (float*)d_out;

  // Workspace layout (byte offsets), 72 MB total.
  // 4..20 MB region sequentially reused: xcpre16 (8MB) -> dtT (16MB).
  char* ws = (char*)d_ws;
  _Float16* hf16    = (_Float16*)(ws);                        //  4 MB [4096][512] f16
  _Float16* xcpre16 = (_Float16*)(ws + ((size_t)4  << 20));   //  8 MB [4096][1024] f16
  float*    dtT     = (float*)   (ws + ((size_t)4  << 20));   // 16 MB [1024][4096] (reuse)
  float*    xcT     = (float*)   (ws + ((size_t)20 << 20));   // 16 MB [1024][4096]
  _Float16* zsT     = (_Float16*)(ws + ((size_t)36 << 20));   //  8 MB [1024][4096]
  float*    Bsc     = (float*)   (ws + ((size_t)44 << 20));   //  2 MB [4][256][64][4] B then C
  _Float16* dtr16   = (_Float16*)(ws + ((size_t)47 << 20));   //  0.25 MB [4096][32]
  _Float16* xc16    = (_Float16*)(ws + ((size_t)48 << 20));   //  8 MB [4096][1024]
  _Float16* y16     = (_Float16*)(ws + ((size_t)56 << 20));   //  8 MB [4096][1024]
  _Float16* w16     = (_Float16*)(ws + ((size_t)64 << 20));   //  7.9 MB f16 pool

  _Float16* exp16 = w16;                 // [512][128]
  _Float16* in16  = w16 + 65536;         // [2][2048][512]
  _Float16* xp16  = w16 + 2162688;       // [2][160][1024]
  _Float16* dt16  = w16 + 2490368;       // [2][1024][32]
  _Float16* out16 = w16 + 2555904;       // [2][512][1024]
  _Float16* x16   = w16 + 3604480;       // [4096][128]

  dim3 blk(256);

  // one-shot f16 conversion of all weights + x (4128768 elems, 4032 blocks)
  wcvt_kernel<<<4032, blk, 0, stream>>>(exp_w, in_w, xproj_w, dtproj_w, out_w,
                                        x, w16);

  // expand: hf16 = f16(x @ exp_w^T + exp_b)   [4096,512] K=128, BK=32.
  gemm_mfma<64,32,0,1,0><<<dim3(8,64), blk, 0, stream>>>(x16, 128, exp16, exp_b,
                                                         hf16, 512, 512, 128, 1.f,
                                                         nullptr);

  for (int l = 0; l < 2; ++l) {
    const float is = l ? (1.f / H1_SCALE) : 1.f;     // undo h1 scaling (exact)
    // fused in_proj: xcpre16 f16 + zsT f16 (Tz aliases Ws). N=2048 K=512 BK=64.
    gemm_mfma<128,64,0,0,1><<<dim3(16,64), blk, 0, stream>>>(hf16, 512,
                                                             in16 + (size_t)l*1048576,
                                                             nullptr, xcpre16, 1024,
                                                             2048, 512, is, zsT);
    // conv + silu -> xcT (fp32, scan) + xc16 (f16, xproj A)
    conv_t_kernel<<<1024, blk, 0, stream>>>(xcpre16, conv_w + l*2048, conv_b + l*1024,
                                            xcT, xc16);
    // xproj (MODE 2): dtr16 f16 [4096][32] + Bsc/Csc scan layout. K=1024 BK=64.
    gemm_mfma<64,64,0,0,2><<<dim3(3,64), blk, 0, stream>>>(xc16, 1024,
                                                           xp16 + (size_t)l*163840,
                                                           nullptr, Bsc, 160,
                                                           160, 1024, 1.f, dtr16);
    // dtproj (MODE 3): dtT [1024][4096] softplus, LDS-transposed. K=32 BK=32.
    gemm_mfma<64,32,0,0,3><<<dim3(16,64), blk, 0, stream>>>(dtr16, 32,
                                                            dt16 + (size_t)l*32768,
                                                            dtproj_b + l*1024,
                                                            dtT, 4096, 1024, 32, 1.f,
                                                            nullptr);
    // selective scan v8 (chain/reduce pipelined, R20 base)
    scan_kernel<<<1024, blk, 0, stream>>>(dtT, xcT, zsT, Bsc,
                                          A_log + (size_t)l*65536, Dp + l*1024, y16);
    // out_proj only for layer 0 (layer-1 h only matters at t=L-1 -> head2)
    if (l == 0)
      gemm_mfma<64,64,0,1,0><<<dim3(8,64), blk, 0, stream>>>(y16, 1024,
                                                             out16, nullptr,
                                                             hf16, 512, 512, 1024,
                                                             H1_SCALE / Y_SCALE,
                                                             nullptr);
  }

  // fused out_proj(l1) + fc head from y16(l1) directly (fp32 weights)
  head2_kernel<<<12, blk, 0, stream>>>(y16, out_w + (size_t)512*1024,
                                       fc_w, fc_b, out);
}

// Round 11
// 419.059 us; speedup vs baseline: 1.2928x; 1.0438x over previous
//
#include <hip/hip_runtime.h>
#include <math.h>

// Problem constants: B=4, L=1024, D_IN=128, D_MODEL=512, N_LAYERS=2,
// N_CLASSES=3, D_INNER=1024, D_STATE=64, D_CONV=2, DT_RANK=32, BL=4096.
//
// Precision plan: all GEMM operands f16 (conversions hoisted upstream).
// Layer-1 residual h f16 scaled by 2^8 (exact). y scaled by 2^14 at the
// scan store. Head works from y16(l1) directly with fp32 weights.
//
// R26: scan fixed at its established floor (v8, ~110us; 7 structures all
// issue-bound at 108-164). This round attacks the unprofiled non-scan time:
// (1) head2 was 12 blocks streaming 2MB out_w1 each (~13us) -> split into
//     w2prep (16 blocks, reads out_w1 exactly once, computes all 3 classes)
//     + slim head2 dot vs cached 12KB w2.
// (2) conv: scalar f16 loads (2B/lane) -> half2/float2 vectorized, 16->8
//     iterations both phases.

using half8  = __attribute__((ext_vector_type(8))) _Float16;
using half4v = __attribute__((ext_vector_type(4))) _Float16;
using half2v = __attribute__((ext_vector_type(2))) _Float16;
using f32x4  = __attribute__((ext_vector_type(4))) float;

#define Y_SCALE 16384.0f   // 2^14
#define H1_SCALE 256.0f    // 2^8

__device__ __forceinline__ float silu_f(float v) {
  return v / (1.f + __expf(-v));
}

__device__ __forceinline__ float fast_exp2(float x) {
#if __has_builtin(__builtin_amdgcn_exp2f)
  return __builtin_amdgcn_exp2f(x);
#else
  return __expf(x * 0.69314718055994531f);
#endif
}

// ---------------------------------------------------------------------------
// One-shot fp32 -> f16 conversion of all weights + x into the w16 pool.
//   exp_w 0..65536 | in_w ..2162688 | xproj_w ..2490368 | dtproj_w ..2555904
//   | out_w ..3604480 | x ..4128768
// ---------------------------------------------------------------------------
__global__ void wcvt_kernel(const float* __restrict__ exp_w,
                            const float* __restrict__ in_w,
                            const float* __restrict__ xproj_w,
                            const float* __restrict__ dtproj_w,
                            const float* __restrict__ out_w,
                            const float* __restrict__ x,
                            _Float16* __restrict__ w16)
{
  size_t gi = ((size_t)blockIdx.x * 256 + threadIdx.x) * 4;
  const float* src; size_t off;
  if      (gi < 65536)   { src = exp_w;    off = gi; }
  else if (gi < 2162688) { src = in_w;     off = gi - 65536; }
  else if (gi < 2490368) { src = xproj_w;  off = gi - 2162688; }
  else if (gi < 2555904) { src = dtproj_w; off = gi - 2490368; }
  else if (gi < 3604480) { src = out_w;    off = gi - 2555904; }
  else                   { src = x;        off = gi - 3604480; }
  float4 v = *(const float4*)(src + off);
  half4v h;
  h[0] = (_Float16)v.x; h[1] = (_Float16)v.y;
  h[2] = (_Float16)v.z; h[3] = (_Float16)v.w;
  *(half4v*)(w16 + gi) = h;
}

// ---------------------------------------------------------------------------
// f16 MFMA GEMM, 64 x BN tile, BK-chunk K-loop. Block 256 thr = 4 waves;
// wave-tile 32 x (BN/2), MI=2 m-frags. BK in {32,64}.
// Modes: 0 plain / 1 in_proj fused (REQUIRES BK=64, BN=128; Tz aliases Ws) /
// 2 xproj split (dtr16 + Bsc/Csc scan layout) / 3 dtproj transposed-softplus.
// MFMA layouts (m89/m120-verified): A-frag A[m=lane&15][k=q*8+j],
// B-frag B[k=q*8+j][n=lane&15], D: col(n)=lane&15, row(m)=q*4+r.
// ---------------------------------------------------------------------------
template<int BN, int BK, int ACT, int OF16, int MODE>
__global__ __launch_bounds__(256)
void gemm_mfma(const _Float16* __restrict__ A, int lda,
               const _Float16* __restrict__ W,
               const float* __restrict__ bias,
               void* __restrict__ Cv, int ldc,
               int N, int K, float oscale,
               void* __restrict__ Cv2)
{
  static_assert(MODE != 1 || (BK == 64 && BN == 128), "MODE1 needs BK=64/BN=128");
  constexpr int NF  = BN / 32;           // n-frags per wave
  constexpr int LS  = BK + 8;            // LDS row stride in halfs (16B-aligned)
  constexpr int NA  = BK / 32;           // A half8 regs per thread
  constexpr int WTR = 256 / BN;          // threads per W row
  constexpr int WH  = BK / WTR;          // W halfs per thread (R18b fix)
  constexpr int NW  = WH / 8;            // W half8 regs per thread
  static_assert(NA >= 1 && NW >= 1, "staging arithmetic");

  __shared__ _Float16 As[64 * LS];
  __shared__ _Float16 Ws[BN * LS];       // MODE1: reused as Tz in epilogue
  __shared__ float    Td[(MODE == 3) ? 64 * 68 : 2];
  const int tid  = threadIdx.x;
  const int lane = tid & 63;
  const int wid  = tid >> 6;
  const int wm   = wid & 1, wn = wid >> 1;   // wave-tile: 32 m x BN/2 n
  const int m0   = blockIdx.y * 64;
  const int n0   = blockIdx.x * BN;
  const int q    = lane >> 4, l16 = lane & 15;

  // staging coords
  const int ar  = tid >> 2;                  // A: 4 thr/row
  const int akq = (tid & 3) * (BK / 4);
  const int wr  = tid / WTR;
  const int wkq = (tid % WTR) * WH;
  const int wrow = n0 + wr;
  const bool wv  = (wrow < N);

  const _Float16* Wp = W + (size_t)wrow * K;
  const size_t aoff = (size_t)(m0 + ar) * lda + akq;

  half8 zh;
  #pragma unroll
  for (int i = 0; i < 8; ++i) zh[i] = (_Float16)0.f;

  // initial loads (k0 = 0)
  half8 rah[NA], rwh[NW];
  #pragma unroll
  for (int i = 0; i < NA; ++i) rah[i] = *(const half8*)(A + aoff + i * 8);
  #pragma unroll
  for (int j = 0; j < NW; ++j)
    rwh[j] = wv ? *(const half8*)(Wp + wkq + j * 8) : zh;

  f32x4 acc[2][NF];
  #pragma unroll
  for (int mi = 0; mi < 2; ++mi)
    #pragma unroll
    for (int ni = 0; ni < NF; ++ni)
      acc[mi][ni] = (f32x4){0.f, 0.f, 0.f, 0.f};

  for (int k0 = 0; k0 < K; k0 += BK) {
    if (k0) __syncthreads();
    #pragma unroll
    for (int i = 0; i < NA; ++i)
      *(half8*)&As[ar * LS + akq + i * 8] = rah[i];
    #pragma unroll
    for (int j = 0; j < NW; ++j)
      *(half8*)&Ws[wr * LS + wkq + j * 8] = rwh[j];
    __syncthreads();

    if (k0 + BK < K) {            // prefetch next chunk
      const int kn = k0 + BK;
      #pragma unroll
      for (int i = 0; i < NA; ++i)
        rah[i] = *(const half8*)(A + aoff + kn + i * 8);
      if (wv) {
        #pragma unroll
        for (int j = 0; j < NW; ++j)
          rwh[j] = *(const half8*)(Wp + kn + wkq + j * 8);
      }
    }

    #pragma unroll
    for (int kk = 0; kk < BK / 32; ++kk) {
      half8 af[2], wf[NF];
      #pragma unroll
      for (int mi = 0; mi < 2; ++mi)
        af[mi] = *(const half8*)&As[(wm * 32 + mi * 16 + l16) * LS + kk * 32 + q * 8];
      #pragma unroll
      for (int ni = 0; ni < NF; ++ni)
        wf[ni] = *(const half8*)&Ws[(wn * (BN / 2) + ni * 16 + l16) * LS + kk * 32 + q * 8];
      #pragma unroll
      for (int mi = 0; mi < 2; ++mi)
        #pragma unroll
        for (int ni = 0; ni < NF; ++ni)
          acc[mi][ni] = __builtin_amdgcn_mfma_f32_16x16x32_f16(af[mi], wf[ni],
                                                               acc[mi][ni], 0, 0, 0);
    }
  }

  float*    Cf = (float*)Cv;
  _Float16* Ch = (_Float16*)Cv;

  if (MODE == 1) {
    if (n0 < 1024) {
      // xc half: f16 [M][1024]
      #pragma unroll
      for (int ni = 0; ni < NF; ++ni) {
        const int n = n0 + wn * (BN / 2) + ni * 16 + l16;
        #pragma unroll
        for (int mi = 0; mi < 2; ++mi) {
          const int mb = m0 + wm * 32 + mi * 16 + q * 4;
          #pragma unroll
          for (int r = 0; r < 4; ++r)
            Ch[(size_t)(mb + r) * 1024 + n] = (_Float16)(acc[mi][ni][r] * oscale);
        }
      }
    } else {
      // z half: silu -> f16, LDS transpose (Tz aliases Ws; LS==72),
      // coalesced 16B row stores
      _Float16* Tz = Ws;
      _Float16* Ch2 = (_Float16*)Cv2;
      __syncthreads();                  // all MFMA reads of Ws done
      #pragma unroll
      for (int ni = 0; ni < NF; ++ni) {
        const int nnl = wn * (BN / 2) + ni * 16 + l16;   // 0..127 local
        #pragma unroll
        for (int mi = 0; mi < 2; ++mi) {
          const int mbl = wm * 32 + mi * 16 + q * 4;     // 0..63 local
          half4v h4;
          #pragma unroll
          for (int r = 0; r < 4; ++r)
            h4[r] = (_Float16)silu_f(acc[mi][ni][r] * oscale);
          *(half4v*)&Tz[nnl * LS + mbl] = h4;
        }
      }
      __syncthreads();
      const int sr = tid >> 3;          // 0..31
      const int sc = (tid & 7) * 8;     // halfs 0..56
      #pragma unroll
      for (int rd = 0; rd < 4; ++rd) {
        const int row = rd * 32 + sr;
        half8 v = *(const half8*)&Tz[row * LS + sc];
        *(half8*)&Ch2[(size_t)(n0 - 1024 + row) * 4096 + m0 + sc] = v;
      }
    }
    return;
  }

  if (MODE == 2) {
    // xproj split:
    //   n <  32           -> dtr16 f16 [M][32]           (via Cv2)
    //   32 <= n <  96     -> Bsc scan layout             (via Cv)
    //   96 <= n < 160     -> Csc = Bsc + 262144
    // Scan layout: [b*256 + t/4][s 0..63][t&3] fp32. mb%4==0 so the 4 acc
    // components (rows mb..mb+3) form one contiguous float4 at s*4.
    float* Bs = Cf;
    _Float16* dtr = (_Float16*)Cv2;
    #pragma unroll
    for (int ni = 0; ni < NF; ++ni) {
      const int n = n0 + wn * (BN / 2) + ni * 16 + l16;
      #pragma unroll
      for (int mi = 0; mi < 2; ++mi) {
        const int mb = m0 + wm * 32 + mi * 16 + q * 4;
        if (n < 32) {
          #pragma unroll
          for (int r = 0; r < 4; ++r)
            dtr[(size_t)(mb + r) * 32 + n] = (_Float16)acc[mi][ni][r];
        } else if (n < 160) {
          const int s = (n < 96) ? (n - 32) : (n - 96);
          float* dst = Bs + ((n < 96) ? 0 : 262144);
          float4 v = make_float4(acc[mi][ni][0], acc[mi][ni][1],
                                 acc[mi][ni][2], acc[mi][ni][3]);
          *(float4*)&dst[((size_t)(mb >> 2) << 8) + s * 4] = v;
        }
      }
    }
    return;
  }

  if (MODE == 3) {
    // dtproj: softplus(acc*oscale + bias) -> fp32 [N][4096] via LDS transpose
    __syncthreads();
    #pragma unroll
    for (int ni = 0; ni < NF; ++ni) {
      const int nnl = wn * (BN / 2) + ni * 16 + l16;     // 0..63 local
      const float bv = (bias != nullptr) ? bias[n0 + nnl] : 0.f;
      #pragma unroll
      for (int mi = 0; mi < 2; ++mi) {
        const int mbl = wm * 32 + mi * 16 + q * 4;       // 0..63 local
        float o[4];
        #pragma unroll
        for (int r = 0; r < 4; ++r) {
          float v = acc[mi][ni][r] * oscale + bv;
          o[r] = (v > 20.f) ? v : log1pf(__expf(v));     // softplus
        }
        *(float4*)&Td[nnl * 68 + mbl] = make_float4(o[0], o[1], o[2], o[3]);
      }
    }
    __syncthreads();
    const int sr = tid >> 4;            // 0..15
    const int sc = (tid & 15) * 4;      // floats 0..60
    #pragma unroll
    for (int rd = 0; rd < 4; ++rd) {
      const int row = rd * 16 + sr;
      float4 v = *(const float4*)&Td[row * 68 + sc];
      *(float4*)&Cf[(size_t)(n0 + row) * 4096 + m0 + sc] = v;
    }
    return;
  }

  // MODE 0 epilogue
  #pragma unroll
  for (int ni = 0; ni < NF; ++ni) {
    const int n = n0 + wn * (BN / 2) + ni * 16 + l16;
    if (n < N) {
      const float bv = (bias != nullptr) ? bias[n] : 0.f;
      #pragma unroll
      for (int mi = 0; mi < 2; ++mi) {
        const int mb = m0 + wm * 32 + mi * 16 + q * 4;
        #pragma unroll
        for (int r = 0; r < 4; ++r) {
          float v = acc[mi][ni][r] * oscale + bv;
          if (ACT == 1) v = (v > 20.f) ? v : log1pf(__expf(v));
          if (ACT == 2) v = silu_f(v);
          size_t off = (size_t)(mb + r) * ldc + n;
          if (OF16) Ch[off] = (_Float16)v;
          else      Cf[off] = v;
        }
      }
    }
  }
}

// ---------------------------------------------------------------------------
// Depthwise causal conv (D_CONV=2) + silu, 64x64 LDS transpose.
// R26: half2/float2 vectorized (was scalar f16 -- Common-mistake #2).
// in : xcp [4096 bl][1024 d] f16
// out: xcT [1024 d][4096 bl] fp32 (scan input)  +  xcf [4096 bl][1024 d] f16
// ---------------------------------------------------------------------------
__global__ void conv_t_kernel(const _Float16* __restrict__ xcp,
                              const float* __restrict__ cw,   // [1024][2]
                              const float* __restrict__ cb,   // [1024]
                              float* __restrict__ xcT,
                              _Float16* __restrict__ xcf)
{
  __shared__ float tile[64][66];
  const int blk = blockIdx.x;            // b*256 + tt*16 + dd
  const int b  = blk >> 8;
  const int tt = (blk >> 4) & 15;
  const int dd = blk & 15;
  const int t0 = tt * 64, d0 = dd * 64;
  const int tid = threadIdx.x;

  #pragma unroll
  for (int i = 0; i < 8; ++i) {
    int idx = i * 256 + tid;             // 0..2047
    int t  = idx >> 5;                   // 0..63
    int d2 = (idx & 31) * 2;             // even 0..62
    int gt = t0 + t;
    size_t rcur = ((size_t)(b * 1024 + gt) << 10) + d0 + d2;
    half2v cur = *(const half2v*)(xcp + rcur);
    half2v prev;
    if (gt > 0) prev = *(const half2v*)(xcp + rcur - 1024);
    else { prev[0] = (_Float16)0.f; prev[1] = (_Float16)0.f; }
    float4 cw4 = *(const float4*)(cw + (size_t)(d0 + d2) * 2);  // 16B aligned
    float2 cb2 = *(const float2*)(cb + d0 + d2);                // 8B aligned
    float v0 = fmaf((float)prev[0], cw4.x, fmaf((float)cur[0], cw4.y, cb2.x));
    float v1 = fmaf((float)prev[1], cw4.z, fmaf((float)cur[1], cw4.w, cb2.y));
    float sv0 = silu_f(v0), sv1 = silu_f(v1);
    *(float2*)&tile[t][d2] = make_float2(sv0, sv1);   // stride 66, d2 even: 8B ok
    half2v sh; sh[0] = (_Float16)sv0; sh[1] = (_Float16)sv1;
    *(half2v*)(xcf + rcur) = sh;
  }
  __syncthreads();
  #pragma unroll
  for (int i = 0; i < 8; ++i) {
    int idx = i * 256 + tid;             // 0..2047
    int d  = idx >> 5;                   // 0..63
    int t2 = (idx & 31) * 2;             // even 0..62
    float2 v = make_float2(tile[t2][d], tile[t2 + 1][d]);
    *(float2*)&xcT[((size_t)(d0 + d) << 12) + b * 1024 + t0 + t2] = v;
  }
}

// ---------------------------------------------------------------------------
// Selective scan v8, time-major. One wave per (b,d), lane = s (D_STATE=64).
// R20 base (C++ float4 loads -> compiler emits SMEM s_loads for the
// wave-uniform dt/x streams; sched_barrier region pinning), plus a
// chain/reduce software pipeline: chunk k's reduce (P-read + 3 shfl + y
// store) is deferred one chunk and co-scheduled with chunk k+1's chain.
// Established floor ~110us (7 structures tried, all issue-bound).
// ---------------------------------------------------------------------------
struct Chunk {
  float4 Bq0, Bq1, Cq0, Cq1, dq0, dq1, xq0, xq1;
  float zs, xvl;
};

__device__ __forceinline__ void load_chunk(int t0, Chunk& c,
    const float* __restrict__ Bb, const float* __restrict__ Cbp,
    const float* __restrict__ dtp, const float* __restrict__ xp,
    const _Float16* __restrict__ zsp, int tt_r)
{
  const float* Bp = Bb  + (((size_t)t0 >> 2) << 8);   // t0*64 floats
  const float* Cp = Cbp + (((size_t)t0 >> 2) << 8);
  c.Bq0 = *(const float4*)(Bp);        c.Bq1 = *(const float4*)(Bp + 256);
  c.Cq0 = *(const float4*)(Cp);        c.Cq1 = *(const float4*)(Cp + 256);
  c.dq0 = *(const float4*)(dtp + t0);  c.dq1 = *(const float4*)(dtp + t0 + 4);
  c.xq0 = *(const float4*)(xp + t0);   c.xq1 = *(const float4*)(xp + t0 + 4);
  c.zs  = (float)zsp[t0 + tt_r] * Y_SCALE;   // exact 2^14 fold
  c.xvl = xp[t0 + tt_r];
}

// chain phase: dA/ub prep + serial h-recurrence + P writes. No reduction.
__device__ __forceinline__ void chain_chunk(const Chunk& c, float& h,
    float al2, float (*Pw)[68], int lane)
{
  float dvv[8] = {c.dq0.x, c.dq0.y, c.dq0.z, c.dq0.w,
                  c.dq1.x, c.dq1.y, c.dq1.z, c.dq1.w};
  float xvv[8] = {c.xq0.x, c.xq0.y, c.xq0.z, c.xq0.w,
                  c.xq1.x, c.xq1.y, c.xq1.z, c.xq1.w};
  float Bvv[8] = {c.Bq0.x, c.Bq0.y, c.Bq0.z, c.Bq0.w,
                  c.Bq1.x, c.Bq1.y, c.Bq1.z, c.Bq1.w};
  float Cvv[8] = {c.Cq0.x, c.Cq0.y, c.Cq0.z, c.Cq0.w,
                  c.Cq1.x, c.Cq1.y, c.Cq1.z, c.Cq1.w};
  float dA[8], ub[8];
  #pragma unroll
  for (int tt = 0; tt < 8; ++tt) {
    dA[tt] = fast_exp2(dvv[tt] * al2);
    ub[tt] = dvv[tt] * xvv[tt] * Bvv[tt];
  }
  #pragma unroll
  for (int tt = 0; tt < 8; ++tt) {
    h = fmaf(h, dA[tt], ub[tt]);
    Pw[tt][lane] = h * Cvv[tt];
  }
}

// reduce phase (deferred one chunk): P-read, lane-tree + 3 shfl, y store.
__device__ __forceinline__ void reduce_chunk(int t0, float (*Pw)[68],
    float zs, float xvl, float dpv, _Float16* __restrict__ yp,
    int lane, int tt_r, int c0)
{
  float4 s0 = *(const float4*)&Pw[tt_r][c0];
  float4 s1 = *(const float4*)&Pw[tt_r][c0 + 4];
  float r = ((s0.x + s0.y) + (s0.z + s0.w)) + ((s1.x + s1.y) + (s1.z + s1.w));
  r += __shfl_xor(r, 1, 64);
  r += __shfl_xor(r, 2, 64);
  r += __shfl_xor(r, 4, 64);
  if ((lane & 7) == 0)
    yp[(size_t)(t0 + tt_r) << 10] = (_Float16)(fmaf(xvl, dpv, r) * zs);
}

__global__ __launch_bounds__(256, 4)
void scan_kernel(const float* __restrict__ dtT,     // [1024][4096]
                 const float* __restrict__ xcT,     // [1024][4096]
                 const _Float16* __restrict__ zsT,  // [1024][4096], silu(z), f16
                 const float* __restrict__ Bsc,     // [4][256][64][4]; Csc at +262144
                 const float* __restrict__ A_log,   // [1024][64]
                 const float* __restrict__ Dp,      // [1024]
                 _Float16* __restrict__ y16)        // [4096 bl][1024 d], y*2^14
{
  __shared__ float P[4][2][8][68];     // per-wave double reduction tiles
  const int tid  = threadIdx.x;
  const int lane = tid & 63;
  const int wrp  = tid >> 6;
  const int rb   = blockIdx.x;
  const int bswz = ((rb & 7) << 7) | (rb >> 3);          // XCD swizzle
  const int wid  = __builtin_amdgcn_readfirstlane(bswz * 4 + wrp);
  const int b = wid >> 10;
  const int d = wid & 1023;
  float (*P0)[68] = P[wrp][0];
  float (*P1)[68] = P[wrp][1];

  const float a   = -__expf(A_log[d * 64 + lane]);
  const float al2 = a * 1.44269504088896f;               // hoisted log2(e)
  const float dpv = Dp[d];
  const size_t row = ((size_t)d << 12) + b * 1024;
  const float*    dtp = dtT + row;
  const float*    xp  = xcT + row;
  const _Float16* zsp = zsT + row;
  _Float16*       yp  = y16 + ((size_t)b << 20) + d;     // + t*1024
  const float*    Bb  = Bsc + ((size_t)b << 16) + lane * 4;
  const float*    Cbp = Bb + 262144;

  const int tt_r = lane >> 3;          // timestep this lane reduces
  const int c0   = (lane & 7) << 3;    // its 8-state column base

  float h = 0.f;
  Chunk ca, cb;
  float zs0, xv0, zs1, xv1;

  // prologue: chunks 0 (ca) and 1 (cb); chain chunk 0 into P0.
  load_chunk(0, ca, Bb, Cbp, dtp, xp, zsp, tt_r);
  load_chunk(8, cb, Bb, Cbp, dtp, xp, zsp, tt_r);
  chain_chunk(ca, h, al2, P0, lane);
  zs0 = ca.zs; xv0 = ca.xvl;
  __builtin_amdgcn_sched_barrier(0);

  // steady state, 2 chunks per iteration (static P-buffer indices):
  //   stage A: load(k+2 -> ca) | chain(k+1 = cb -> P1) | reduce(k via P0)
  //   stage B: load(k+3 -> cb) | chain(k+2 = ca -> P0) | reduce(k+1 via P1)
  for (int t0 = 0; t0 < 1008; t0 += 16) {
    load_chunk(t0 + 16, ca, Bb, Cbp, dtp, xp, zsp, tt_r);
    chain_chunk(cb, h, al2, P1, lane);
    zs1 = cb.zs; xv1 = cb.xvl;
    reduce_chunk(t0, P0, zs0, xv0, dpv, yp, lane, tt_r, c0);
    __builtin_amdgcn_sched_barrier(0);

    load_chunk(t0 + 24, cb, Bb, Cbp, dtp, xp, zsp, tt_r);  // t0+24 <= 1016
    chain_chunk(ca, h, al2, P0, lane);
    zs0 = ca.zs; xv0 = ca.xvl;
    reduce_chunk(t0 + 8, P1, zs1, xv1, dpv, yp, lane, tt_r, c0);
    __builtin_amdgcn_sched_barrier(0);
  }
  // epilogue: chunk 127 (cb) chain, then the two pending reduces.
  chain_chunk(cb, h, al2, P1, lane);
  zs1 = cb.zs; xv1 = cb.xvl;
  reduce_chunk(1008, P0, zs0, xv0, dpv, yp, lane, tt_r, c0);
  reduce_chunk(1016, P1, zs1, xv1, dpv, yp, lane, tt_r, c0);
}

// ---------------------------------------------------------------------------
// R26: w2 precompute. w2[c][di] = sum_dm fc_w[c][dm] * out_w1[dm][di].
// 16 blocks x 256 thr; block owns a 64-di tile, reads out_w1 exactly once
// (128KB/block), computes all 3 classes. Coalesced: tid&63 -> consecutive di.
// ---------------------------------------------------------------------------
__global__ void w2prep_kernel(const float* __restrict__ out_w1, // [512][1024]
                              const float* __restrict__ fc_w,   // [3][512]
                              float* __restrict__ w2)           // [3][1024]
{
  __shared__ float part[3][4][64];
  const int tid = threadIdx.x;
  const int di0 = blockIdx.x * 64;
  const int dl  = tid & 63;
  const int sl  = tid >> 6;             // dm-slice 0..3
  const float* col = out_w1 + di0 + dl;
  float a0 = 0.f, a1 = 0.f, a2 = 0.f;
  for (int dm = sl * 128; dm < sl * 128 + 128; ++dm) {
    float o = col[(size_t)dm << 10];    // coalesced 256B across dl
    a0 = fmaf(fc_w[dm],        o, a0);
    a1 = fmaf(fc_w[512 + dm],  o, a1);
    a2 = fmaf(fc_w[1024 + dm], o, a2);
  }
  part[0][sl][dl] = a0; part[1][sl][dl] = a1; part[2][sl][dl] = a2;
  __syncthreads();
  if (tid < 192) {
    const int c = tid >> 6, j = tid & 63;
    w2[c * 1024 + di0 + j] = part[c][0][j] + part[c][1][j]
                           + part[c][2][j] + part[c][3][j];
  }
}

// ---------------------------------------------------------------------------
// Fused head: out[b,c] = (sum_di y16l1[b*1024+1023][di] * w2[c][di]) * 2^-14
//             + fc_b[c].  w2 precomputed by w2prep_kernel.
// ---------------------------------------------------------------------------
__global__ void head2_kernel(const _Float16* __restrict__ y16,
                             const float* __restrict__ w2,   // [3][1024]
                             const float* __restrict__ fc_b,
                             float* __restrict__ out)
{
  __shared__ float red[4];
  const int bc = blockIdx.x;            // 0..11
  const int b = bc / 3, c = bc % 3;
  const int tid = threadIdx.x;
  const int lane = tid & 63, wv = tid >> 6;

  const _Float16* yr = y16 + ((size_t)(b * 1024 + 1023) << 10) + tid * 4;
  half4v yv = *(const half4v*)yr;
  float4 wq = *(const float4*)(w2 + c * 1024 + tid * 4);
  float s = (float)yv[0] * wq.x + (float)yv[1] * wq.y
          + (float)yv[2] * wq.z + (float)yv[3] * wq.w;
  #pragma unroll
  for (int o = 32; o > 0; o >>= 1) s += __shfl_xor(s, o, 64);
  if (lane == 0) red[wv] = s;
  __syncthreads();
  if (tid == 0)
    out[b * 3 + c] = (red[0] + red[1] + red[2] + red[3]) * (1.f / Y_SCALE)
                     + fc_b[c];
}

extern "C" void kernel_launch(void* const* d_in, const int* in_sizes, int n_in,
                              void* d_out, int out_size, void* d_ws, size_t ws_size,
                              hipStream_t stream)
{
  const float* x        = (const float*)d_in[0];
  const float* exp_w    = (const float*)d_in[1];
  const float* exp_b    = (const float*)d_in[2];
  const float* in_w     = (const float*)d_in[3];
  const float* conv_w   = (const float*)d_in[4];
  const float* conv_b   = (const float*)d_in[5];
  const float* xproj_w  = (const float*)d_in[6];
  const float* dtproj_w = (const float*)d_in[7];
  const float* dtproj_b = (const float*)d_in[8];
  const float* A_log    = (const float*)d_in[9];
  const float* Dp       = (const float*)d_in[10];
  const float* out_w    = (const float*)d_in[11];
  const float* fc_w     = (const float*)d_in[12];
  const float* fc_b     = (const float*)d_in[13];
  float* out = (float*)d_out;

  // Workspace layout (byte offsets), 72 MB total.
  // 4..20 MB region sequentially reused: xcpre16 (8MB) -> dtT (16MB).
  char* ws = (char*)d_ws;
  _Float16* hf16    = (_Float16*)(ws);                        //  4 MB [4096][512] f16
  _Float16* xcpre16 = (_Float16*)(ws + ((size_t)4  << 20));   //  8 MB [4096][1024] f16
  float*    dtT     = (float*)   (ws + ((size_t)4  << 20));   // 16 MB [1024][4096] (reuse)
  float*    xcT     = (float*)   (ws + ((size_t)20 << 20));   // 16 MB [1024][4096]
  _Float16* zsT     = (_Float16*)(ws + ((size_t)36 << 20));   //  8 MB [1024][4096]
  float*    Bsc     = (float*)   (ws + ((size_t)44 << 20));   //  2 MB [4][256][64][4] B then C
  float*    w2buf   = (float*)   (ws + ((size_t)46 << 20));   //  12 KB [3][1024]
  _Float16* dtr16   = (_Float16*)(ws + ((size_t)47 << 20));   //  0.25 MB [4096][32]
  _Float16* xc16    = (_Float16*)(ws + ((size_t)48 << 20));   //  8 MB [4096][1024]
  _Float16* y16     = (_Float16*)(ws + ((size_t)56 << 20));   //  8 MB [4096][1024]
  _Float16* w16     = (_Float16*)(ws + ((size_t)64 << 20));   //  7.9 MB f16 pool

  _Float16* exp16 = w16;                 // [512][128]
  _Float16* in16  = w16 + 65536;         // [2][2048][512]
  _Float16* xp16  = w16 + 2162688;       // [2][160][1024]
  _Float16* dt16  = w16 + 2490368;       // [2][1024][32]
  _Float16* out16 = w16 + 2555904;       // [2][512][1024]
  _Float16* x16   = w16 + 3604480;       // [4096][128]

  dim3 blk(256);

  // one-shot f16 conversion of all weights + x (4128768 elems, 4032 blocks)
  wcvt_kernel<<<4032, blk, 0, stream>>>(exp_w, in_w, xproj_w, dtproj_w, out_w,
                                        x, w16);

  // w2 precompute (weights only; feeds head2 at the end)
  w2prep_kernel<<<16, blk, 0, stream>>>(out_w + (size_t)512 * 1024, fc_w, w2buf);

  // expand: hf16 = f16(x @ exp_w^T + exp_b)   [4096,512] K=128, BK=32.
  gemm_mfma<64,32,0,1,0><<<dim3(8,64), blk, 0, stream>>>(x16, 128, exp16, exp_b,
                                                         hf16, 512, 512, 128, 1.f,
                                                         nullptr);

  for (int l = 0; l < 2; ++l) {
    const float is = l ? (1.f / H1_SCALE) : 1.f;     // undo h1 scaling (exact)
    // fused in_proj: xcpre16 f16 + zsT f16 (Tz aliases Ws). N=2048 K=512 BK=64.
    gemm_mfma<128,64,0,0,1><<<dim3(16,64), blk, 0, stream>>>(hf16, 512,
                                                             in16 + (size_t)l*1048576,
                                                             nullptr, xcpre16, 1024,
                                                             2048, 512, is, zsT);
    // conv + silu -> xcT (fp32, scan) + xc16 (f16, xproj A)  [R26 vectorized]
    conv_t_kernel<<<1024, blk, 0, stream>>>(xcpre16, conv_w + l*2048, conv_b + l*1024,
                                            xcT, xc16);
    // xproj (MODE 2): dtr16 f16 [4096][32] + Bsc/Csc scan layout. K=1024 BK=64.
    gemm_mfma<64,64,0,0,2><<<dim3(3,64), blk, 0, stream>>>(xc16, 1024,
                                                           xp16 + (size_t)l*163840,
                                                           nullptr, Bsc, 160,
                                                           160, 1024, 1.f, dtr16);
    // dtproj (MODE 3): dtT [1024][4096] softplus, LDS-transposed. K=32 BK=32.
    gemm_mfma<64,32,0,0,3><<<dim3(16,64), blk, 0, stream>>>(dtr16, 32,
                                                            dt16 + (size_t)l*32768,
                                                            dtproj_b + l*1024,
                                                            dtT, 4096, 1024, 32, 1.f,
                                                            nullptr);
    // selective scan v8 (chain/reduce pipelined, R20 base)
    scan_kernel<<<1024, blk, 0, stream>>>(dtT, xcT, zsT, Bsc,
                                          A_log + (size_t)l*65536, Dp + l*1024, y16);
    // out_proj only for layer 0 (layer-1 h only matters at t=L-1 -> head2)
    if (l == 0)
      gemm_mfma<64,64,0,1,0><<<dim3(8,64), blk, 0, stream>>>(y16, 1024,
                                                             out16, nullptr,
                                                             hf16, 512, 512, 1024,
                                                             H1_SCALE / Y_SCALE,
                                                             nullptr);
  }

  // head: y16(l1) . w2 (precomputed) + fc_b
  head2_kernel<<<12, blk, 0, stream>>>(y16, w2buf, fc_b, out);
}

// Round 12
// 414.891 us; speedup vs baseline: 1.3058x; 1.0100x over previous
//
#include <hip/hip_runtime.h>
#include <math.h>

// Problem constants: B=4, L=1024, D_IN=128, D_MODEL=512, N_LAYERS=2,
// N_CLASSES=3, D_INNER=1024, D_STATE=64, D_CONV=2, DT_RANK=32, BL=4096.
//
// Precision plan: all GEMM operands f16 (conversions hoisted upstream).
// Layer-1 residual h f16 scaled by 2^8 (exact). y scaled by 2^14 at the
// scan store. Head works from y16(l1) directly with fp32 weights.
//
// R27: scan at floor (v8 ~107us). This round: XCD L2-collocation for the
// A-heavy GEMMs via grid-axis swap (template SW): same-A blocks now map to
// the same XCD (bid diff % 8 == 0), so per-XCD working set = A-slice +
// full W (2.5MB) fits the 4MB L2 instead of replicating A into all 8 L2s
// and re-reading from L3. Applied to in_proj / xproj / out_proj. Also
// w2prep fused into wcvt as blocks 4032..4047 (-1 dispatch).

using half8  = __attribute__((ext_vector_type(8))) _Float16;
using half4v = __attribute__((ext_vector_type(4))) _Float16;
using half2v = __attribute__((ext_vector_type(2))) _Float16;
using f32x4  = __attribute__((ext_vector_type(4))) float;

#define Y_SCALE 16384.0f   // 2^14
#define H1_SCALE 256.0f    // 2^8

__device__ __forceinline__ float silu_f(float v) {
  return v / (1.f + __expf(-v));
}

__device__ __forceinline__ float fast_exp2(float x) {
#if __has_builtin(__builtin_amdgcn_exp2f)
  return __builtin_amdgcn_exp2f(x);
#else
  return __expf(x * 0.69314718055994531f);
#endif
}

// ---------------------------------------------------------------------------
// One-shot fp32 -> f16 conversion of all weights + x into the w16 pool,
// with w2prep fused as blocks 4032..4047 (R27).
//   exp_w 0..65536 | in_w ..2162688 | xproj_w ..2490368 | dtproj_w ..2555904
//   | out_w ..3604480 | x ..4128768
// w2[c][di] = sum_dm fc_w[c][dm] * out_w1[dm][di], out_w1 = out_w + 512K.
// ---------------------------------------------------------------------------
__global__ void wcvt_kernel(const float* __restrict__ exp_w,
                            const float* __restrict__ in_w,
                            const float* __restrict__ xproj_w,
                            const float* __restrict__ dtproj_w,
                            const float* __restrict__ out_w,
                            const float* __restrict__ x,
                            _Float16* __restrict__ w16,
                            const float* __restrict__ fc_w,
                            float* __restrict__ w2)
{
  __shared__ float part[3][4][64];
  const int tid = threadIdx.x;
  if (blockIdx.x >= 4032) {
    // ---- w2prep: block owns a 64-di tile, reads out_w1 exactly once ----
    const float* out_w1 = out_w + (size_t)512 * 1024;
    const int di0 = (blockIdx.x - 4032) * 64;
    const int dl  = tid & 63;
    const int sl  = tid >> 6;             // dm-slice 0..3
    const float* col = out_w1 + di0 + dl;
    float a0 = 0.f, a1 = 0.f, a2 = 0.f;
    for (int dm = sl * 128; dm < sl * 128 + 128; ++dm) {
      float o = col[(size_t)dm << 10];    // coalesced across dl
      a0 = fmaf(fc_w[dm],        o, a0);
      a1 = fmaf(fc_w[512 + dm],  o, a1);
      a2 = fmaf(fc_w[1024 + dm], o, a2);
    }
    part[0][sl][dl] = a0; part[1][sl][dl] = a1; part[2][sl][dl] = a2;
    __syncthreads();
    if (tid < 192) {
      const int c = tid >> 6, j = tid & 63;
      w2[c * 1024 + di0 + j] = part[c][0][j] + part[c][1][j]
                             + part[c][2][j] + part[c][3][j];
    }
    return;
  }
  size_t gi = ((size_t)blockIdx.x * 256 + tid) * 4;
  const float* src; size_t off;
  if      (gi < 65536)   { src = exp_w;    off = gi; }
  else if (gi < 2162688) { src = in_w;     off = gi - 65536; }
  else if (gi < 2490368) { src = xproj_w;  off = gi - 2162688; }
  else if (gi < 2555904) { src = dtproj_w; off = gi - 2490368; }
  else if (gi < 3604480) { src = out_w;    off = gi - 2555904; }
  else                   { src = x;        off = gi - 3604480; }
  float4 v = *(const float4*)(src + off);
  half4v h;
  h[0] = (_Float16)v.x; h[1] = (_Float16)v.y;
  h[2] = (_Float16)v.z; h[3] = (_Float16)v.w;
  *(half4v*)(w16 + gi) = h;
}

// ---------------------------------------------------------------------------
// f16 MFMA GEMM, 64 x BN tile, BK-chunk K-loop. Block 256 thr = 4 waves;
// wave-tile 32 x (BN/2), MI=2 m-frags. BK in {32,64}.
// Modes: 0 plain / 1 in_proj fused (REQUIRES BK=64, BN=128; Tz aliases Ws) /
// 2 xproj split (dtr16 + Bsc/Csc scan layout) / 3 dtproj transposed-softplus.
// SW (R27): grid-axis swap for XCD L2 collocation of the A panel --
// SW=1: m0 from blockIdx.x (fastest), n0 from blockIdx.y; same-A blocks
// then differ by gridDim.x (multiple of 8) -> same XCD L2.
// MFMA layouts (m89/m120-verified): A-frag A[m=lane&15][k=q*8+j],
// B-frag B[k=q*8+j][n=lane&15], D: col(n)=lane&15, row(m)=q*4+r.
// ---------------------------------------------------------------------------
template<int BN, int BK, int ACT, int OF16, int MODE, int SW = 0>
__global__ __launch_bounds__(256)
void gemm_mfma(const _Float16* __restrict__ A, int lda,
               const _Float16* __restrict__ W,
               const float* __restrict__ bias,
               void* __restrict__ Cv, int ldc,
               int N, int K, float oscale,
               void* __restrict__ Cv2)
{
  static_assert(MODE != 1 || (BK == 64 && BN == 128), "MODE1 needs BK=64/BN=128");
  constexpr int NF  = BN / 32;           // n-frags per wave
  constexpr int LS  = BK + 8;            // LDS row stride in halfs (16B-aligned)
  constexpr int NA  = BK / 32;           // A half8 regs per thread
  constexpr int WTR = 256 / BN;          // threads per W row
  constexpr int WH  = BK / WTR;          // W halfs per thread (R18b fix)
  constexpr int NW  = WH / 8;            // W half8 regs per thread
  static_assert(NA >= 1 && NW >= 1, "staging arithmetic");

  __shared__ _Float16 As[64 * LS];
  __shared__ _Float16 Ws[BN * LS];       // MODE1: reused as Tz in epilogue
  __shared__ float    Td[(MODE == 3) ? 64 * 68 : 2];
  const int tid  = threadIdx.x;
  const int lane = tid & 63;
  const int wid  = tid >> 6;
  const int wm   = wid & 1, wn = wid >> 1;   // wave-tile: 32 m x BN/2 n
  const int m0   = (SW ? blockIdx.x : blockIdx.y) * 64;
  const int n0   = (SW ? blockIdx.y : blockIdx.x) * BN;
  const int q    = lane >> 4, l16 = lane & 15;

  // staging coords
  const int ar  = tid >> 2;                  // A: 4 thr/row
  const int akq = (tid & 3) * (BK / 4);
  const int wr  = tid / WTR;
  const int wkq = (tid % WTR) * WH;
  const int wrow = n0 + wr;
  const bool wv  = (wrow < N);

  const _Float16* Wp = W + (size_t)wrow * K;
  const size_t aoff = (size_t)(m0 + ar) * lda + akq;

  half8 zh;
  #pragma unroll
  for (int i = 0; i < 8; ++i) zh[i] = (_Float16)0.f;

  // initial loads (k0 = 0)
  half8 rah[NA], rwh[NW];
  #pragma unroll
  for (int i = 0; i < NA; ++i) rah[i] = *(const half8*)(A + aoff + i * 8);
  #pragma unroll
  for (int j = 0; j < NW; ++j)
    rwh[j] = wv ? *(const half8*)(Wp + wkq + j * 8) : zh;

  f32x4 acc[2][NF];
  #pragma unroll
  for (int mi = 0; mi < 2; ++mi)
    #pragma unroll
    for (int ni = 0; ni < NF; ++ni)
      acc[mi][ni] = (f32x4){0.f, 0.f, 0.f, 0.f};

  for (int k0 = 0; k0 < K; k0 += BK) {
    if (k0) __syncthreads();
    #pragma unroll
    for (int i = 0; i < NA; ++i)
      *(half8*)&As[ar * LS + akq + i * 8] = rah[i];
    #pragma unroll
    for (int j = 0; j < NW; ++j)
      *(half8*)&Ws[wr * LS + wkq + j * 8] = rwh[j];
    __syncthreads();

    if (k0 + BK < K) {            // prefetch next chunk
      const int kn = k0 + BK;
      #pragma unroll
      for (int i = 0; i < NA; ++i)
        rah[i] = *(const half8*)(A + aoff + kn + i * 8);
      if (wv) {
        #pragma unroll
        for (int j = 0; j < NW; ++j)
          rwh[j] = *(const half8*)(Wp + kn + wkq + j * 8);
      }
    }

    #pragma unroll
    for (int kk = 0; kk < BK / 32; ++kk) {
      half8 af[2], wf[NF];
      #pragma unroll
      for (int mi = 0; mi < 2; ++mi)
        af[mi] = *(const half8*)&As[(wm * 32 + mi * 16 + l16) * LS + kk * 32 + q * 8];
      #pragma unroll
      for (int ni = 0; ni < NF; ++ni)
        wf[ni] = *(const half8*)&Ws[(wn * (BN / 2) + ni * 16 + l16) * LS + kk * 32 + q * 8];
      #pragma unroll
      for (int mi = 0; mi < 2; ++mi)
        #pragma unroll
        for (int ni = 0; ni < NF; ++ni)
          acc[mi][ni] = __builtin_amdgcn_mfma_f32_16x16x32_f16(af[mi], wf[ni],
                                                               acc[mi][ni], 0, 0, 0);
    }
  }

  float*    Cf = (float*)Cv;
  _Float16* Ch = (_Float16*)Cv;

  if (MODE == 1) {
    if (n0 < 1024) {
      // xc half: f16 [M][1024]
      #pragma unroll
      for (int ni = 0; ni < NF; ++ni) {
        const int n = n0 + wn * (BN / 2) + ni * 16 + l16;
        #pragma unroll
        for (int mi = 0; mi < 2; ++mi) {
          const int mb = m0 + wm * 32 + mi * 16 + q * 4;
          #pragma unroll
          for (int r = 0; r < 4; ++r)
            Ch[(size_t)(mb + r) * 1024 + n] = (_Float16)(acc[mi][ni][r] * oscale);
        }
      }
    } else {
      // z half: silu -> f16, LDS transpose (Tz aliases Ws; LS==72),
      // coalesced 16B row stores
      _Float16* Tz = Ws;
      _Float16* Ch2 = (_Float16*)Cv2;
      __syncthreads();                  // all MFMA reads of Ws done
      #pragma unroll
      for (int ni = 0; ni < NF; ++ni) {
        const int nnl = wn * (BN / 2) + ni * 16 + l16;   // 0..127 local
        #pragma unroll
        for (int mi = 0; mi < 2; ++mi) {
          const int mbl = wm * 32 + mi * 16 + q * 4;     // 0..63 local
          half4v h4;
          #pragma unroll
          for (int r = 0; r < 4; ++r)
            h4[r] = (_Float16)silu_f(acc[mi][ni][r] * oscale);
          *(half4v*)&Tz[nnl * LS + mbl] = h4;
        }
      }
      __syncthreads();
      const int sr = tid >> 3;          // 0..31
      const int sc = (tid & 7) * 8;     // halfs 0..56
      #pragma unroll
      for (int rd = 0; rd < 4; ++rd) {
        const int row = rd * 32 + sr;
        half8 v = *(const half8*)&Tz[row * LS + sc];
        *(half8*)&Ch2[(size_t)(n0 - 1024 + row) * 4096 + m0 + sc] = v;
      }
    }
    return;
  }

  if (MODE == 2) {
    // xproj split:
    //   n <  32           -> dtr16 f16 [M][32]           (via Cv2)
    //   32 <= n <  96     -> Bsc scan layout             (via Cv)
    //   96 <= n < 160     -> Csc = Bsc + 262144
    // Scan layout: [b*256 + t/4][s 0..63][t&3] fp32. mb%4==0 so the 4 acc
    // components (rows mb..mb+3) form one contiguous float4 at s*4.
    float* Bs = Cf;
    _Float16* dtr = (_Float16*)Cv2;
    #pragma unroll
    for (int ni = 0; ni < NF; ++ni) {
      const int n = n0 + wn * (BN / 2) + ni * 16 + l16;
      #pragma unroll
      for (int mi = 0; mi < 2; ++mi) {
        const int mb = m0 + wm * 32 + mi * 16 + q * 4;
        if (n < 32) {
          #pragma unroll
          for (int r = 0; r < 4; ++r)
            dtr[(size_t)(mb + r) * 32 + n] = (_Float16)acc[mi][ni][r];
        } else if (n < 160) {
          const int s = (n < 96) ? (n - 32) : (n - 96);
          float* dst = Bs + ((n < 96) ? 0 : 262144);
          float4 v = make_float4(acc[mi][ni][0], acc[mi][ni][1],
                                 acc[mi][ni][2], acc[mi][ni][3]);
          *(float4*)&dst[((size_t)(mb >> 2) << 8) + s * 4] = v;
        }
      }
    }
    return;
  }

  if (MODE == 3) {
    // dtproj: softplus(acc*oscale + bias) -> fp32 [N][4096] via LDS transpose
    __syncthreads();
    #pragma unroll
    for (int ni = 0; ni < NF; ++ni) {
      const int nnl = wn * (BN / 2) + ni * 16 + l16;     // 0..63 local
      const float bv = (bias != nullptr) ? bias[n0 + nnl] : 0.f;
      #pragma unroll
      for (int mi = 0; mi < 2; ++mi) {
        const int mbl = wm * 32 + mi * 16 + q * 4;       // 0..63 local
        float o[4];
        #pragma unroll
        for (int r = 0; r < 4; ++r) {
          float v = acc[mi][ni][r] * oscale + bv;
          o[r] = (v > 20.f) ? v : log1pf(__expf(v));     // softplus
        }
        *(float4*)&Td[nnl * 68 + mbl] = make_float4(o[0], o[1], o[2], o[3]);
      }
    }
    __syncthreads();
    const int sr = tid >> 4;            // 0..15
    const int sc = (tid & 15) * 4;      // floats 0..60
    #pragma unroll
    for (int rd = 0; rd < 4; ++rd) {
      const int row = rd * 16 + sr;
      float4 v = *(const float4*)&Td[row * 68 + sc];
      *(float4*)&Cf[(size_t)(n0 + row) * 4096 + m0 + sc] = v;
    }
    return;
  }

  // MODE 0 epilogue
  #pragma unroll
  for (int ni = 0; ni < NF; ++ni) {
    const int n = n0 + wn * (BN / 2) + ni * 16 + l16;
    if (n < N) {
      const float bv = (bias != nullptr) ? bias[n] : 0.f;
      #pragma unroll
      for (int mi = 0; mi < 2; ++mi) {
        const int mb = m0 + wm * 32 + mi * 16 + q * 4;
        #pragma unroll
        for (int r = 0; r < 4; ++r) {
          float v = acc[mi][ni][r] * oscale + bv;
          if (ACT == 1) v = (v > 20.f) ? v : log1pf(__expf(v));
          if (ACT == 2) v = silu_f(v);
          size_t off = (size_t)(mb + r) * ldc + n;
          if (OF16) Ch[off] = (_Float16)v;
          else      Cf[off] = v;
        }
      }
    }
  }
}

// ---------------------------------------------------------------------------
// Depthwise causal conv (D_CONV=2) + silu, 64x64 LDS transpose.
// half2/float2 vectorized (R26).
// in : xcp [4096 bl][1024 d] f16
// out: xcT [1024 d][4096 bl] fp32 (scan input)  +  xcf [4096 bl][1024 d] f16
// ---------------------------------------------------------------------------
__global__ void conv_t_kernel(const _Float16* __restrict__ xcp,
                              const float* __restrict__ cw,   // [1024][2]
                              const float* __restrict__ cb,   // [1024]
                              float* __restrict__ xcT,
                              _Float16* __restrict__ xcf)
{
  __shared__ float tile[64][66];
  const int blk = blockIdx.x;            // b*256 + tt*16 + dd
  const int b  = blk >> 8;
  const int tt = (blk >> 4) & 15;
  const int dd = blk & 15;
  const int t0 = tt * 64, d0 = dd * 64;
  const int tid = threadIdx.x;

  #pragma unroll
  for (int i = 0; i < 8; ++i) {
    int idx = i * 256 + tid;             // 0..2047
    int t  = idx >> 5;                   // 0..63
    int d2 = (idx & 31) * 2;             // even 0..62
    int gt = t0 + t;
    size_t rcur = ((size_t)(b * 1024 + gt) << 10) + d0 + d2;
    half2v cur = *(const half2v*)(xcp + rcur);
    half2v prev;
    if (gt > 0) prev = *(const half2v*)(xcp + rcur - 1024);
    else { prev[0] = (_Float16)0.f; prev[1] = (_Float16)0.f; }
    float4 cw4 = *(const float4*)(cw + (size_t)(d0 + d2) * 2);  // 16B aligned
    float2 cb2 = *(const float2*)(cb + d0 + d2);                // 8B aligned
    float v0 = fmaf((float)prev[0], cw4.x, fmaf((float)cur[0], cw4.y, cb2.x));
    float v1 = fmaf((float)prev[1], cw4.z, fmaf((float)cur[1], cw4.w, cb2.y));
    float sv0 = silu_f(v0), sv1 = silu_f(v1);
    *(float2*)&tile[t][d2] = make_float2(sv0, sv1);   // stride 66, d2 even: 8B ok
    half2v sh; sh[0] = (_Float16)sv0; sh[1] = (_Float16)sv1;
    *(half2v*)(xcf + rcur) = sh;
  }
  __syncthreads();
  #pragma unroll
  for (int i = 0; i < 8; ++i) {
    int idx = i * 256 + tid;             // 0..2047
    int d  = idx >> 5;                   // 0..63
    int t2 = (idx & 31) * 2;             // even 0..62
    float2 v = make_float2(tile[t2][d], tile[t2 + 1][d]);
    *(float2*)&xcT[((size_t)(d0 + d) << 12) + b * 1024 + t0 + t2] = v;
  }
}

// ---------------------------------------------------------------------------
// Selective scan v8, time-major. One wave per (b,d), lane = s (D_STATE=64).
// R20 base (C++ float4 loads -> compiler emits SMEM s_loads for the
// wave-uniform dt/x streams; sched_barrier region pinning), plus a
// chain/reduce software pipeline: chunk k's reduce (P-read + 3 shfl + y
// store) is deferred one chunk and co-scheduled with chunk k+1's chain.
// Established floor ~107us (8 structures tried, all issue-bound).
// ---------------------------------------------------------------------------
struct Chunk {
  float4 Bq0, Bq1, Cq0, Cq1, dq0, dq1, xq0, xq1;
  float zs, xvl;
};

__device__ __forceinline__ void load_chunk(int t0, Chunk& c,
    const float* __restrict__ Bb, const float* __restrict__ Cbp,
    const float* __restrict__ dtp, const float* __restrict__ xp,
    const _Float16* __restrict__ zsp, int tt_r)
{
  const float* Bp = Bb  + (((size_t)t0 >> 2) << 8);   // t0*64 floats
  const float* Cp = Cbp + (((size_t)t0 >> 2) << 8);
  c.Bq0 = *(const float4*)(Bp);        c.Bq1 = *(const float4*)(Bp + 256);
  c.Cq0 = *(const float4*)(Cp);        c.Cq1 = *(const float4*)(Cp + 256);
  c.dq0 = *(const float4*)(dtp + t0);  c.dq1 = *(const float4*)(dtp + t0 + 4);
  c.xq0 = *(const float4*)(xp + t0);   c.xq1 = *(const float4*)(xp + t0 + 4);
  c.zs  = (float)zsp[t0 + tt_r] * Y_SCALE;   // exact 2^14 fold
  c.xvl = xp[t0 + tt_r];
}

// chain phase: dA/ub prep + serial h-recurrence + P writes. No reduction.
__device__ __forceinline__ void chain_chunk(const Chunk& c, float& h,
    float al2, float (*Pw)[68], int lane)
{
  float dvv[8] = {c.dq0.x, c.dq0.y, c.dq0.z, c.dq0.w,
                  c.dq1.x, c.dq1.y, c.dq1.z, c.dq1.w};
  float xvv[8] = {c.xq0.x, c.xq0.y, c.xq0.z, c.xq0.w,
                  c.xq1.x, c.xq1.y, c.xq1.z, c.xq1.w};
  float Bvv[8] = {c.Bq0.x, c.Bq0.y, c.Bq0.z, c.Bq0.w,
                  c.Bq1.x, c.Bq1.y, c.Bq1.z, c.Bq1.w};
  float Cvv[8] = {c.Cq0.x, c.Cq0.y, c.Cq0.z, c.Cq0.w,
                  c.Cq1.x, c.Cq1.y, c.Cq1.z, c.Cq1.w};
  float dA[8], ub[8];
  #pragma unroll
  for (int tt = 0; tt < 8; ++tt) {
    dA[tt] = fast_exp2(dvv[tt] * al2);
    ub[tt] = dvv[tt] * xvv[tt] * Bvv[tt];
  }
  #pragma unroll
  for (int tt = 0; tt < 8; ++tt) {
    h = fmaf(h, dA[tt], ub[tt]);
    Pw[tt][lane] = h * Cvv[tt];
  }
}

// reduce phase (deferred one chunk): P-read, lane-tree + 3 shfl, y store.
__device__ __forceinline__ void reduce_chunk(int t0, float (*Pw)[68],
    float zs, float xvl, float dpv, _Float16* __restrict__ yp,
    int lane, int tt_r, int c0)
{
  float4 s0 = *(const float4*)&Pw[tt_r][c0];
  float4 s1 = *(const float4*)&Pw[tt_r][c0 + 4];
  float r = ((s0.x + s0.y) + (s0.z + s0.w)) + ((s1.x + s1.y) + (s1.z + s1.w));
  r += __shfl_xor(r, 1, 64);
  r += __shfl_xor(r, 2, 64);
  r += __shfl_xor(r, 4, 64);
  if ((lane & 7) == 0)
    yp[(size_t)(t0 + tt_r) << 10] = (_Float16)(fmaf(xvl, dpv, r) * zs);
}

__global__ __launch_bounds__(256, 4)
void scan_kernel(const float* __restrict__ dtT,     // [1024][4096]
                 const float* __restrict__ xcT,     // [1024][4096]
                 const _Float16* __restrict__ zsT,  // [1024][4096], silu(z), f16
                 const float* __restrict__ Bsc,     // [4][256][64][4]; Csc at +262144
                 const float* __restrict__ A_log,   // [1024][64]
                 const float* __restrict__ Dp,      // [1024]
                 _Float16* __restrict__ y16)        // [4096 bl][1024 d], y*2^14
{
  __shared__ float P[4][2][8][68];     // per-wave double reduction tiles
  const int tid  = threadIdx.x;
  const int lane = tid & 63;
  const int wrp  = tid >> 6;
  const int rb   = blockIdx.x;
  const int bswz = ((rb & 7) << 7) | (rb >> 3);          // XCD swizzle
  const int wid  = __builtin_amdgcn_readfirstlane(bswz * 4 + wrp);
  const int b = wid >> 10;
  const int d = wid & 1023;
  float (*P0)[68] = P[wrp][0];
  float (*P1)[68] = P[wrp][1];

  const float a   = -__expf(A_log[d * 64 + lane]);
  const float al2 = a * 1.44269504088896f;               // hoisted log2(e)
  const float dpv = Dp[d];
  const size_t row = ((size_t)d << 12) + b * 1024;
  const float*    dtp = dtT + row;
  const float*    xp  = xcT + row;
  const _Float16* zsp = zsT + row;
  _Float16*       yp  = y16 + ((size_t)b << 20) + d;     // + t*1024
  const float*    Bb  = Bsc + ((size_t)b << 16) + lane * 4;
  const float*    Cbp = Bb + 262144;

  const int tt_r = lane >> 3;          // timestep this lane reduces
  const int c0   = (lane & 7) << 3;    // its 8-state column base

  float h = 0.f;
  Chunk ca, cb;
  float zs0, xv0, zs1, xv1;

  // prologue: chunks 0 (ca) and 1 (cb); chain chunk 0 into P0.
  load_chunk(0, ca, Bb, Cbp, dtp, xp, zsp, tt_r);
  load_chunk(8, cb, Bb, Cbp, dtp, xp, zsp, tt_r);
  chain_chunk(ca, h, al2, P0, lane);
  zs0 = ca.zs; xv0 = ca.xvl;
  __builtin_amdgcn_sched_barrier(0);

  // steady state, 2 chunks per iteration (static P-buffer indices):
  //   stage A: load(k+2 -> ca) | chain(k+1 = cb -> P1) | reduce(k via P0)
  //   stage B: load(k+3 -> cb) | chain(k+2 = ca -> P0) | reduce(k+1 via P1)
  for (int t0 = 0; t0 < 1008; t0 += 16) {
    load_chunk(t0 + 16, ca, Bb, Cbp, dtp, xp, zsp, tt_r);
    chain_chunk(cb, h, al2, P1, lane);
    zs1 = cb.zs; xv1 = cb.xvl;
    reduce_chunk(t0, P0, zs0, xv0, dpv, yp, lane, tt_r, c0);
    __builtin_amdgcn_sched_barrier(0);

    load_chunk(t0 + 24, cb, Bb, Cbp, dtp, xp, zsp, tt_r);  // t0+24 <= 1016
    chain_chunk(ca, h, al2, P0, lane);
    zs0 = ca.zs; xv0 = ca.xvl;
    reduce_chunk(t0 + 8, P1, zs1, xv1, dpv, yp, lane, tt_r, c0);
    __builtin_amdgcn_sched_barrier(0);
  }
  // epilogue: chunk 127 (cb) chain, then the two pending reduces.
  chain_chunk(cb, h, al2, P1, lane);
  zs1 = cb.zs; xv1 = cb.xvl;
  reduce_chunk(1008, P0, zs0, xv0, dpv, yp, lane, tt_r, c0);
  reduce_chunk(1016, P1, zs1, xv1, dpv, yp, lane, tt_r, c0);
}

// ---------------------------------------------------------------------------
// Fused head: out[b,c] = (sum_di y16l1[b*1024+1023][di] * w2[c][di]) * 2^-14
//             + fc_b[c].  w2 precomputed in wcvt (fused w2prep).
// ---------------------------------------------------------------------------
__global__ void head2_kernel(const _Float16* __restrict__ y16,
                             const float* __restrict__ w2,   // [3][1024]
                             const float* __restrict__ fc_b,
                             float* __restrict__ out)
{
  __shared__ float red[4];
  const int bc = blockIdx.x;            // 0..11
  const int b = bc / 3, c = bc % 3;
  const int tid = threadIdx.x;
  const int lane = tid & 63, wv = tid >> 6;

  const _Float16* yr = y16 + ((size_t)(b * 1024 + 1023) << 10) + tid * 4;
  half4v yv = *(const half4v*)yr;
  float4 wq = *(const float4*)(w2 + c * 1024 + tid * 4);
  float s = (float)yv[0] * wq.x + (float)yv[1] * wq.y
          + (float)yv[2] * wq.z + (float)yv[3] * wq.w;
  #pragma unroll
  for (int o = 32; o > 0; o >>= 1) s += __shfl_xor(s, o, 64);
  if (lane == 0) red[wv] = s;
  __syncthreads();
  if (tid == 0)
    out[b * 3 + c] = (red[0] + red[1] + red[2] + red[3]) * (1.f / Y_SCALE)
                     + fc_b[c];
}

extern "C" void kernel_launch(void* const* d_in, const int* in_sizes, int n_in,
                              void* d_out, int out_size, void* d_ws, size_t ws_size,
                              hipStream_t stream)
{
  const float* x        = (const float*)d_in[0];
  const float* exp_w    = (const float*)d_in[1];
  const float* exp_b    = (const float*)d_in[2];
  const float* in_w     = (const float*)d_in[3];
  const float* conv_w   = (const float*)d_in[4];
  const float* conv_b   = (const float*)d_in[5];
  const float* xproj_w  = (const float*)d_in[6];
  const float* dtproj_w = (const float*)d_in[7];
  const float* dtproj_b = (const float*)d_in[8];
  const float* A_log    = (const float*)d_in[9];
  const float* Dp       = (const float*)d_in[10];
  const float* out_w    = (const float*)d_in[11];
  const float* fc_w     = (const float*)d_in[12];
  const float* fc_b     = (const float*)d_in[13];
  float* out = (float*)d_out;

  // Workspace layout (byte offsets), 72 MB total.
  // 4..20 MB region sequentially reused: xcpre16 (8MB) -> dtT (16MB).
  char* ws = (char*)d_ws;
  _Float16* hf16    = (_Float16*)(ws);                        //  4 MB [4096][512] f16
  _Float16* xcpre16 = (_Float16*)(ws + ((size_t)4  << 20));   //  8 MB [4096][1024] f16
  float*    dtT     = (float*)   (ws + ((size_t)4  << 20));   // 16 MB [1024][4096] (reuse)
  float*    xcT     = (float*)   (ws + ((size_t)20 << 20));   // 16 MB [1024][4096]
  _Float16* zsT     = (_Float16*)(ws + ((size_t)36 << 20));   //  8 MB [1024][4096]
  float*    Bsc     = (float*)   (ws + ((size_t)44 << 20));   //  2 MB [4][256][64][4] B then C
  float*    w2buf   = (float*)   (ws + ((size_t)46 << 20));   //  12 KB [3][1024]
  _Float16* dtr16   = (_Float16*)(ws + ((size_t)47 << 20));   //  0.25 MB [4096][32]
  _Float16* xc16    = (_Float16*)(ws + ((size_t)48 << 20));   //  8 MB [4096][1024]
  _Float16* y16     = (_Float16*)(ws + ((size_t)56 << 20));   //  8 MB [4096][1024]
  _Float16* w16     = (_Float16*)(ws + ((size_t)64 << 20));   //  7.9 MB f16 pool

  _Float16* exp16 = w16;                 // [512][128]
  _Float16* in16  = w16 + 65536;         // [2][2048][512]
  _Float16* xp16  = w16 + 2162688;       // [2][160][1024]
  _Float16* dt16  = w16 + 2490368;       // [2][1024][32]
  _Float16* out16 = w16 + 2555904;       // [2][512][1024]
  _Float16* x16   = w16 + 3604480;       // [4096][128]

  dim3 blk(256);

  // one-shot f16 conversion of all weights + x (4032 blocks) + fused
  // w2prep (blocks 4032..4047)
  wcvt_kernel<<<4048, blk, 0, stream>>>(exp_w, in_w, xproj_w, dtproj_w, out_w,
                                        x, w16, fc_w, w2buf);

  // expand: hf16 = f16(x @ exp_w^T + exp_b)   [4096,512] K=128, BK=32.
  gemm_mfma<64,32,0,1,0><<<dim3(8,64), blk, 0, stream>>>(x16, 128, exp16, exp_b,
                                                         hf16, 512, 512, 128, 1.f,
                                                         nullptr);

  for (int l = 0; l < 2; ++l) {
    const float is = l ? (1.f / H1_SCALE) : 1.f;     // undo h1 scaling (exact)
    // fused in_proj: xcpre16 f16 + zsT f16 (Tz aliases Ws). N=2048 K=512 BK=64.
    // R27: SW=1 grid(64,16) -- same-A blocks collocate per XCD L2.
    gemm_mfma<128,64,0,0,1,1><<<dim3(64,16), blk, 0, stream>>>(hf16, 512,
                                                             in16 + (size_t)l*1048576,
                                                             nullptr, xcpre16, 1024,
                                                             2048, 512, is, zsT);
    // conv + silu -> xcT (fp32, scan) + xc16 (f16, xproj A)
    conv_t_kernel<<<1024, blk, 0, stream>>>(xcpre16, conv_w + l*2048, conv_b + l*1024,
                                            xcT, xc16);
    // xproj (MODE 2): dtr16 f16 [4096][32] + Bsc/Csc scan layout. K=1024 BK=64.
    // R27: SW=1 grid(64,3).
    gemm_mfma<64,64,0,0,2,1><<<dim3(64,3), blk, 0, stream>>>(xc16, 1024,
                                                           xp16 + (size_t)l*163840,
                                                           nullptr, Bsc, 160,
                                                           160, 1024, 1.f, dtr16);
    // dtproj (MODE 3): dtT [1024][4096] softplus, LDS-transposed. K=32 BK=32.
    gemm_mfma<64,32,0,0,3><<<dim3(16,64), blk, 0, stream>>>(dtr16, 32,
                                                            dt16 + (size_t)l*32768,
                                                            dtproj_b + l*1024,
                                                            dtT, 4096, 1024, 32, 1.f,
                                                            nullptr);
    // selective scan v8 (chain/reduce pipelined, R20 base)
    scan_kernel<<<1024, blk, 0, stream>>>(dtT, xcT, zsT, Bsc,
                                          A_log + (size_t)l*65536, Dp + l*1024, y16);
    // out_proj only for layer 0 (layer-1 h only matters at t=L-1 -> head2)
    // R27: SW=1 grid(64,8).
    if (l == 0)
      gemm_mfma<64,64,0,1,0,1><<<dim3(64,8), blk, 0, stream>>>(y16, 1024,
                                                             out16, nullptr,
                                                             hf16, 512, 512, 1024,
                                                             H1_SCALE / Y_SCALE,
                                                             nullptr);
  }

  // head: y16(l1) . w2 (precomputed in wcvt) + fc_b
  head2_kernel<<<12, blk, 0, stream>>>(y16, w2buf, fc_b, out);
}